// Round 1
// baseline (1690.211 us; speedup 1.0000x reference)
//
#include <hip/hip_runtime.h>
#include <hip/hip_bf16.h>

#define NN 100000
#define EE 1000000
#define TE (EE + NN)   // edges incl. self loops
#define INDIM 128
#define C1 128         // HEADS*HID
#define HEADS 4
#define HID 32
#define C2 64

__device__ __forceinline__ unsigned fenc(float f) {
    unsigned b = __float_as_uint(f);
    return (b & 0x80000000u) ? ~b : (b | 0x80000000u);
}
__device__ __forceinline__ float fdec(unsigned k) {
    unsigned b = (k & 0x80000000u) ? (k ^ 0x80000000u) : ~k;
    return __uint_as_float(b);
}
__device__ __forceinline__ float lrelu(float v) { return v > 0.f ? v : 0.2f * v; }

// ---------------- GEMM1: h1 = x @ W1, plus s_src1/s_dst1 ----------------
__global__ __launch_bounds__(128) void k1_gemm1(const float* __restrict__ x,
    const float* __restrict__ W1, const float* __restrict__ a_src,
    const float* __restrict__ a_dst, float* __restrict__ h1,
    float* __restrict__ ssrc, float* __restrict__ sdst) {
    __shared__ float Wl[INDIM * C1];     // 64 KB
    __shared__ float xs[32][INDIM];      // 16 KB
    int t = threadIdx.x;
    for (int i = t; i < INDIM * C1; i += 128) Wl[i] = W1[i];
    int rbase = blockIdx.x * 32;
    for (int i = t; i < 32 * INDIM; i += 128) {
        int r = i >> 7, k = i & 127;
        xs[r][k] = x[(rbase + r) * INDIM + k];
    }
    __syncthreads();
    float av = a_src[t], dv = a_dst[t];
    int head = t >> 5;
    for (int r0 = 0; r0 < 32; r0 += 4) {
        float a0 = 0, a1 = 0, a2 = 0, a3 = 0;
        #pragma unroll 4
        for (int k = 0; k < INDIM; ++k) {
            float w = Wl[k * C1 + t];
            a0 = fmaf(xs[r0][k], w, a0);
            a1 = fmaf(xs[r0 + 1][k], w, a1);
            a2 = fmaf(xs[r0 + 2][k], w, a2);
            a3 = fmaf(xs[r0 + 3][k], w, a3);
        }
        float accs[4] = {a0, a1, a2, a3};
        #pragma unroll
        for (int i = 0; i < 4; ++i) {
            int row = rbase + r0 + i;
            h1[row * C1 + t] = accs[i];
            float ps = accs[i] * av, pd = accs[i] * dv;
            #pragma unroll
            for (int off = 16; off >= 1; off >>= 1) {
                ps += __shfl_xor(ps, off);
                pd += __shfl_xor(pd, off);
            }
            if ((t & 31) == 0) {
                ssrc[row * HEADS + head] = ps;
                sdst[row * HEADS + head] = pd;
            }
        }
    }
}

// ---------------- segment max, layer 1 (4 heads) ----------------
__global__ __launch_bounds__(256) void k2_max1(const int* __restrict__ esrc,
    const int* __restrict__ edst, const float* __restrict__ ssrc,
    const float* __restrict__ sdst, unsigned* __restrict__ m1) {
    int e = blockIdx.x * 256 + threadIdx.x;
    if (e >= TE) return;
    int s = e < EE ? esrc[e] : e - EE;
    int d = e < EE ? edst[e] : e - EE;
    const float4 ss = *(const float4*)(ssrc + s * 4);
    const float4 sd = *(const float4*)(sdst + d * 4);
    atomicMax(m1 + d * 4 + 0, fenc(lrelu(ss.x + sd.x)));
    atomicMax(m1 + d * 4 + 1, fenc(lrelu(ss.y + sd.y)));
    atomicMax(m1 + d * 4 + 2, fenc(lrelu(ss.z + sd.z)));
    atomicMax(m1 + d * 4 + 3, fenc(lrelu(ss.w + sd.w)));
}

// ---------------- scatter accumulate, layer 1 ----------------
__global__ __launch_bounds__(256) void k3_acc1(const int* __restrict__ esrc,
    const int* __restrict__ edst, const float* __restrict__ ssrc,
    const float* __restrict__ sdst, const unsigned* __restrict__ m1,
    const float* __restrict__ h1, float* __restrict__ acc,
    float* __restrict__ denom) {
    int t = threadIdx.x;
    int e = blockIdx.x * 2 + (t >> 7);
    if (e >= TE) return;
    int c = t & 127, h = c >> 5;
    int s = e < EE ? esrc[e] : e - EE;
    int d = e < EE ? edst[e] : e - EE;
    float ev = lrelu(ssrc[s * 4 + h] + sdst[d * 4 + h]);
    float w = __expf(ev - fdec(m1[d * 4 + h]));
    unsafeAtomicAdd(acc + d * C1 + c, w * h1[s * C1 + c]);
    if ((c & 31) == 0) unsafeAtomicAdd(denom + d * 4 + h, w);
}

// ---------------- finalize layer 1: /denom + b1, relu (in place) ----------------
__global__ __launch_bounds__(256) void k4_fin1(float* __restrict__ acc,
    const float* __restrict__ denom, const float* __restrict__ b1) {
    int idx = blockIdx.x * 256 + threadIdx.x;
    if (idx >= NN * C1) return;
    int n = idx >> 7, c = idx & 127;
    float v = acc[idx] / denom[n * 4 + (c >> 5)] + b1[c];
    acc[idx] = v > 0.f ? v : 0.f;
}

// ---------------- GEMM2: h2 = relu_out @ W2, plus s_src2/s_dst2 ----------------
__global__ __launch_bounds__(64) void k5_gemm2(const float* __restrict__ B,
    const float* __restrict__ W2, const float* __restrict__ a_src,
    const float* __restrict__ a_dst, float* __restrict__ h2,
    float* __restrict__ ssrc, float* __restrict__ sdst) {
    __shared__ float Wl[INDIM * C2];     // 32 KB
    __shared__ float xs[32][C1];         // 16 KB
    int t = threadIdx.x;
    for (int i = t; i < INDIM * C2; i += 64) Wl[i] = W2[i];
    int rbase = blockIdx.x * 32;
    for (int i = t; i < 32 * C1; i += 64) {
        int r = i >> 7, k = i & 127;
        xs[r][k] = B[(rbase + r) * C1 + k];
    }
    __syncthreads();
    float av = a_src[t], dv = a_dst[t];
    for (int r0 = 0; r0 < 32; r0 += 4) {
        float a0 = 0, a1 = 0, a2 = 0, a3 = 0;
        #pragma unroll 4
        for (int k = 0; k < C1; ++k) {
            float w = Wl[k * C2 + t];
            a0 = fmaf(xs[r0][k], w, a0);
            a1 = fmaf(xs[r0 + 1][k], w, a1);
            a2 = fmaf(xs[r0 + 2][k], w, a2);
            a3 = fmaf(xs[r0 + 3][k], w, a3);
        }
        float accs[4] = {a0, a1, a2, a3};
        #pragma unroll
        for (int i = 0; i < 4; ++i) {
            int row = rbase + r0 + i;
            h2[row * C2 + t] = accs[i];
            float ps = accs[i] * av, pd = accs[i] * dv;
            #pragma unroll
            for (int off = 32; off >= 1; off >>= 1) {
                ps += __shfl_xor(ps, off);
                pd += __shfl_xor(pd, off);
            }
            if (t == 0) { ssrc[row] = ps; sdst[row] = pd; }
        }
    }
}

// ---------------- segment max, layer 2 (1 head) ----------------
__global__ __launch_bounds__(256) void k6_max2(const int* __restrict__ esrc,
    const int* __restrict__ edst, const float* __restrict__ ssrc,
    const float* __restrict__ sdst, unsigned* __restrict__ m2) {
    int e = blockIdx.x * 256 + threadIdx.x;
    if (e >= TE) return;
    int s = e < EE ? esrc[e] : e - EE;
    int d = e < EE ? edst[e] : e - EE;
    atomicMax(m2 + d, fenc(lrelu(ssrc[s] + sdst[d])));
}

// ---------------- scatter accumulate, layer 2 (into d_out) ----------------
__global__ __launch_bounds__(256) void k7_acc2(const int* __restrict__ esrc,
    const int* __restrict__ edst, const float* __restrict__ ssrc,
    const float* __restrict__ sdst, const unsigned* __restrict__ m2,
    const float* __restrict__ h2, float* __restrict__ out,
    float* __restrict__ denom) {
    int t = threadIdx.x;
    int e = blockIdx.x * 4 + (t >> 6);
    if (e >= TE) return;
    int c = t & 63;
    int s = e < EE ? esrc[e] : e - EE;
    int d = e < EE ? edst[e] : e - EE;
    float w = __expf(lrelu(ssrc[s] + sdst[d]) - fdec(m2[d]));
    unsafeAtomicAdd(out + d * C2 + c, w * h2[s * C2 + c]);
    if (c == 0) unsafeAtomicAdd(denom + d, w);
}

// ---------------- final: /denom + b2, FC, log_softmax (in place on d_out) ----------------
__global__ __launch_bounds__(256) void k8_final(const float* __restrict__ denom,
    const float* __restrict__ b2, const float* __restrict__ fcW,
    const float* __restrict__ fcb, float* __restrict__ out) {
    __shared__ float Wl[C2 * C2];        // 16 KB
    int t = threadIdx.x;
    for (int i = t; i < C2 * C2; i += 256) Wl[i] = fcW[i];
    __syncthreads();
    int lane = t & 63, wid = t >> 6;
    int wg = blockIdx.x * 4 + wid;
    int nw = gridDim.x * 4;
    float b2v = b2[lane], fbv = fcb[lane];
    for (int n = wg; n < NN; n += nw) {
        float val = out[n * C2 + lane] / denom[n] + b2v;
        float y = fbv;
        #pragma unroll
        for (int c = 0; c < C2; ++c) {
            float vc = __shfl(val, c);
            y = fmaf(vc, Wl[c * C2 + lane], y);
        }
        float m = y;
        #pragma unroll
        for (int off = 32; off >= 1; off >>= 1) m = fmaxf(m, __shfl_xor(m, off));
        float sv = __expf(y - m);
        #pragma unroll
        for (int off = 32; off >= 1; off >>= 1) sv += __shfl_xor(sv, off);
        out[n * C2 + lane] = y - m - logf(sv);
    }
}

extern "C" void kernel_launch(void* const* d_in, const int* in_sizes, int n_in,
                              void* d_out, int out_size, void* d_ws, size_t ws_size,
                              hipStream_t stream) {
    const float* x   = (const float*)d_in[0];
    const int*   ei  = (const int*)d_in[1];
    const float* W1  = (const float*)d_in[2];
    const float* as1 = (const float*)d_in[3];
    const float* ad1 = (const float*)d_in[4];
    const float* b1  = (const float*)d_in[5];
    const float* W2  = (const float*)d_in[6];
    const float* as2 = (const float*)d_in[7];
    const float* ad2 = (const float*)d_in[8];
    const float* b2  = (const float*)d_in[9];
    const float* fcW = (const float*)d_in[10];
    const float* fcb = (const float*)d_in[11];
    float* out = (float*)d_out;

    float* ws = (float*)d_ws;
    size_t o = 0;
    float* h1    = ws + o; o += (size_t)NN * C1;      // 12.8M
    float* acc1  = ws + o; o += (size_t)NN * C1;      // 12.8M (becomes relu output)
    float* ssrc1 = ws + o; o += (size_t)NN * HEADS;
    float* sdst1 = ws + o; o += (size_t)NN * HEADS;
    unsigned* m1 = (unsigned*)(ws + o); o += (size_t)NN * HEADS;
    float* den1  = ws + o; o += (size_t)NN * HEADS;
    float* ssrc2 = ws + o; o += NN;
    float* sdst2 = ws + o; o += NN;
    unsigned* m2 = (unsigned*)(ws + o); o += NN;
    float* den2  = ws + o; o += NN;
    float* h2    = h1;   // h1 dead after k3/k4; reuse for h2

    const int* esrc = ei;
    const int* edst = ei + EE;

    hipMemsetAsync(acc1, 0, (size_t)NN * C1 * sizeof(float), stream);
    hipMemsetAsync(m1,   0, (size_t)NN * HEADS * sizeof(unsigned), stream);
    hipMemsetAsync(den1, 0, (size_t)NN * HEADS * sizeof(float), stream);
    hipMemsetAsync(m2,   0, (size_t)NN * sizeof(unsigned), stream);
    hipMemsetAsync(den2, 0, (size_t)NN * sizeof(float), stream);
    hipMemsetAsync(out,  0, (size_t)NN * C2 * sizeof(float), stream);

    k1_gemm1<<<NN / 32, 128, 0, stream>>>(x, W1, as1, ad1, h1, ssrc1, sdst1);
    k2_max1<<<(TE + 255) / 256, 256, 0, stream>>>(esrc, edst, ssrc1, sdst1, m1);
    k3_acc1<<<(TE + 1) / 2, 256, 0, stream>>>(esrc, edst, ssrc1, sdst1, m1, h1, acc1, den1);
    k4_fin1<<<(NN * C1 + 255) / 256, 256, 0, stream>>>(acc1, den1, b1);
    k5_gemm2<<<NN / 32, 64, 0, stream>>>(acc1, W2, as2, ad2, h2, ssrc2, sdst2);
    k6_max2<<<(TE + 255) / 256, 256, 0, stream>>>(esrc, edst, ssrc2, sdst2, m2);
    k7_acc2<<<(TE + 3) / 4, 256, 0, stream>>>(esrc, edst, ssrc2, sdst2, m2, h2, out, den2);
    k8_final<<<1024, 256, 0, stream>>>(den2, b2, fcW, fcb, out);
}

// Round 2
// 670.135 us; speedup vs baseline: 2.5222x; 2.5222x over previous
//
#include <hip/hip_runtime.h>
#include <hip/hip_bf16.h>
#include <cfloat>

#define NN 100000
#define EE 1000000
#define TE (EE + NN)   // edges incl. self loops
#define C1 128         // HEADS*HID
#define C2 64
#define NBLK 391       // ceil(NN/256)

__device__ __forceinline__ float lrelu(float v) { return v > 0.f ? v : 0.2f * v; }

// ================= CSR build (counting sort by dst) =================
__global__ __launch_bounds__(256) void kc_count(const int* __restrict__ edst,
                                                int* __restrict__ cnt) {
    int e = blockIdx.x * 256 + threadIdx.x;
    if (e >= TE) return;
    int d = e < EE ? edst[e] : e - EE;
    atomicAdd(cnt + d, 1);
}

__global__ __launch_bounds__(256) void kc_scan1(const int* __restrict__ cnt,
                                                int* __restrict__ pscan,
                                                int* __restrict__ bsum) {
    __shared__ int sm[256];
    int tid = threadIdx.x;
    int i = blockIdx.x * 256 + tid;
    int v = (i < NN) ? cnt[i] : 0;
    sm[tid] = v;
    __syncthreads();
    for (int off = 1; off < 256; off <<= 1) {
        int o = 0;
        if (tid >= off) o = sm[tid - off];
        __syncthreads();
        if (tid >= off) sm[tid] += o;
        __syncthreads();
    }
    if (i < NN) pscan[i] = sm[tid] - v;      // exclusive within block
    if (tid == 255) bsum[blockIdx.x] = sm[255];
}

__global__ __launch_bounds__(512) void kc_scan2(const int* __restrict__ bsum,
                                                int* __restrict__ boff) {
    __shared__ int sm[512];
    int tid = threadIdx.x;
    int v = (tid < NBLK) ? bsum[tid] : 0;
    sm[tid] = v;
    __syncthreads();
    for (int off = 1; off < 512; off <<= 1) {
        int o = 0;
        if (tid >= off) o = sm[tid - off];
        __syncthreads();
        if (tid >= off) sm[tid] += o;
        __syncthreads();
    }
    if (tid < NBLK) boff[tid] = sm[tid] - v; // exclusive block offsets
}

__global__ __launch_bounds__(256) void kc_scan3(const int* __restrict__ pscan,
                                                const int* __restrict__ boff,
                                                int* __restrict__ rowstart,
                                                int* __restrict__ cursor) {
    int i = blockIdx.x * 256 + threadIdx.x;
    if (i >= NN) return;
    int rs = pscan[i] + boff[blockIdx.x];
    rowstart[i] = rs;
    cursor[i] = rs;
    if (i == 0) rowstart[NN] = TE;
}

__global__ __launch_bounds__(256) void kc_fill(const int* __restrict__ esrc,
                                               const int* __restrict__ edst,
                                               int* __restrict__ cursor,
                                               int* __restrict__ eidx) {
    int e = blockIdx.x * 256 + threadIdx.x;
    if (e >= TE) return;
    int s = e < EE ? esrc[e] : e - EE;
    int d = e < EE ? edst[e] : e - EE;
    int pos = atomicAdd(cursor + d, 1);
    eidx[pos] = s;
}

// ================= GEMM1: h1 = x @ W1 (+ attention scores) =================
__global__ __launch_bounds__(256) void k1_gemm1(const float* __restrict__ x,
    const float* __restrict__ W1, const float* __restrict__ a_src,
    const float* __restrict__ a_dst, float* __restrict__ h1,
    float* __restrict__ ssrc, float* __restrict__ sdst) {
    __shared__ float Wl[C1 * C1];    // 64 KB
    __shared__ float xs[32][C1];     // 16 KB
    int t = threadIdx.x;
    int c = t & 127, rh = t >> 7;
    for (int i = t; i < C1 * C1; i += 256) Wl[i] = W1[i];
    int rbase = blockIdx.x * 32;
    for (int i = t; i < 32 * C1; i += 256) {
        int r = i >> 7, k = i & 127;
        xs[r][k] = x[(size_t)(rbase + r) * C1 + k];
    }
    __syncthreads();
    float av = a_src[c], dv = a_dst[c];
    int head = c >> 5;
    for (int r0 = 0; r0 < 16; r0 += 4) {
        int rb = rh * 16 + r0;
        float a0 = 0, a1 = 0, a2 = 0, a3 = 0;
        for (int k = 0; k < C1; ++k) {
            float w = Wl[k * C1 + c];
            a0 = fmaf(xs[rb][k],     w, a0);
            a1 = fmaf(xs[rb + 1][k], w, a1);
            a2 = fmaf(xs[rb + 2][k], w, a2);
            a3 = fmaf(xs[rb + 3][k], w, a3);
        }
        float accs[4] = {a0, a1, a2, a3};
        #pragma unroll
        for (int i = 0; i < 4; ++i) {
            int row = rbase + rb + i;
            h1[(size_t)row * C1 + c] = accs[i];
            float ps = accs[i] * av, pd = accs[i] * dv;
            #pragma unroll
            for (int off = 16; off >= 1; off >>= 1) {
                ps += __shfl_xor(ps, off);
                pd += __shfl_xor(pd, off);
            }
            if ((c & 31) == 0) {
                ssrc[row * 4 + head] = ps;
                sdst[row * 4 + head] = pd;
            }
        }
    }
}

// ====== Aggregation layer 1: one wave per dst node, 128 channels ======
// fuses: segment max, softmax weights, denom, gather-accumulate, /denom + b1, relu
__global__ __launch_bounds__(256) void agg1(const int* __restrict__ rowstart,
    const int* __restrict__ eidx, const float* __restrict__ ssrc,
    const float* __restrict__ sdst, const float* __restrict__ h1,
    const float* __restrict__ b1, float* __restrict__ hr) {
    int lane = threadIdx.x & 63;
    int n = blockIdx.x * 4 + (threadIdx.x >> 6);
    if (n >= NN) return;
    int r0 = rowstart[n], deg = rowstart[n + 1] - r0;
    int h4 = lane >> 4, j16 = lane & 15;   // score duty: head h4, edge slot j16
    float sd = sdst[n * 4 + h4];
    // sweep A: per-head max
    float mx = -FLT_MAX;
    for (int base = 0; base < deg; base += 16) {
        int j = base + j16;
        if (j < deg) {
            int s = eidx[r0 + j];
            mx = fmaxf(mx, lrelu(ssrc[s * 4 + h4] + sd));
        }
    }
    #pragma unroll
    for (int off = 1; off <= 8; off <<= 1) mx = fmaxf(mx, __shfl_xor(mx, off));
    // mx == m[h4] in every lane of its 16-group
    int hA = lane >> 5, hB = hA + 2;       // channel duty: c=lane (head hA), c=lane+64 (head hB)
    float acc0 = 0.f, acc1 = 0.f, den = 0.f;
    for (int base = 0; base < deg; base += 16) {
        int j = base + j16;
        int sreg = 0; float w = 0.f;
        if (j < deg) {
            sreg = eidx[r0 + j];
            w = __expf(lrelu(ssrc[sreg * 4 + h4] + sd) - mx);
        }
        den += w;
        int lim = deg - base; if (lim > 16) lim = 16;
        for (int jj = 0; jj < lim; ++jj) {
            int s    = __shfl(sreg, jj);
            float wA = __shfl(w, (hA << 4) + jj);
            float wB = __shfl(w, (hB << 4) + jj);
            const float* hp = h1 + (size_t)s * C1;
            acc0 = fmaf(wA, hp[lane],      acc0);
            acc1 = fmaf(wB, hp[64 + lane], acc1);
        }
    }
    #pragma unroll
    for (int off = 1; off <= 8; off <<= 1) den += __shfl_xor(den, off);
    float dA = __shfl(den, hA << 4);
    float dB = __shfl(den, hB << 4);
    float v0 = acc0 / dA + b1[lane];
    float v1 = acc1 / dB + b1[64 + lane];
    hr[(size_t)n * C1 + lane]      = v0 > 0.f ? v0 : 0.f;
    hr[(size_t)n * C1 + 64 + lane] = v1 > 0.f ? v1 : 0.f;
}

// ================= GEMM2: h2 = hr @ W2 (+ scores) =================
__global__ __launch_bounds__(256) void k5_gemm2(const float* __restrict__ B,
    const float* __restrict__ W2, const float* __restrict__ a_src,
    const float* __restrict__ a_dst, float* __restrict__ h2,
    float* __restrict__ ssrc, float* __restrict__ sdst) {
    __shared__ float Wl[C1 * C2];    // 32 KB
    __shared__ float xs[64][C1];     // 32 KB
    int t = threadIdx.x;
    int c = t & 63, rq = t >> 6;
    for (int i = t; i < C1 * C2; i += 256) Wl[i] = W2[i];
    int rbase = blockIdx.x * 64;
    for (int i = t; i < 64 * C1; i += 256) {
        int r = i >> 7, k = i & 127;
        int row = rbase + r;
        xs[r][k] = (row < NN) ? B[(size_t)row * C1 + k] : 0.f;
    }
    __syncthreads();
    float av = a_src[c], dv = a_dst[c];
    for (int r0 = 0; r0 < 16; r0 += 4) {
        int rb = rq * 16 + r0;
        float a0 = 0, a1 = 0, a2 = 0, a3 = 0;
        for (int k = 0; k < C1; ++k) {
            float w = Wl[k * C2 + c];
            a0 = fmaf(xs[rb][k],     w, a0);
            a1 = fmaf(xs[rb + 1][k], w, a1);
            a2 = fmaf(xs[rb + 2][k], w, a2);
            a3 = fmaf(xs[rb + 3][k], w, a3);
        }
        float accs[4] = {a0, a1, a2, a3};
        #pragma unroll
        for (int i = 0; i < 4; ++i) {
            int row = rbase + rb + i;
            if (row < NN) {
                h2[(size_t)row * C2 + c] = accs[i];
                float ps = accs[i] * av, pd = accs[i] * dv;
                #pragma unroll
                for (int off = 32; off >= 1; off >>= 1) {
                    ps += __shfl_xor(ps, off);
                    pd += __shfl_xor(pd, off);
                }
                if (c == 0) { ssrc[row] = ps; sdst[row] = pd; }
            }
        }
    }
}

// ====== Aggregation layer 2: one wave per dst node, 64 channels ======
// writes finalized (acc/den + b2) rows directly to d_out
__global__ __launch_bounds__(256) void agg2(const int* __restrict__ rowstart,
    const int* __restrict__ eidx, const float* __restrict__ ssrc,
    const float* __restrict__ sdst, const float* __restrict__ h2,
    const float* __restrict__ b2, float* __restrict__ out) {
    int lane = threadIdx.x & 63;
    int n = blockIdx.x * 4 + (threadIdx.x >> 6);
    if (n >= NN) return;
    int r0 = rowstart[n], deg = rowstart[n + 1] - r0;
    float sd = sdst[n];
    float mx = -FLT_MAX;
    for (int base = 0; base < deg; base += 64) {
        int j = base + lane;
        if (j < deg) {
            int s = eidx[r0 + j];
            mx = fmaxf(mx, lrelu(ssrc[s] + sd));
        }
    }
    #pragma unroll
    for (int off = 1; off <= 32; off <<= 1) mx = fmaxf(mx, __shfl_xor(mx, off));
    float acc = 0.f, den = 0.f;
    for (int base = 0; base < deg; base += 64) {
        int j = base + lane;
        int sreg = 0; float w = 0.f;
        if (j < deg) {
            sreg = eidx[r0 + j];
            w = __expf(lrelu(ssrc[sreg] + sd) - mx);
        }
        den += w;
        int lim = deg - base; if (lim > 64) lim = 64;
        for (int jj = 0; jj < lim; ++jj) {
            int s = __shfl(sreg, jj);
            float wj = __shfl(w, jj);
            acc = fmaf(wj, h2[(size_t)s * C2 + lane], acc);
        }
    }
    #pragma unroll
    for (int off = 1; off <= 32; off <<= 1) den += __shfl_xor(den, off);
    out[(size_t)n * C2 + lane] = acc / den + b2[lane];
}

// ================= FC + log_softmax (in place on d_out) =================
__global__ __launch_bounds__(256) void k8_final(const float* __restrict__ fcW,
    const float* __restrict__ fcb, float* __restrict__ out) {
    __shared__ float Wl[C2 * C2];    // 16 KB
    int t = threadIdx.x;
    for (int i = t; i < C2 * C2; i += 256) Wl[i] = fcW[i];
    __syncthreads();
    int lane = t & 63, wid = t >> 6;
    int wg = blockIdx.x * 4 + wid, nw = gridDim.x * 4;
    float fbv = fcb[lane];
    for (int n = wg; n < NN; n += nw) {
        float val = out[(size_t)n * C2 + lane];
        float y = fbv;
        #pragma unroll
        for (int cc = 0; cc < C2; ++cc) {
            y = fmaf(__shfl(val, cc), Wl[cc * C2 + lane], y);
        }
        float m = y;
        #pragma unroll
        for (int off = 32; off >= 1; off >>= 1) m = fmaxf(m, __shfl_xor(m, off));
        float sv = __expf(y - m);
        #pragma unroll
        for (int off = 32; off >= 1; off >>= 1) sv += __shfl_xor(sv, off);
        out[(size_t)n * C2 + lane] = y - m - logf(sv);
    }
}

extern "C" void kernel_launch(void* const* d_in, const int* in_sizes, int n_in,
                              void* d_out, int out_size, void* d_ws, size_t ws_size,
                              hipStream_t stream) {
    const float* x   = (const float*)d_in[0];
    const int*   ei  = (const int*)d_in[1];
    const float* W1  = (const float*)d_in[2];
    const float* as1 = (const float*)d_in[3];
    const float* ad1 = (const float*)d_in[4];
    const float* b1  = (const float*)d_in[5];
    const float* W2  = (const float*)d_in[6];
    const float* as2 = (const float*)d_in[7];
    const float* ad2 = (const float*)d_in[8];
    const float* b2  = (const float*)d_in[9];
    const float* fcW = (const float*)d_in[10];
    const float* fcb = (const float*)d_in[11];
    float* out = (float*)d_out;

    float* ws = (float*)d_ws;
    size_t o = 0;
    float* h1    = ws + o; o += (size_t)NN * C1;   // 12.8M (reused as h2)
    float* hr1   = ws + o; o += (size_t)NN * C1;   // 12.8M
    float* ssrc1 = ws + o; o += (size_t)NN * 4;
    float* sdst1 = ws + o; o += (size_t)NN * 4;
    float* ssrc2 = ws + o; o += NN;
    float* sdst2 = ws + o; o += NN;
    int* ip = (int*)(ws + o);
    int* cnt      = ip; ip += NN;
    int* pscan    = ip; ip += NN;
    int* bsum     = ip; ip += 512;
    int* boff     = ip; ip += 512;
    int* rowstart = ip; ip += NN + 2;
    int* cursor   = ip; ip += NN;
    int* eidx     = ip; ip += TE;
    float* h2 = h1;

    const int* esrc = ei;
    const int* edst = ei + EE;

    hipMemsetAsync(cnt, 0, (size_t)NN * sizeof(int), stream);

    // CSR build
    kc_count<<<(TE + 255) / 256, 256, 0, stream>>>(edst, cnt);
    kc_scan1<<<NBLK, 256, 0, stream>>>(cnt, pscan, bsum);
    kc_scan2<<<1, 512, 0, stream>>>(bsum, boff);
    kc_scan3<<<NBLK, 256, 0, stream>>>(pscan, boff, rowstart, cursor);
    kc_fill<<<(TE + 255) / 256, 256, 0, stream>>>(esrc, edst, cursor, eidx);

    // layer 1
    k1_gemm1<<<NN / 32, 256, 0, stream>>>(x, W1, as1, ad1, h1, ssrc1, sdst1);
    agg1<<<(NN + 3) / 4, 256, 0, stream>>>(rowstart, eidx, ssrc1, sdst1, h1, b1, hr1);
    // layer 2
    k5_gemm2<<<(NN + 63) / 64, 256, 0, stream>>>(hr1, W2, as2, ad2, h2, ssrc2, sdst2);
    agg2<<<(NN + 3) / 4, 256, 0, stream>>>(rowstart, eidx, ssrc2, sdst2, h2, b2, out);
    // FC + log_softmax
    k8_final<<<1024, 256, 0, stream>>>(fcW, fcb, out);
}

// Round 3
// 561.913 us; speedup vs baseline: 3.0080x; 1.1926x over previous
//
#include <hip/hip_runtime.h>
#include <hip/hip_bf16.h>
#include <cfloat>

#define NN 100000
#define EE 1000000
#define TE (EE + NN)   // edges incl. self loops
#define C1 128         // HEADS*HID
#define C2 64
#define NBLK 391       // ceil(NN/256)
#define NB1 782        // ceil(NN/128)

__device__ __forceinline__ float lrelu(float v) { return v > 0.f ? v : 0.2f * v; }

// ================= CSR build (counting sort by dst) =================
__global__ __launch_bounds__(256) void kc_count(const int* __restrict__ edst,
                                                int* __restrict__ cnt) {
    int e = blockIdx.x * 256 + threadIdx.x;
    if (e >= TE) return;
    int d = e < EE ? edst[e] : e - EE;
    atomicAdd(cnt + d, 1);
}

__global__ __launch_bounds__(256) void kc_scan1(const int* __restrict__ cnt,
                                                int* __restrict__ pscan,
                                                int* __restrict__ bsum) {
    __shared__ int sm[256];
    int tid = threadIdx.x;
    int i = blockIdx.x * 256 + tid;
    int v = (i < NN) ? cnt[i] : 0;
    sm[tid] = v;
    __syncthreads();
    for (int off = 1; off < 256; off <<= 1) {
        int o = 0;
        if (tid >= off) o = sm[tid - off];
        __syncthreads();
        if (tid >= off) sm[tid] += o;
        __syncthreads();
    }
    if (i < NN) pscan[i] = sm[tid] - v;      // exclusive within block
    if (tid == 255) bsum[blockIdx.x] = sm[255];
}

__global__ __launch_bounds__(512) void kc_scan2(const int* __restrict__ bsum,
                                                int* __restrict__ boff) {
    __shared__ int sm[512];
    int tid = threadIdx.x;
    int v = (tid < NBLK) ? bsum[tid] : 0;
    sm[tid] = v;
    __syncthreads();
    for (int off = 1; off < 512; off <<= 1) {
        int o = 0;
        if (tid >= off) o = sm[tid - off];
        __syncthreads();
        if (tid >= off) sm[tid] += o;
        __syncthreads();
    }
    if (tid < NBLK) boff[tid] = sm[tid] - v; // exclusive block offsets
}

__global__ __launch_bounds__(256) void kc_scan3(const int* __restrict__ pscan,
                                                const int* __restrict__ boff,
                                                int* __restrict__ rowstart,
                                                int* __restrict__ cursor) {
    int i = blockIdx.x * 256 + threadIdx.x;
    if (i >= NN) return;
    int rs = pscan[i] + boff[blockIdx.x];
    rowstart[i] = rs;
    cursor[i] = rs;
    if (i == 0) rowstart[NN] = TE;
}

__global__ __launch_bounds__(256) void kc_fill(const int* __restrict__ esrc,
                                               const int* __restrict__ edst,
                                               int* __restrict__ cursor,
                                               int* __restrict__ eidx) {
    int e = blockIdx.x * 256 + threadIdx.x;
    if (e >= TE) return;
    int s = e < EE ? esrc[e] : e - EE;
    int d = e < EE ? edst[e] : e - EE;
    int pos = atomicAdd(cursor + d, 1);
    eidx[pos] = s;
}

// ============ GEMM1: h1 = x @ W1 (+ attention scores), 128x128 tile ============
// 256 threads: thread grid 16(tr) x 16(tc); micro-tile 8 rows x (4+4) cols.
// Thread cols: {4tc..4tc+3} and {64+4tc..64+4tc+3}  -> 2-way LDS banks (free).
__global__ __launch_bounds__(256, 1) void k1_gemm1(const float* __restrict__ x,
    const float* __restrict__ W1, const float* __restrict__ a_src,
    const float* __restrict__ a_dst, float* __restrict__ h1,
    float* __restrict__ ssrc, float* __restrict__ sdst) {
    __shared__ float xs[128][129];   // 66 KB, pad -> bank (r+k)%32
    __shared__ float Wl[128 * 128];  // 64 KB, Wl[k*128+c]
    int t = threadIdx.x;
    int rbase = blockIdx.x * 128;
    for (int i = t; i < 128 * 128; i += 256) Wl[i] = W1[i];
    for (int i = t; i < 128 * 128; i += 256) {
        int r = i >> 7, k = i & 127;
        int row = rbase + r; if (row >= NN) row = NN - 1;
        xs[r][k] = x[(size_t)row * 128 + k];
    }
    __syncthreads();
    int tc = t & 15, tr = t >> 4;
    int r0 = tr * 8, cA = tc * 4, cB = 64 + tc * 4;
    float acc[8][8];
    #pragma unroll
    for (int i = 0; i < 8; ++i)
        #pragma unroll
        for (int j = 0; j < 8; ++j) acc[i][j] = 0.f;
    for (int k = 0; k < 128; ++k) {
        float xv[8], wv[8];
        #pragma unroll
        for (int i = 0; i < 8; ++i) xv[i] = xs[r0 + i][k];
        #pragma unroll
        for (int j = 0; j < 4; ++j) wv[j] = Wl[k * 128 + cA + j];
        #pragma unroll
        for (int j = 0; j < 4; ++j) wv[4 + j] = Wl[k * 128 + cB + j];
        #pragma unroll
        for (int i = 0; i < 8; ++i)
            #pragma unroll
            for (int j = 0; j < 8; ++j) acc[i][j] = fmaf(xv[i], wv[j], acc[i][j]);
    }
    // epilogue: store h1, compute per-row per-head score partials
    float asv[8], adv[8];
    #pragma unroll
    for (int j = 0; j < 4; ++j) {
        asv[j] = a_src[cA + j];     adv[j] = a_dst[cA + j];
        asv[4 + j] = a_src[cB + j]; adv[4 + j] = a_dst[cB + j];
    }
    #pragma unroll
    for (int i = 0; i < 8; ++i) {
        int row = rbase + r0 + i;
        bool ok = row < NN;
        if (ok) {
            *(float4*)(h1 + (size_t)row * 128 + cA) =
                make_float4(acc[i][0], acc[i][1], acc[i][2], acc[i][3]);
            *(float4*)(h1 + (size_t)row * 128 + cB) =
                make_float4(acc[i][4], acc[i][5], acc[i][6], acc[i][7]);
        }
        float psA = 0.f, pdA = 0.f, psB = 0.f, pdB = 0.f;
        #pragma unroll
        for (int j = 0; j < 4; ++j) {
            psA = fmaf(acc[i][j], asv[j], psA);
            pdA = fmaf(acc[i][j], adv[j], pdA);
            psB = fmaf(acc[i][4 + j], asv[4 + j], psB);
            pdB = fmaf(acc[i][4 + j], adv[4 + j], pdB);
        }
        // reduce across the 8 tc's sharing a head (tc groups of 8: heads {0,1} in A, {2,3} in B)
        #pragma unroll
        for (int off = 1; off <= 4; off <<= 1) {
            psA += __shfl_xor(psA, off); pdA += __shfl_xor(pdA, off);
            psB += __shfl_xor(psB, off); pdB += __shfl_xor(pdB, off);
        }
        if ((tc & 7) == 0 && ok) {
            int hA = tc >> 3;          // 0 or 1
            ssrc[row * 4 + hA] = psA;     sdst[row * 4 + hA] = pdA;
            ssrc[row * 4 + 2 + hA] = psB; sdst[row * 4 + 2 + hA] = pdB;
        }
    }
}

// ====== Aggregation layer 1: one wave per dst node, 128 channels ======
__global__ __launch_bounds__(256) void agg1(const int* __restrict__ rowstart,
    const int* __restrict__ eidx, const float* __restrict__ ssrc,
    const float* __restrict__ sdst, const float* __restrict__ h1,
    const float* __restrict__ b1, float* __restrict__ hr) {
    int lane = threadIdx.x & 63;
    int n = blockIdx.x * 4 + (threadIdx.x >> 6);
    if (n >= NN) return;
    int r0 = rowstart[n], deg = rowstart[n + 1] - r0;
    int h4 = lane >> 4, j16 = lane & 15;
    float sd = sdst[n * 4 + h4];
    float mx = -FLT_MAX;
    for (int base = 0; base < deg; base += 16) {
        int j = base + j16;
        if (j < deg) {
            int s = eidx[r0 + j];
            mx = fmaxf(mx, lrelu(ssrc[s * 4 + h4] + sd));
        }
    }
    #pragma unroll
    for (int off = 1; off <= 8; off <<= 1) mx = fmaxf(mx, __shfl_xor(mx, off));
    int hA = lane >> 5, hB = hA + 2;
    float acc0 = 0.f, acc1 = 0.f, den = 0.f;
    for (int base = 0; base < deg; base += 16) {
        int j = base + j16;
        int sreg = 0; float w = 0.f;
        if (j < deg) {
            sreg = eidx[r0 + j];
            w = __expf(lrelu(ssrc[sreg * 4 + h4] + sd) - mx);
        }
        den += w;
        int lim = deg - base; if (lim > 16) lim = 16;
        for (int jj = 0; jj < lim; ++jj) {
            int s    = __shfl(sreg, jj);
            float wA = __shfl(w, (hA << 4) + jj);
            float wB = __shfl(w, (hB << 4) + jj);
            const float* hp = h1 + (size_t)s * C1;
            acc0 = fmaf(wA, hp[lane],      acc0);
            acc1 = fmaf(wB, hp[64 + lane], acc1);
        }
    }
    #pragma unroll
    for (int off = 1; off <= 8; off <<= 1) den += __shfl_xor(den, off);
    float dA = __shfl(den, hA << 4);
    float dB = __shfl(den, hB << 4);
    float v0 = acc0 / dA + b1[lane];
    float v1 = acc1 / dB + b1[64 + lane];
    hr[(size_t)n * C1 + lane]      = v0 > 0.f ? v0 : 0.f;
    hr[(size_t)n * C1 + 64 + lane] = v1 > 0.f ? v1 : 0.f;
}

// ============ GEMM2: h2 = hr @ W2 (+ scores), 128x64 tile ============
// 256 threads: 16(tr) x 16(tc); micro-tile 8 rows x 4 cols.
__global__ __launch_bounds__(256, 1) void k5_gemm2(const float* __restrict__ B,
    const float* __restrict__ W2, const float* __restrict__ a_src,
    const float* __restrict__ a_dst, float* __restrict__ h2,
    float* __restrict__ ssrc, float* __restrict__ sdst) {
    __shared__ float xs[128][129];  // 66 KB
    __shared__ float Wl[128 * 64];  // 32 KB, Wl[k*64+c]
    int t = threadIdx.x;
    int rbase = blockIdx.x * 128;
    for (int i = t; i < 128 * 64; i += 256) Wl[i] = W2[i];
    for (int i = t; i < 128 * 128; i += 256) {
        int r = i >> 7, k = i & 127;
        int row = rbase + r; if (row >= NN) row = NN - 1;
        xs[r][k] = B[(size_t)row * 128 + k];
    }
    __syncthreads();
    int tc = t & 15, tr = t >> 4;
    int r0 = tr * 8, c0 = tc * 4;
    float acc[8][4];
    #pragma unroll
    for (int i = 0; i < 8; ++i)
        #pragma unroll
        for (int j = 0; j < 4; ++j) acc[i][j] = 0.f;
    for (int k = 0; k < 128; ++k) {
        float xv[8], wv[4];
        #pragma unroll
        for (int i = 0; i < 8; ++i) xv[i] = xs[r0 + i][k];
        #pragma unroll
        for (int j = 0; j < 4; ++j) wv[j] = Wl[k * 64 + c0 + j];
        #pragma unroll
        for (int i = 0; i < 8; ++i)
            #pragma unroll
            for (int j = 0; j < 4; ++j) acc[i][j] = fmaf(xv[i], wv[j], acc[i][j]);
    }
    float asv[4], adv[4];
    #pragma unroll
    for (int j = 0; j < 4; ++j) { asv[j] = a_src[c0 + j]; adv[j] = a_dst[c0 + j]; }
    #pragma unroll
    for (int i = 0; i < 8; ++i) {
        int row = rbase + r0 + i;
        bool ok = row < NN;
        if (ok) {
            *(float4*)(h2 + (size_t)row * 64 + c0) =
                make_float4(acc[i][0], acc[i][1], acc[i][2], acc[i][3]);
        }
        float ps = 0.f, pd = 0.f;
        #pragma unroll
        for (int j = 0; j < 4; ++j) {
            ps = fmaf(acc[i][j], asv[j], ps);
            pd = fmaf(acc[i][j], adv[j], pd);
        }
        #pragma unroll
        for (int off = 1; off <= 8; off <<= 1) {
            ps += __shfl_xor(ps, off); pd += __shfl_xor(pd, off);
        }
        if (tc == 0 && ok) { ssrc[row] = ps; sdst[row] = pd; }
    }
}

// ====== Aggregation layer 2: one wave per dst node, 64 channels ======
__global__ __launch_bounds__(256) void agg2(const int* __restrict__ rowstart,
    const int* __restrict__ eidx, const float* __restrict__ ssrc,
    const float* __restrict__ sdst, const float* __restrict__ h2,
    const float* __restrict__ b2, float* __restrict__ out) {
    int lane = threadIdx.x & 63;
    int n = blockIdx.x * 4 + (threadIdx.x >> 6);
    if (n >= NN) return;
    int r0 = rowstart[n], deg = rowstart[n + 1] - r0;
    float sd = sdst[n];
    float mx = -FLT_MAX;
    for (int base = 0; base < deg; base += 64) {
        int j = base + lane;
        if (j < deg) {
            int s = eidx[r0 + j];
            mx = fmaxf(mx, lrelu(ssrc[s] + sd));
        }
    }
    #pragma unroll
    for (int off = 1; off <= 32; off <<= 1) mx = fmaxf(mx, __shfl_xor(mx, off));
    float acc = 0.f, den = 0.f;
    for (int base = 0; base < deg; base += 64) {
        int j = base + lane;
        int sreg = 0; float w = 0.f;
        if (j < deg) {
            sreg = eidx[r0 + j];
            w = __expf(lrelu(ssrc[sreg] + sd) - mx);
        }
        den += w;
        int lim = deg - base; if (lim > 64) lim = 64;
        for (int jj = 0; jj < lim; ++jj) {
            int s = __shfl(sreg, jj);
            float wj = __shfl(w, jj);
            acc = fmaf(wj, h2[(size_t)s * C2 + lane], acc);
        }
    }
    #pragma unroll
    for (int off = 1; off <= 32; off <<= 1) den += __shfl_xor(den, off);
    out[(size_t)n * C2 + lane] = acc / den + b2[lane];
}

// ================= FC + log_softmax (in place on d_out) =================
__global__ __launch_bounds__(256) void k8_final(const float* __restrict__ fcW,
    const float* __restrict__ fcb, float* __restrict__ out) {
    __shared__ float Wl[C2 * C2];    // 16 KB
    int t = threadIdx.x;
    for (int i = t; i < C2 * C2; i += 256) Wl[i] = fcW[i];
    __syncthreads();
    int lane = t & 63, wid = t >> 6;
    int wg = blockIdx.x * 4 + wid, nw = gridDim.x * 4;
    float fbv = fcb[lane];
    for (int n = wg; n < NN; n += nw) {
        float val = out[(size_t)n * C2 + lane];
        float y = fbv;
        #pragma unroll
        for (int cc = 0; cc < C2; ++cc) {
            y = fmaf(__shfl(val, cc), Wl[cc * C2 + lane], y);
        }
        float m = y;
        #pragma unroll
        for (int off = 32; off >= 1; off >>= 1) m = fmaxf(m, __shfl_xor(m, off));
        float sv = __expf(y - m);
        #pragma unroll
        for (int off = 32; off >= 1; off >>= 1) sv += __shfl_xor(sv, off);
        out[(size_t)n * C2 + lane] = y - m - logf(sv);
    }
}

extern "C" void kernel_launch(void* const* d_in, const int* in_sizes, int n_in,
                              void* d_out, int out_size, void* d_ws, size_t ws_size,
                              hipStream_t stream) {
    const float* x   = (const float*)d_in[0];
    const int*   ei  = (const int*)d_in[1];
    const float* W1  = (const float*)d_in[2];
    const float* as1 = (const float*)d_in[3];
    const float* ad1 = (const float*)d_in[4];
    const float* b1  = (const float*)d_in[5];
    const float* W2  = (const float*)d_in[6];
    const float* as2 = (const float*)d_in[7];
    const float* ad2 = (const float*)d_in[8];
    const float* b2  = (const float*)d_in[9];
    const float* fcW = (const float*)d_in[10];
    const float* fcb = (const float*)d_in[11];
    float* out = (float*)d_out;

    float* ws = (float*)d_ws;
    size_t o = 0;
    float* h1    = ws + o; o += (size_t)NN * C1;   // 12.8M (reused as h2)
    float* hr1   = ws + o; o += (size_t)NN * C1;   // 12.8M
    float* ssrc1 = ws + o; o += (size_t)NN * 4;
    float* sdst1 = ws + o; o += (size_t)NN * 4;
    float* ssrc2 = ws + o; o += NN;
    float* sdst2 = ws + o; o += NN;
    int* ip = (int*)(ws + o);
    int* cnt      = ip; ip += NN;
    int* pscan    = ip; ip += NN;
    int* bsum     = ip; ip += 512;
    int* boff     = ip; ip += 512;
    int* rowstart = ip; ip += NN + 2;
    int* cursor   = ip; ip += NN;
    int* eidx     = ip; ip += TE;
    float* h2 = h1;

    const int* esrc = ei;
    const int* edst = ei + EE;

    hipMemsetAsync(cnt, 0, (size_t)NN * sizeof(int), stream);

    // CSR build
    kc_count<<<(TE + 255) / 256, 256, 0, stream>>>(edst, cnt);
    kc_scan1<<<NBLK, 256, 0, stream>>>(cnt, pscan, bsum);
    kc_scan2<<<1, 512, 0, stream>>>(bsum, boff);
    kc_scan3<<<NBLK, 256, 0, stream>>>(pscan, boff, rowstart, cursor);
    kc_fill<<<(TE + 255) / 256, 256, 0, stream>>>(esrc, edst, cursor, eidx);

    // layer 1
    k1_gemm1<<<NB1, 256, 0, stream>>>(x, W1, as1, ad1, h1, ssrc1, sdst1);
    agg1<<<(NN + 3) / 4, 256, 0, stream>>>(rowstart, eidx, ssrc1, sdst1, h1, b1, hr1);
    // layer 2
    k5_gemm2<<<NB1, 256, 0, stream>>>(hr1, W2, as2, ad2, h2, ssrc2, sdst2);
    agg2<<<(NN + 3) / 4, 256, 0, stream>>>(rowstart, eidx, ssrc2, sdst2, h2, b2, out);
    // FC + log_softmax
    k8_final<<<1024, 256, 0, stream>>>(fcW, fcb, out);
}

// Round 4
// 529.719 us; speedup vs baseline: 3.1908x; 1.0608x over previous
//
#include <hip/hip_runtime.h>
#include <hip/hip_bf16.h>
#include <cfloat>

#define NN 100000
#define EE 1000000
#define TE (EE + NN)   // edges incl. self loops
#define C1 128         // HEADS*HID
#define C2 64
#define NBLK 391       // ceil(NN/256)
#define NB1 782        // ceil(NN/128)

typedef unsigned short u16;
typedef unsigned int u32;

__device__ __forceinline__ float lrelu(float v) { return v > 0.f ? v : 0.2f * v; }
__device__ __forceinline__ u16 f2bf(float f) {           // RNE f32 -> bf16 bits
    u32 b = __float_as_uint(f);
    b += 0x7fffu + ((b >> 16) & 1u);
    return (u16)(b >> 16);
}
__device__ __forceinline__ float bflo(u32 p) { return __uint_as_float(p << 16); }
__device__ __forceinline__ float bfhi(u32 p) { return __uint_as_float(p & 0xffff0000u); }
__device__ __forceinline__ float b2f(u16 u)  { return __uint_as_float((u32)u << 16); }

// ================= CSR build (counting sort by dst) =================
__global__ __launch_bounds__(256) void kc_count(const int* __restrict__ edst,
                                                int* __restrict__ cnt) {
    int e = blockIdx.x * 256 + threadIdx.x;
    if (e >= TE) return;
    int d = e < EE ? edst[e] : e - EE;
    atomicAdd(cnt + d, 1);
}

__global__ __launch_bounds__(256) void kc_scan1(const int* __restrict__ cnt,
                                                int* __restrict__ pscan,
                                                int* __restrict__ bsum) {
    __shared__ int sm[256];
    int tid = threadIdx.x;
    int i = blockIdx.x * 256 + tid;
    int v = (i < NN) ? cnt[i] : 0;
    sm[tid] = v;
    __syncthreads();
    for (int off = 1; off < 256; off <<= 1) {
        int o = 0;
        if (tid >= off) o = sm[tid - off];
        __syncthreads();
        if (tid >= off) sm[tid] += o;
        __syncthreads();
    }
    if (i < NN) pscan[i] = sm[tid] - v;
    if (tid == 255) bsum[blockIdx.x] = sm[255];
}

__global__ __launch_bounds__(512) void kc_scan2(const int* __restrict__ bsum,
                                                int* __restrict__ boff) {
    __shared__ int sm[512];
    int tid = threadIdx.x;
    int v = (tid < NBLK) ? bsum[tid] : 0;
    sm[tid] = v;
    __syncthreads();
    for (int off = 1; off < 512; off <<= 1) {
        int o = 0;
        if (tid >= off) o = sm[tid - off];
        __syncthreads();
        if (tid >= off) sm[tid] += o;
        __syncthreads();
    }
    if (tid < NBLK) boff[tid] = sm[tid] - v;
}

__global__ __launch_bounds__(256) void kc_scan3(const int* __restrict__ pscan,
                                                const int* __restrict__ boff,
                                                int* __restrict__ rowstart,
                                                int* __restrict__ cursor) {
    int i = blockIdx.x * 256 + threadIdx.x;
    if (i >= NN) return;
    int rs = pscan[i] + boff[blockIdx.x];
    rowstart[i] = rs;
    cursor[i] = rs;
    if (i == 0) rowstart[NN] = TE;
}

__global__ __launch_bounds__(256) void kc_fill(const int* __restrict__ esrc,
                                               const int* __restrict__ edst,
                                               int* __restrict__ cursor,
                                               int* __restrict__ eidx) {
    int e = blockIdx.x * 256 + threadIdx.x;
    if (e >= TE) return;
    int s = e < EE ? esrc[e] : e - EE;
    int d = e < EE ? edst[e] : e - EE;
    int pos = atomicAdd(cursor + d, 1);
    eidx[pos] = s;
}

// ============ GEMM1: h1 = x @ W1 (+ scores), 128x128 tile, 512 thr ============
// thread grid 32(tr) x 16(tc); micro-tile 4 rows x (4+4) cols. h1 stored bf16.
__global__ __launch_bounds__(512, 1) void k1_gemm1(const float* __restrict__ x,
    const float* __restrict__ W1, const float* __restrict__ a_src,
    const float* __restrict__ a_dst, u16* __restrict__ h1b,
    float* __restrict__ ssrc, float* __restrict__ sdst) {
    __shared__ float xs[128][129];   // 66 KB, bank (r+k)%32
    __shared__ float Wl[128 * 128];  // 64 KB
    int t = threadIdx.x;
    int rbase = blockIdx.x * 128;
    for (int i = t; i < 128 * 128; i += 512) Wl[i] = W1[i];
    for (int i = t; i < 128 * 128; i += 512) {
        int r = i >> 7, k = i & 127;
        int row = rbase + r; if (row >= NN) row = NN - 1;
        xs[r][k] = x[(size_t)row * 128 + k];
    }
    __syncthreads();
    int tc = t & 15, tr = t >> 4;
    int r0 = tr * 4, cA = tc * 4, cB = 64 + tc * 4;
    float acc[4][8];
    #pragma unroll
    for (int i = 0; i < 4; ++i)
        #pragma unroll
        for (int j = 0; j < 8; ++j) acc[i][j] = 0.f;
    for (int k = 0; k < 128; ++k) {
        float xv[4], wv[8];
        #pragma unroll
        for (int i = 0; i < 4; ++i) xv[i] = xs[r0 + i][k];
        #pragma unroll
        for (int j = 0; j < 4; ++j) wv[j] = Wl[k * 128 + cA + j];
        #pragma unroll
        for (int j = 0; j < 4; ++j) wv[4 + j] = Wl[k * 128 + cB + j];
        #pragma unroll
        for (int i = 0; i < 4; ++i)
            #pragma unroll
            for (int j = 0; j < 8; ++j) acc[i][j] = fmaf(xv[i], wv[j], acc[i][j]);
    }
    float asv[8], adv[8];
    #pragma unroll
    for (int j = 0; j < 4; ++j) {
        asv[j] = a_src[cA + j];     adv[j] = a_dst[cA + j];
        asv[4 + j] = a_src[cB + j]; adv[4 + j] = a_dst[cB + j];
    }
    #pragma unroll
    for (int i = 0; i < 4; ++i) {
        int row = rbase + r0 + i;
        bool ok = row < NN;
        if (ok) {
            *(ushort4*)(h1b + (size_t)row * 128 + cA) = make_ushort4(
                f2bf(acc[i][0]), f2bf(acc[i][1]), f2bf(acc[i][2]), f2bf(acc[i][3]));
            *(ushort4*)(h1b + (size_t)row * 128 + cB) = make_ushort4(
                f2bf(acc[i][4]), f2bf(acc[i][5]), f2bf(acc[i][6]), f2bf(acc[i][7]));
        }
        float psA = 0.f, pdA = 0.f, psB = 0.f, pdB = 0.f;
        #pragma unroll
        for (int j = 0; j < 4; ++j) {
            psA = fmaf(acc[i][j], asv[j], psA);
            pdA = fmaf(acc[i][j], adv[j], pdA);
            psB = fmaf(acc[i][4 + j], asv[4 + j], psB);
            pdB = fmaf(acc[i][4 + j], adv[4 + j], pdB);
        }
        #pragma unroll
        for (int off = 1; off <= 4; off <<= 1) {
            psA += __shfl_xor(psA, off); pdA += __shfl_xor(pdA, off);
            psB += __shfl_xor(psB, off); pdB += __shfl_xor(pdB, off);
        }
        if ((tc & 7) == 0 && ok) {
            int hA = tc >> 3;
            ssrc[row * 4 + hA] = psA;     sdst[row * 4 + hA] = pdA;
            ssrc[row * 4 + 2 + hA] = psB; sdst[row * 4 + 2 + hA] = pdB;
        }
    }
}

// ====== Aggregation layer 1: one wave per dst node, bf16 h1 gathers ======
// lane covers channels {2*lane, 2*lane+1}; channel head == score-duty head (lane>>4)
__global__ __launch_bounds__(256) void agg1(const int* __restrict__ rowstart,
    const int* __restrict__ eidx, const float* __restrict__ ssrc,
    const float* __restrict__ sdst, const u16* __restrict__ h1b,
    const float* __restrict__ b1, float* __restrict__ hr) {
    int lane = threadIdx.x & 63;
    int n = blockIdx.x * 4 + (threadIdx.x >> 6);
    if (n >= NN) return;
    int r0 = rowstart[n], deg = rowstart[n + 1] - r0;
    int h4 = lane >> 4, j16 = lane & 15;
    float sd = sdst[n * 4 + h4];
    float mx = -FLT_MAX;
    for (int base = 0; base < deg; base += 16) {
        int j = base + j16;
        if (j < deg) {
            int s = eidx[r0 + j];
            mx = fmaxf(mx, lrelu(ssrc[s * 4 + h4] + sd));
        }
    }
    #pragma unroll
    for (int off = 1; off <= 8; off <<= 1) mx = fmaxf(mx, __shfl_xor(mx, off));
    float acc0 = 0.f, acc1 = 0.f, den = 0.f;
    for (int base = 0; base < deg; base += 16) {
        int j = base + j16;
        int sreg = 0; float w = 0.f;
        if (j < deg) {
            sreg = eidx[r0 + j];
            w = __expf(lrelu(ssrc[sreg * 4 + h4] + sd) - mx);
        }
        den += w;
        int lim = deg - base; if (lim > 16) lim = 16;
        for (int jj = 0; jj < lim; ++jj) {
            int s    = __shfl(sreg, jj);
            float wA = __shfl(w, (lane & 48) + jj);
            u32 pv = *(const u32*)(h1b + (size_t)s * C1 + 2 * lane);
            acc0 = fmaf(wA, bflo(pv), acc0);
            acc1 = fmaf(wA, bfhi(pv), acc1);
        }
    }
    #pragma unroll
    for (int off = 1; off <= 8; off <<= 1) den += __shfl_xor(den, off);
    float v0 = acc0 / den + b1[2 * lane];
    float v1 = acc1 / den + b1[2 * lane + 1];
    float2 o2 = make_float2(v0 > 0.f ? v0 : 0.f, v1 > 0.f ? v1 : 0.f);
    *(float2*)(hr + (size_t)n * C1 + 2 * lane) = o2;
}

// ============ GEMM2: h2 = hr @ W2 (+ scores), 128x64 tile, 512 thr ============
__global__ __launch_bounds__(512, 1) void k5_gemm2(const float* __restrict__ B,
    const float* __restrict__ W2, const float* __restrict__ a_src,
    const float* __restrict__ a_dst, u16* __restrict__ h2b,
    float* __restrict__ ssrc, float* __restrict__ sdst) {
    __shared__ float xs[128][129];  // 66 KB
    __shared__ float Wl[128 * 64];  // 32 KB
    int t = threadIdx.x;
    int rbase = blockIdx.x * 128;
    for (int i = t; i < 128 * 64; i += 512) Wl[i] = W2[i];
    for (int i = t; i < 128 * 128; i += 512) {
        int r = i >> 7, k = i & 127;
        int row = rbase + r; if (row >= NN) row = NN - 1;
        xs[r][k] = B[(size_t)row * 128 + k];
    }
    __syncthreads();
    int tc = t & 15, tr = t >> 4;
    int r0 = tr * 4, c0 = tc * 4;
    float acc[4][4];
    #pragma unroll
    for (int i = 0; i < 4; ++i)
        #pragma unroll
        for (int j = 0; j < 4; ++j) acc[i][j] = 0.f;
    for (int k = 0; k < 128; ++k) {
        float xv[4], wv[4];
        #pragma unroll
        for (int i = 0; i < 4; ++i) xv[i] = xs[r0 + i][k];
        #pragma unroll
        for (int j = 0; j < 4; ++j) wv[j] = Wl[k * 64 + c0 + j];
        #pragma unroll
        for (int i = 0; i < 4; ++i)
            #pragma unroll
            for (int j = 0; j < 4; ++j) acc[i][j] = fmaf(xv[i], wv[j], acc[i][j]);
    }
    float asv[4], adv[4];
    #pragma unroll
    for (int j = 0; j < 4; ++j) { asv[j] = a_src[c0 + j]; adv[j] = a_dst[c0 + j]; }
    #pragma unroll
    for (int i = 0; i < 4; ++i) {
        int row = rbase + r0 + i;
        bool ok = row < NN;
        if (ok) {
            *(ushort4*)(h2b + (size_t)row * 64 + c0) = make_ushort4(
                f2bf(acc[i][0]), f2bf(acc[i][1]), f2bf(acc[i][2]), f2bf(acc[i][3]));
        }
        float ps = 0.f, pd = 0.f;
        #pragma unroll
        for (int j = 0; j < 4; ++j) {
            ps = fmaf(acc[i][j], asv[j], ps);
            pd = fmaf(acc[i][j], adv[j], pd);
        }
        #pragma unroll
        for (int off = 1; off <= 8; off <<= 1) {
            ps += __shfl_xor(ps, off); pd += __shfl_xor(pd, off);
        }
        if (tc == 0 && ok) { ssrc[row] = ps; sdst[row] = pd; }
    }
}

// ====== Aggregation layer 2: one wave per dst node, bf16 h2 gathers ======
__global__ __launch_bounds__(256) void agg2(const int* __restrict__ rowstart,
    const int* __restrict__ eidx, const float* __restrict__ ssrc,
    const float* __restrict__ sdst, const u16* __restrict__ h2b,
    const float* __restrict__ b2, float* __restrict__ out) {
    int lane = threadIdx.x & 63;
    int n = blockIdx.x * 4 + (threadIdx.x >> 6);
    if (n >= NN) return;
    int r0 = rowstart[n], deg = rowstart[n + 1] - r0;
    float sd = sdst[n];
    float mx = -FLT_MAX;
    for (int base = 0; base < deg; base += 64) {
        int j = base + lane;
        if (j < deg) {
            int s = eidx[r0 + j];
            mx = fmaxf(mx, lrelu(ssrc[s] + sd));
        }
    }
    #pragma unroll
    for (int off = 1; off <= 32; off <<= 1) mx = fmaxf(mx, __shfl_xor(mx, off));
    float acc = 0.f, den = 0.f;
    for (int base = 0; base < deg; base += 64) {
        int j = base + lane;
        int sreg = 0; float w = 0.f;
        if (j < deg) {
            sreg = eidx[r0 + j];
            w = __expf(lrelu(ssrc[sreg] + sd) - mx);
        }
        den += w;
        int lim = deg - base; if (lim > 64) lim = 64;
        for (int jj = 0; jj < lim; ++jj) {
            int s = __shfl(sreg, jj);
            float wj = __shfl(w, jj);
            acc = fmaf(wj, b2f(h2b[(size_t)s * C2 + lane]), acc);
        }
    }
    #pragma unroll
    for (int off = 1; off <= 32; off <<= 1) den += __shfl_xor(den, off);
    out[(size_t)n * C2 + lane] = acc / den + b2[lane];
}

// ================= FC + log_softmax (in place on d_out) =================
__global__ __launch_bounds__(256) void k8_final(const float* __restrict__ fcW,
    const float* __restrict__ fcb, float* __restrict__ out) {
    __shared__ float Wl[C2 * C2];
    int t = threadIdx.x;
    for (int i = t; i < C2 * C2; i += 256) Wl[i] = fcW[i];
    __syncthreads();
    int lane = t & 63, wid = t >> 6;
    int wg = blockIdx.x * 4 + wid, nw = gridDim.x * 4;
    float fbv = fcb[lane];
    for (int n = wg; n < NN; n += nw) {
        float val = out[(size_t)n * C2 + lane];
        float y = fbv;
        #pragma unroll
        for (int cc = 0; cc < C2; ++cc) {
            y = fmaf(__shfl(val, cc), Wl[cc * C2 + lane], y);
        }
        float m = y;
        #pragma unroll
        for (int off = 32; off >= 1; off >>= 1) m = fmaxf(m, __shfl_xor(m, off));
        float sv = __expf(y - m);
        #pragma unroll
        for (int off = 32; off >= 1; off >>= 1) sv += __shfl_xor(sv, off);
        out[(size_t)n * C2 + lane] = y - m - logf(sv);
    }
}

extern "C" void kernel_launch(void* const* d_in, const int* in_sizes, int n_in,
                              void* d_out, int out_size, void* d_ws, size_t ws_size,
                              hipStream_t stream) {
    const float* x   = (const float*)d_in[0];
    const int*   ei  = (const int*)d_in[1];
    const float* W1  = (const float*)d_in[2];
    const float* as1 = (const float*)d_in[3];
    const float* ad1 = (const float*)d_in[4];
    const float* b1  = (const float*)d_in[5];
    const float* W2  = (const float*)d_in[6];
    const float* as2 = (const float*)d_in[7];
    const float* ad2 = (const float*)d_in[8];
    const float* b2  = (const float*)d_in[9];
    const float* fcW = (const float*)d_in[10];
    const float* fcb = (const float*)d_in[11];
    float* out = (float*)d_out;

    float* ws = (float*)d_ws;
    size_t o = 0;
    u16* h1b   = (u16*)(ws + o); o += (size_t)NN * C1 / 2;  // bf16 [NN][128] (reused as h2b)
    float* hr1   = ws + o; o += (size_t)NN * C1;            // fp32 [NN][128]
    float* ssrc1 = ws + o; o += (size_t)NN * 4;
    float* sdst1 = ws + o; o += (size_t)NN * 4;
    float* ssrc2 = ws + o; o += NN;
    float* sdst2 = ws + o; o += NN;
    int* ip = (int*)(ws + o);
    int* cnt      = ip; ip += NN;
    int* pscan    = ip; ip += NN;
    int* bsum     = ip; ip += 512;
    int* boff     = ip; ip += 512;
    int* rowstart = ip; ip += NN + 2;
    int* cursor   = ip; ip += NN;
    int* eidx     = ip; ip += TE;
    u16* h2b = h1b;   // h1b dead after agg1; reuse for h2

    const int* esrc = ei;
    const int* edst = ei + EE;

    hipMemsetAsync(cnt, 0, (size_t)NN * sizeof(int), stream);

    // CSR build
    kc_count<<<(TE + 255) / 256, 256, 0, stream>>>(edst, cnt);
    kc_scan1<<<NBLK, 256, 0, stream>>>(cnt, pscan, bsum);
    kc_scan2<<<1, 512, 0, stream>>>(bsum, boff);
    kc_scan3<<<NBLK, 256, 0, stream>>>(pscan, boff, rowstart, cursor);
    kc_fill<<<(TE + 255) / 256, 256, 0, stream>>>(esrc, edst, cursor, eidx);

    // layer 1
    k1_gemm1<<<NB1, 512, 0, stream>>>(x, W1, as1, ad1, h1b, ssrc1, sdst1);
    agg1<<<(NN + 3) / 4, 256, 0, stream>>>(rowstart, eidx, ssrc1, sdst1, h1b, b1, hr1);
    // layer 2
    k5_gemm2<<<NB1, 512, 0, stream>>>(hr1, W2, as2, ad2, h2b, ssrc2, sdst2);
    agg2<<<(NN + 3) / 4, 256, 0, stream>>>(rowstart, eidx, ssrc2, sdst2, h2b, b2, out);
    // FC + log_softmax
    k8_final<<<1024, 256, 0, stream>>>(fcW, fcb, out);
}

// Round 5
// 467.795 us; speedup vs baseline: 3.6131x; 1.1324x over previous
//
#include <hip/hip_runtime.h>
#include <hip/hip_bf16.h>
#include <cfloat>

#define NN 100000
#define EE 1000000
#define TE (EE + NN)   // edges incl. self loops
#define C1 128         // HEADS*HID
#define C2 64
#define NBLK 391       // ceil(NN/256)
#define NB1 782        // ceil(NN/128)

typedef unsigned short u16;
typedef unsigned int u32;

__device__ __forceinline__ float lrelu(float v) { return v > 0.f ? v : 0.2f * v; }
__device__ __forceinline__ u16 f2bf(float f) {           // RNE f32 -> bf16 bits
    u32 b = __float_as_uint(f);
    b += 0x7fffu + ((b >> 16) & 1u);
    return (u16)(b >> 16);
}
__device__ __forceinline__ float bflo(u32 p) { return __uint_as_float(p << 16); }
__device__ __forceinline__ float bfhi(u32 p) { return __uint_as_float(p & 0xffff0000u); }

// ================= CSR build (counting sort by dst) =================
__global__ __launch_bounds__(256) void kc_count(const int* __restrict__ edst,
                                                int* __restrict__ cnt) {
    int e = blockIdx.x * 256 + threadIdx.x;
    if (e >= TE) return;
    int d = e < EE ? edst[e] : e - EE;
    atomicAdd(cnt + d, 1);
}

__global__ __launch_bounds__(256) void kc_scan1(const int* __restrict__ cnt,
                                                int* __restrict__ pscan,
                                                int* __restrict__ bsum) {
    __shared__ int sm[256];
    int tid = threadIdx.x;
    int i = blockIdx.x * 256 + tid;
    int v = (i < NN) ? cnt[i] : 0;
    sm[tid] = v;
    __syncthreads();
    for (int off = 1; off < 256; off <<= 1) {
        int o = 0;
        if (tid >= off) o = sm[tid - off];
        __syncthreads();
        if (tid >= off) sm[tid] += o;
        __syncthreads();
    }
    if (i < NN) pscan[i] = sm[tid] - v;
    if (tid == 255) bsum[blockIdx.x] = sm[255];
}

__global__ __launch_bounds__(512) void kc_scan2(const int* __restrict__ bsum,
                                                int* __restrict__ boff) {
    __shared__ int sm[512];
    int tid = threadIdx.x;
    int v = (tid < NBLK) ? bsum[tid] : 0;
    sm[tid] = v;
    __syncthreads();
    for (int off = 1; off < 512; off <<= 1) {
        int o = 0;
        if (tid >= off) o = sm[tid - off];
        __syncthreads();
        if (tid >= off) sm[tid] += o;
        __syncthreads();
    }
    if (tid < NBLK) boff[tid] = sm[tid] - v;
}

__global__ __launch_bounds__(256) void kc_scan3(const int* __restrict__ pscan,
                                                const int* __restrict__ boff,
                                                int* __restrict__ rowstart,
                                                int* __restrict__ cursor) {
    int i = blockIdx.x * 256 + threadIdx.x;
    if (i >= NN) return;
    int rs = pscan[i] + boff[blockIdx.x];
    rowstart[i] = rs;
    cursor[i] = rs;
    if (i == 0) rowstart[NN] = TE;
}

__global__ __launch_bounds__(256) void kc_fill(const int* __restrict__ esrc,
                                               const int* __restrict__ edst,
                                               int* __restrict__ cursor,
                                               int* __restrict__ eidx) {
    int e = blockIdx.x * 256 + threadIdx.x;
    if (e >= TE) return;
    int s = e < EE ? esrc[e] : e - EE;
    int d = e < EE ? edst[e] : e - EE;
    int pos = atomicAdd(cursor + d, 1);
    eidx[pos] = s;
}

// ============ GEMM1: h1 = x @ W1 (+ scores), 128x128 tile, 512 thr ============
__global__ __launch_bounds__(512, 1) void k1_gemm1(const float* __restrict__ x,
    const float* __restrict__ W1, const float* __restrict__ a_src,
    const float* __restrict__ a_dst, u16* __restrict__ h1b,
    float* __restrict__ ssrc, float* __restrict__ sdst) {
    __shared__ float xs[128][129];   // 66 KB, bank (r+k)%32
    __shared__ float Wl[128 * 128];  // 64 KB
    int t = threadIdx.x;
    int rbase = blockIdx.x * 128;
    for (int i = t; i < 128 * 128; i += 512) Wl[i] = W1[i];
    for (int i = t; i < 128 * 128; i += 512) {
        int r = i >> 7, k = i & 127;
        int row = rbase + r; if (row >= NN) row = NN - 1;
        xs[r][k] = x[(size_t)row * 128 + k];
    }
    __syncthreads();
    int tc = t & 15, tr = t >> 4;
    int r0 = tr * 4, cA = tc * 4, cB = 64 + tc * 4;
    float acc[4][8];
    #pragma unroll
    for (int i = 0; i < 4; ++i)
        #pragma unroll
        for (int j = 0; j < 8; ++j) acc[i][j] = 0.f;
    for (int k = 0; k < 128; ++k) {
        float xv[4], wv[8];
        #pragma unroll
        for (int i = 0; i < 4; ++i) xv[i] = xs[r0 + i][k];
        #pragma unroll
        for (int j = 0; j < 4; ++j) wv[j] = Wl[k * 128 + cA + j];
        #pragma unroll
        for (int j = 0; j < 4; ++j) wv[4 + j] = Wl[k * 128 + cB + j];
        #pragma unroll
        for (int i = 0; i < 4; ++i)
            #pragma unroll
            for (int j = 0; j < 8; ++j) acc[i][j] = fmaf(xv[i], wv[j], acc[i][j]);
    }
    float asv[8], adv[8];
    #pragma unroll
    for (int j = 0; j < 4; ++j) {
        asv[j] = a_src[cA + j];     adv[j] = a_dst[cA + j];
        asv[4 + j] = a_src[cB + j]; adv[4 + j] = a_dst[cB + j];
    }
    #pragma unroll
    for (int i = 0; i < 4; ++i) {
        int row = rbase + r0 + i;
        bool ok = row < NN;
        if (ok) {
            *(ushort4*)(h1b + (size_t)row * 128 + cA) = make_ushort4(
                f2bf(acc[i][0]), f2bf(acc[i][1]), f2bf(acc[i][2]), f2bf(acc[i][3]));
            *(ushort4*)(h1b + (size_t)row * 128 + cB) = make_ushort4(
                f2bf(acc[i][4]), f2bf(acc[i][5]), f2bf(acc[i][6]), f2bf(acc[i][7]));
        }
        float psA = 0.f, pdA = 0.f, psB = 0.f, pdB = 0.f;
        #pragma unroll
        for (int j = 0; j < 4; ++j) {
            psA = fmaf(acc[i][j], asv[j], psA);
            pdA = fmaf(acc[i][j], adv[j], pdA);
            psB = fmaf(acc[i][4 + j], asv[4 + j], psB);
            pdB = fmaf(acc[i][4 + j], adv[4 + j], pdB);
        }
        #pragma unroll
        for (int off = 1; off <= 4; off <<= 1) {
            psA += __shfl_xor(psA, off); pdA += __shfl_xor(pdA, off);
            psB += __shfl_xor(psB, off); pdB += __shfl_xor(pdB, off);
        }
        if ((tc & 7) == 0 && ok) {
            int hA = tc >> 3;
            ssrc[row * 4 + hA] = psA;     sdst[row * 4 + hA] = pdA;
            ssrc[row * 4 + 2 + hA] = psB; sdst[row * 4 + 2 + hA] = pdB;
        }
    }
}

// ====== Aggregation layer 1: one wave per dst node, batched bf16 gathers ======
// lane covers channels {2*lane, 2*lane+1}; head = lane>>4 matches score duty.
// Full 16-edge batches: padding lanes carry w=0, so their (cached) row-0 loads add 0.
__global__ __launch_bounds__(256) void agg1(const int* __restrict__ rowstart,
    const int* __restrict__ eidx, const float* __restrict__ ssrc,
    const float* __restrict__ sdst, const u16* __restrict__ h1b,
    const float* __restrict__ b1, float* __restrict__ hr) {
    int lane = threadIdx.x & 63;
    int n = blockIdx.x * 4 + (threadIdx.x >> 6);
    if (n >= NN) return;
    int r0 = rowstart[n], deg = rowstart[n + 1] - r0;
    int h4 = lane >> 4, j16 = lane & 15;
    float sd = sdst[n * 4 + h4];
    float mx = -FLT_MAX;
    for (int base = 0; base < deg; base += 16) {
        int j = base + j16;
        if (j < deg) {
            int s = eidx[r0 + j];
            mx = fmaxf(mx, lrelu(ssrc[s * 4 + h4] + sd));
        }
    }
    #pragma unroll
    for (int off = 1; off <= 8; off <<= 1) mx = fmaxf(mx, __shfl_xor(mx, off));
    float acc0 = 0.f, acc1 = 0.f, den = 0.f;
    for (int base = 0; base < deg; base += 16) {
        int j = base + j16;
        int sreg = 0; float w = 0.f;
        if (j < deg) {
            sreg = eidx[r0 + j];
            w = __expf(lrelu(ssrc[sreg * 4 + h4] + sd) - mx);
        }
        den += w;
        // phase 1: issue all 16 gathers (16 outstanding vmem loads)
        u32 pv[16];
        #pragma unroll
        for (int jj = 0; jj < 16; ++jj) {
            int s = __shfl(sreg, jj);
            pv[jj] = *(const u32*)(h1b + (size_t)s * C1 + 2 * lane);
        }
        // phase 2: weighted accumulate
        #pragma unroll
        for (int jj = 0; jj < 16; ++jj) {
            float wA = __shfl(w, (lane & 48) + jj);
            acc0 = fmaf(wA, bflo(pv[jj]), acc0);
            acc1 = fmaf(wA, bfhi(pv[jj]), acc1);
        }
    }
    #pragma unroll
    for (int off = 1; off <= 8; off <<= 1) den += __shfl_xor(den, off);
    float v0 = acc0 / den + b1[2 * lane];
    float v1 = acc1 / den + b1[2 * lane + 1];
    float2 o2 = make_float2(v0 > 0.f ? v0 : 0.f, v1 > 0.f ? v1 : 0.f);
    *(float2*)(hr + (size_t)n * C1 + 2 * lane) = o2;
}

// ============ GEMM2: h2 = hr @ W2 (+ scores), 128x64 tile, 512 thr ============
__global__ __launch_bounds__(512, 1) void k5_gemm2(const float* __restrict__ B,
    const float* __restrict__ W2, const float* __restrict__ a_src,
    const float* __restrict__ a_dst, u16* __restrict__ h2b,
    float* __restrict__ ssrc, float* __restrict__ sdst) {
    __shared__ float xs[128][129];  // 66 KB
    __shared__ float Wl[128 * 64];  // 32 KB
    int t = threadIdx.x;
    int rbase = blockIdx.x * 128;
    for (int i = t; i < 128 * 64; i += 512) Wl[i] = W2[i];
    for (int i = t; i < 128 * 128; i += 512) {
        int r = i >> 7, k = i & 127;
        int row = rbase + r; if (row >= NN) row = NN - 1;
        xs[r][k] = B[(size_t)row * 128 + k];
    }
    __syncthreads();
    int tc = t & 15, tr = t >> 4;
    int r0 = tr * 4, c0 = tc * 4;
    float acc[4][4];
    #pragma unroll
    for (int i = 0; i < 4; ++i)
        #pragma unroll
        for (int j = 0; j < 4; ++j) acc[i][j] = 0.f;
    for (int k = 0; k < 128; ++k) {
        float xv[4], wv[4];
        #pragma unroll
        for (int i = 0; i < 4; ++i) xv[i] = xs[r0 + i][k];
        #pragma unroll
        for (int j = 0; j < 4; ++j) wv[j] = Wl[k * 64 + c0 + j];
        #pragma unroll
        for (int i = 0; i < 4; ++i)
            #pragma unroll
            for (int j = 0; j < 4; ++j) acc[i][j] = fmaf(xv[i], wv[j], acc[i][j]);
    }
    float asv[4], adv[4];
    #pragma unroll
    for (int j = 0; j < 4; ++j) { asv[j] = a_src[c0 + j]; adv[j] = a_dst[c0 + j]; }
    #pragma unroll
    for (int i = 0; i < 4; ++i) {
        int row = rbase + r0 + i;
        bool ok = row < NN;
        if (ok) {
            *(ushort4*)(h2b + (size_t)row * 64 + c0) = make_ushort4(
                f2bf(acc[i][0]), f2bf(acc[i][1]), f2bf(acc[i][2]), f2bf(acc[i][3]));
        }
        float ps = 0.f, pd = 0.f;
        #pragma unroll
        for (int j = 0; j < 4; ++j) {
            ps = fmaf(acc[i][j], asv[j], ps);
            pd = fmaf(acc[i][j], adv[j], pd);
        }
        #pragma unroll
        for (int off = 1; off <= 8; off <<= 1) {
            ps += __shfl_xor(ps, off); pd += __shfl_xor(pd, off);
        }
        if (tc == 0 && ok) { ssrc[row] = ps; sdst[row] = pd; }
    }
}

// ====== Aggregation layer 2 + FC + log_softmax, fused (writes d_out) ======
// Gather: 2 edges per step, lanes 0-31 even edge / 32-63 odd edge, u32 = 2 channels.
__global__ __launch_bounds__(256) void agg2fc(const int* __restrict__ rowstart,
    const int* __restrict__ eidx, const float* __restrict__ ssrc,
    const float* __restrict__ sdst, const u16* __restrict__ h2b,
    const float* __restrict__ b2, const float* __restrict__ fcW,
    const float* __restrict__ fcb, float* __restrict__ out) {
    __shared__ float Wfc[C2 * C2];   // 16 KB
    for (int i = threadIdx.x; i < C2 * C2; i += 256) Wfc[i] = fcW[i];
    __syncthreads();
    int lane = threadIdx.x & 63;
    int n = blockIdx.x * 4 + (threadIdx.x >> 6);
    if (n >= NN) return;
    int r0 = rowstart[n], deg = rowstart[n + 1] - r0;
    int j16 = lane & 15, half = lane >> 5, c = lane & 31;
    float sd = sdst[n];
    float mx = -FLT_MAX;
    for (int base = 0; base < deg; base += 16) {
        int j = base + j16;
        if (j < deg) {
            int s = eidx[r0 + j];
            mx = fmaxf(mx, lrelu(ssrc[s] + sd));
        }
    }
    #pragma unroll
    for (int off = 1; off <= 8; off <<= 1) mx = fmaxf(mx, __shfl_xor(mx, off));
    float acc0 = 0.f, acc1 = 0.f, den = 0.f;
    for (int base = 0; base < deg; base += 16) {
        int j = base + j16;
        int sreg = 0; float w = 0.f;
        if (j < deg) {
            sreg = eidx[r0 + j];
            w = __expf(lrelu(ssrc[sreg] + sd) - mx);
        }
        den += w;
        u32 pv[8];
        #pragma unroll
        for (int q = 0; q < 8; ++q) {
            int s = __shfl(sreg, 2 * q + half);
            pv[q] = *(const u32*)(h2b + (size_t)s * C2 + 2 * c);
        }
        #pragma unroll
        for (int q = 0; q < 8; ++q) {
            float wq = __shfl(w, 2 * q + half);
            acc0 = fmaf(wq, bflo(pv[q]), acc0);
            acc1 = fmaf(wq, bfhi(pv[q]), acc1);
        }
    }
    #pragma unroll
    for (int off = 1; off <= 8; off <<= 1) den += __shfl_xor(den, off);
    acc0 += __shfl_xor(acc0, 32);          // combine even/odd edge halves
    acc1 += __shfl_xor(acc1, 32);
    float v0 = acc0 / den + b2[2 * c];     // channel 2c   (valid in all lanes)
    float v1 = acc1 / den + b2[2 * c + 1]; // channel 2c+1
    // redistribute to lane-per-channel: lane l holds channel l
    float e0 = __shfl(v0, lane >> 1), e1 = __shfl(v1, lane >> 1);
    float val = (lane & 1) ? e1 : e0;
    // FC
    float y = fcb[lane];
    #pragma unroll
    for (int cc = 0; cc < C2; ++cc)
        y = fmaf(__shfl(val, cc), Wfc[cc * C2 + lane], y);
    // log_softmax
    float m = y;
    #pragma unroll
    for (int off = 32; off >= 1; off >>= 1) m = fmaxf(m, __shfl_xor(m, off));
    float sv = __expf(y - m);
    #pragma unroll
    for (int off = 32; off >= 1; off >>= 1) sv += __shfl_xor(sv, off);
    out[(size_t)n * C2 + lane] = y - m - logf(sv);
}

extern "C" void kernel_launch(void* const* d_in, const int* in_sizes, int n_in,
                              void* d_out, int out_size, void* d_ws, size_t ws_size,
                              hipStream_t stream) {
    const float* x   = (const float*)d_in[0];
    const int*   ei  = (const int*)d_in[1];
    const float* W1  = (const float*)d_in[2];
    const float* as1 = (const float*)d_in[3];
    const float* ad1 = (const float*)d_in[4];
    const float* b1  = (const float*)d_in[5];
    const float* W2  = (const float*)d_in[6];
    const float* as2 = (const float*)d_in[7];
    const float* ad2 = (const float*)d_in[8];
    const float* b2  = (const float*)d_in[9];
    const float* fcW = (const float*)d_in[10];
    const float* fcb = (const float*)d_in[11];
    float* out = (float*)d_out;

    float* ws = (float*)d_ws;
    size_t o = 0;
    u16* h1b   = (u16*)(ws + o); o += (size_t)NN * C1 / 2;  // bf16 [NN][128] (reused as h2b)
    float* hr1   = ws + o; o += (size_t)NN * C1;            // fp32 [NN][128]
    float* ssrc1 = ws + o; o += (size_t)NN * 4;
    float* sdst1 = ws + o; o += (size_t)NN * 4;
    float* ssrc2 = ws + o; o += NN;
    float* sdst2 = ws + o; o += NN;
    int* ip = (int*)(ws + o);
    int* cnt      = ip; ip += NN;
    int* pscan    = ip; ip += NN;
    int* bsum     = ip; ip += 512;
    int* boff     = ip; ip += 512;
    int* rowstart = ip; ip += NN + 2;
    int* cursor   = ip; ip += NN;
    int* eidx     = ip; ip += TE;
    u16* h2b = h1b;   // h1b dead after agg1; reuse for h2

    const int* esrc = ei;
    const int* edst = ei + EE;

    hipMemsetAsync(cnt, 0, (size_t)NN * sizeof(int), stream);

    // CSR build
    kc_count<<<(TE + 255) / 256, 256, 0, stream>>>(edst, cnt);
    kc_scan1<<<NBLK, 256, 0, stream>>>(cnt, pscan, bsum);
    kc_scan2<<<1, 512, 0, stream>>>(bsum, boff);
    kc_scan3<<<NBLK, 256, 0, stream>>>(pscan, boff, rowstart, cursor);
    kc_fill<<<(TE + 255) / 256, 256, 0, stream>>>(esrc, edst, cursor, eidx);

    // layer 1
    k1_gemm1<<<NB1, 512, 0, stream>>>(x, W1, as1, ad1, h1b, ssrc1, sdst1);
    agg1<<<(NN + 3) / 4, 256, 0, stream>>>(rowstart, eidx, ssrc1, sdst1, h1b, b1, hr1);
    // layer 2
    k5_gemm2<<<NB1, 512, 0, stream>>>(hr1, W2, as2, ad2, h2b, ssrc2, sdst2);
    agg2fc<<<(NN + 3) / 4, 256, 0, stream>>>(rowstart, eidx, ssrc2, sdst2, h2b, b2,
                                             fcW, fcb, out);
}

// Round 6
// 413.760 us; speedup vs baseline: 4.0850x; 1.1306x over previous
//
#include <hip/hip_runtime.h>
#include <hip/hip_bf16.h>
#include <cfloat>

#define NN 100000
#define EE 1000000
#define TE (EE + NN)   // edges incl. self loops
#define C1 128         // HEADS*HID
#define C2 64
#define NBLK 391       // ceil(NN/256)
#define NB1 782        // ceil(NN/128)

typedef unsigned short u16;
typedef unsigned int u32;

__device__ __forceinline__ float lrelu(float v) { return v > 0.f ? v : 0.2f * v; }
__device__ __forceinline__ u16 f2bf(float f) {           // RNE f32 -> bf16 bits
    u32 b = __float_as_uint(f);
    b += 0x7fffu + ((b >> 16) & 1u);
    return (u16)(b >> 16);
}
__device__ __forceinline__ float bflo(u32 p) { return __uint_as_float(p << 16); }
__device__ __forceinline__ float bfhi(u32 p) { return __uint_as_float(p & 0xffff0000u); }

// ================= CSR build (counting sort by dst) =================
__global__ __launch_bounds__(256) void kc_count(const int* __restrict__ edst,
                                                int* __restrict__ cnt) {
    int e = blockIdx.x * 256 + threadIdx.x;
    if (e >= TE) return;
    int d = e < EE ? edst[e] : e - EE;
    atomicAdd(cnt + d, 1);
}

__global__ __launch_bounds__(256) void kc_scan1(const int* __restrict__ cnt,
                                                int* __restrict__ pscan,
                                                int* __restrict__ bsum) {
    __shared__ int sm[256];
    int tid = threadIdx.x;
    int i = blockIdx.x * 256 + tid;
    int v = (i < NN) ? cnt[i] : 0;
    sm[tid] = v;
    __syncthreads();
    for (int off = 1; off < 256; off <<= 1) {
        int o = 0;
        if (tid >= off) o = sm[tid - off];
        __syncthreads();
        if (tid >= off) sm[tid] += o;
        __syncthreads();
    }
    if (i < NN) pscan[i] = sm[tid] - v;
    if (tid == 255) bsum[blockIdx.x] = sm[255];
}

__global__ __launch_bounds__(512) void kc_scan2(const int* __restrict__ bsum,
                                                int* __restrict__ boff) {
    __shared__ int sm[512];
    int tid = threadIdx.x;
    int v = (tid < NBLK) ? bsum[tid] : 0;
    sm[tid] = v;
    __syncthreads();
    for (int off = 1; off < 512; off <<= 1) {
        int o = 0;
        if (tid >= off) o = sm[tid - off];
        __syncthreads();
        if (tid >= off) sm[tid] += o;
        __syncthreads();
    }
    if (tid < NBLK) boff[tid] = sm[tid] - v;
}

__global__ __launch_bounds__(256) void kc_scan3(const int* __restrict__ pscan,
                                                const int* __restrict__ boff,
                                                int* __restrict__ rowstart,
                                                int* __restrict__ cursor) {
    int i = blockIdx.x * 256 + threadIdx.x;
    if (i >= NN) return;
    int rs = pscan[i] + boff[blockIdx.x];
    rowstart[i] = rs;
    cursor[i] = rs;
    if (i == 0) rowstart[NN] = TE;
}

__global__ __launch_bounds__(256) void kc_fill(const int* __restrict__ esrc,
                                               const int* __restrict__ edst,
                                               int* __restrict__ cursor,
                                               int* __restrict__ eidx) {
    int e = blockIdx.x * 256 + threadIdx.x;
    if (e >= TE) return;
    int s = e < EE ? esrc[e] : e - EE;
    int d = e < EE ? edst[e] : e - EE;
    int pos = atomicAdd(cursor + d, 1);
    eidx[pos] = s;
}

// ============ GEMM1: h1 = x @ W1 (+ scores), 128x128 tile, 512 thr ============
__global__ __launch_bounds__(512, 1) void k1_gemm1(const float* __restrict__ x,
    const float* __restrict__ W1, const float* __restrict__ a_src,
    const float* __restrict__ a_dst, u16* __restrict__ h1b,
    float* __restrict__ ssrc, float* __restrict__ sdst) {
    __shared__ float xs[128][129];   // 66 KB, bank (r+k)%32
    __shared__ float Wl[128 * 128];  // 64 KB
    int t = threadIdx.x;
    int rbase = blockIdx.x * 128;
    for (int i = t; i < 128 * 128; i += 512) Wl[i] = W1[i];
    for (int i = t; i < 128 * 128; i += 512) {
        int r = i >> 7, k = i & 127;
        int row = rbase + r; if (row >= NN) row = NN - 1;
        xs[r][k] = x[(size_t)row * 128 + k];
    }
    __syncthreads();
    int tc = t & 15, tr = t >> 4;
    int r0 = tr * 4, cA = tc * 4, cB = 64 + tc * 4;
    float acc[4][8];
    #pragma unroll
    for (int i = 0; i < 4; ++i)
        #pragma unroll
        for (int j = 0; j < 8; ++j) acc[i][j] = 0.f;
    for (int k = 0; k < 128; ++k) {
        float xv[4], wv[8];
        #pragma unroll
        for (int i = 0; i < 4; ++i) xv[i] = xs[r0 + i][k];
        #pragma unroll
        for (int j = 0; j < 4; ++j) wv[j] = Wl[k * 128 + cA + j];
        #pragma unroll
        for (int j = 0; j < 4; ++j) wv[4 + j] = Wl[k * 128 + cB + j];
        #pragma unroll
        for (int i = 0; i < 4; ++i)
            #pragma unroll
            for (int j = 0; j < 8; ++j) acc[i][j] = fmaf(xv[i], wv[j], acc[i][j]);
    }
    float asv[8], adv[8];
    #pragma unroll
    for (int j = 0; j < 4; ++j) {
        asv[j] = a_src[cA + j];     adv[j] = a_dst[cA + j];
        asv[4 + j] = a_src[cB + j]; adv[4 + j] = a_dst[cB + j];
    }
    #pragma unroll
    for (int i = 0; i < 4; ++i) {
        int row = rbase + r0 + i;
        bool ok = row < NN;
        if (ok) {
            *(ushort4*)(h1b + (size_t)row * 128 + cA) = make_ushort4(
                f2bf(acc[i][0]), f2bf(acc[i][1]), f2bf(acc[i][2]), f2bf(acc[i][3]));
            *(ushort4*)(h1b + (size_t)row * 128 + cB) = make_ushort4(
                f2bf(acc[i][4]), f2bf(acc[i][5]), f2bf(acc[i][6]), f2bf(acc[i][7]));
        }
        float psA = 0.f, pdA = 0.f, psB = 0.f, pdB = 0.f;
        #pragma unroll
        for (int j = 0; j < 4; ++j) {
            psA = fmaf(acc[i][j], asv[j], psA);
            pdA = fmaf(acc[i][j], adv[j], pdA);
            psB = fmaf(acc[i][4 + j], asv[4 + j], psB);
            pdB = fmaf(acc[i][4 + j], adv[4 + j], pdB);
        }
        #pragma unroll
        for (int off = 1; off <= 4; off <<= 1) {
            psA += __shfl_xor(psA, off); pdA += __shfl_xor(pdA, off);
            psB += __shfl_xor(psB, off); pdB += __shfl_xor(pdB, off);
        }
        if ((tc & 7) == 0 && ok) {
            int hA = tc >> 3;
            ssrc[row * 4 + hA] = psA;     sdst[row * 4 + hA] = pdA;
            ssrc[row * 4 + 2 + hA] = psB; sdst[row * 4 + 2 + hA] = pdB;
        }
    }
}

// ====== Aggregation layer 1: one wave/node; gathers issued BEFORE softmax ======
// lane covers channels {2*lane, 2*lane+1}; head = lane>>4 matches score duty.
__global__ __launch_bounds__(256) void agg1(const int* __restrict__ rowstart,
    const int* __restrict__ eidx, const float* __restrict__ ssrc,
    const float* __restrict__ sdst, const u16* __restrict__ h1b,
    const float* __restrict__ b1, float* __restrict__ hr) {
    int lane = threadIdx.x & 63;
    int n = blockIdx.x * 4 + (threadIdx.x >> 6);
    if (n >= NN) return;
    int r0 = rowstart[n], deg = rowstart[n + 1] - r0;
    int h4 = lane >> 4, j16 = lane & 15;
    float sd = sdst[n * 4 + h4];
    // batch 0: issue all 16 row-gathers immediately (address = f(eidx) only)
    int s0 = (j16 < deg) ? eidx[r0 + j16] : eidx[r0];
    u32 pv[16];
    #pragma unroll
    for (int jj = 0; jj < 16; ++jj) {
        int s = __shfl(s0, jj);
        pv[jj] = *(const u32*)(h1b + (size_t)s * C1 + 2 * lane);
    }
    // softmax max while gathers are in flight
    float sv0 = (j16 < deg) ? lrelu(ssrc[s0 * 4 + h4] + sd) : -FLT_MAX;
    float mx = sv0;
    #pragma unroll
    for (int off = 1; off <= 8; off <<= 1) mx = fmaxf(mx, __shfl_xor(mx, off));
    for (int base = 16; base < deg; base += 16) {            // rare (deg>16)
        int j = base + j16;
        float sv = (j < deg) ? lrelu(ssrc[eidx[r0 + j] * 4 + h4] + sd) : -FLT_MAX;
        #pragma unroll
        for (int off = 1; off <= 8; off <<= 1) sv = fmaxf(sv, __shfl_xor(sv, off));
        mx = fmaxf(mx, sv);
    }
    float w = (j16 < deg) ? __expf(sv0 - mx) : 0.f;
    float den = w, acc0 = 0.f, acc1 = 0.f;
    #pragma unroll
    for (int jj = 0; jj < 16; ++jj) {
        float wA = __shfl(w, (lane & 48) + jj);
        acc0 = fmaf(wA, bflo(pv[jj]), acc0);
        acc1 = fmaf(wA, bfhi(pv[jj]), acc1);
    }
    for (int base = 16; base < deg; base += 16) {            // rare (deg>16)
        int j = base + j16;
        int sreg = (j < deg) ? eidx[r0 + j] : eidx[r0];
        u32 qv[16];
        #pragma unroll
        for (int jj = 0; jj < 16; ++jj) {
            int s = __shfl(sreg, jj);
            qv[jj] = *(const u32*)(h1b + (size_t)s * C1 + 2 * lane);
        }
        float wb = (j < deg) ? __expf(lrelu(ssrc[sreg * 4 + h4] + sd) - mx) : 0.f;
        den += wb;
        #pragma unroll
        for (int jj = 0; jj < 16; ++jj) {
            float wA = __shfl(wb, (lane & 48) + jj);
            acc0 = fmaf(wA, bflo(qv[jj]), acc0);
            acc1 = fmaf(wA, bfhi(qv[jj]), acc1);
        }
    }
    #pragma unroll
    for (int off = 1; off <= 8; off <<= 1) den += __shfl_xor(den, off);
    float v0 = acc0 / den + b1[2 * lane];
    float v1 = acc1 / den + b1[2 * lane + 1];
    float2 o2 = make_float2(v0 > 0.f ? v0 : 0.f, v1 > 0.f ? v1 : 0.f);
    *(float2*)(hr + (size_t)n * C1 + 2 * lane) = o2;
}

// ============ GEMM2: h2 = hr @ W2 (+ scores), 128x64 tile, 512 thr ============
__global__ __launch_bounds__(512, 1) void k5_gemm2(const float* __restrict__ B,
    const float* __restrict__ W2, const float* __restrict__ a_src,
    const float* __restrict__ a_dst, u16* __restrict__ h2b,
    float* __restrict__ ssrc, float* __restrict__ sdst) {
    __shared__ float xs[128][129];  // 66 KB
    __shared__ float Wl[128 * 64];  // 32 KB
    int t = threadIdx.x;
    int rbase = blockIdx.x * 128;
    for (int i = t; i < 128 * 64; i += 512) Wl[i] = W2[i];
    for (int i = t; i < 128 * 128; i += 512) {
        int r = i >> 7, k = i & 127;
        int row = rbase + r; if (row >= NN) row = NN - 1;
        xs[r][k] = B[(size_t)row * 128 + k];
    }
    __syncthreads();
    int tc = t & 15, tr = t >> 4;
    int r0 = tr * 4, c0 = tc * 4;
    float acc[4][4];
    #pragma unroll
    for (int i = 0; i < 4; ++i)
        #pragma unroll
        for (int j = 0; j < 4; ++j) acc[i][j] = 0.f;
    for (int k = 0; k < 128; ++k) {
        float xv[4], wv[4];
        #pragma unroll
        for (int i = 0; i < 4; ++i) xv[i] = xs[r0 + i][k];
        #pragma unroll
        for (int j = 0; j < 4; ++j) wv[j] = Wl[k * 64 + c0 + j];
        #pragma unroll
        for (int i = 0; i < 4; ++i)
            #pragma unroll
            for (int j = 0; j < 4; ++j) acc[i][j] = fmaf(xv[i], wv[j], acc[i][j]);
    }
    float asv[4], adv[4];
    #pragma unroll
    for (int j = 0; j < 4; ++j) { asv[j] = a_src[c0 + j]; adv[j] = a_dst[c0 + j]; }
    #pragma unroll
    for (int i = 0; i < 4; ++i) {
        int row = rbase + r0 + i;
        bool ok = row < NN;
        if (ok) {
            *(ushort4*)(h2b + (size_t)row * 64 + c0) = make_ushort4(
                f2bf(acc[i][0]), f2bf(acc[i][1]), f2bf(acc[i][2]), f2bf(acc[i][3]));
        }
        float ps = 0.f, pd = 0.f;
        #pragma unroll
        for (int j = 0; j < 4; ++j) {
            ps = fmaf(acc[i][j], asv[j], ps);
            pd = fmaf(acc[i][j], adv[j], pd);
        }
        #pragma unroll
        for (int off = 1; off <= 8; off <<= 1) {
            ps += __shfl_xor(ps, off); pd += __shfl_xor(pd, off);
        }
        if (tc == 0 && ok) { ssrc[row] = ps; sdst[row] = pd; }
    }
}

// ====== Aggregation layer 2 + FC + log_softmax, fused; early-issued gathers ======
__global__ __launch_bounds__(256) void agg2fc(const int* __restrict__ rowstart,
    const int* __restrict__ eidx, const float* __restrict__ ssrc,
    const float* __restrict__ sdst, const u16* __restrict__ h2b,
    const float* __restrict__ b2, const float* __restrict__ fcW,
    const float* __restrict__ fcb, float* __restrict__ out) {
    __shared__ float Wfc[C2 * C2];              // 16 KB
    __shared__ __align__(16) float vbuf[4][64]; // per-wave node vector
    for (int i = threadIdx.x; i < C2 * C2; i += 256) Wfc[i] = fcW[i];
    __syncthreads();
    int lane = threadIdx.x & 63;
    int wid = threadIdx.x >> 6;
    int n = blockIdx.x * 4 + wid;
    if (n >= NN) return;
    int r0 = rowstart[n], deg = rowstart[n + 1] - r0;
    int j16 = lane & 15, half = lane >> 5, c = lane & 31;
    float sd = sdst[n];
    // batch 0: issue the 8 gathers first (2 edges per step, 32 lanes each)
    int s0 = (j16 < deg) ? eidx[r0 + j16] : eidx[r0];
    u32 pv[8];
    #pragma unroll
    for (int q = 0; q < 8; ++q) {
        int s = __shfl(s0, 2 * q + half);
        pv[q] = *(const u32*)(h2b + (size_t)s * C2 + 2 * c);
    }
    float sv0 = (j16 < deg) ? lrelu(ssrc[s0] + sd) : -FLT_MAX;
    float mx = sv0;
    #pragma unroll
    for (int off = 1; off <= 8; off <<= 1) mx = fmaxf(mx, __shfl_xor(mx, off));
    for (int base = 16; base < deg; base += 16) {            // rare
        int j = base + j16;
        float sv = (j < deg) ? lrelu(ssrc[eidx[r0 + j]] + sd) : -FLT_MAX;
        #pragma unroll
        for (int off = 1; off <= 8; off <<= 1) sv = fmaxf(sv, __shfl_xor(sv, off));
        mx = fmaxf(mx, sv);
    }
    float w = (j16 < deg) ? __expf(sv0 - mx) : 0.f;
    float den = w, acc0 = 0.f, acc1 = 0.f;
    #pragma unroll
    for (int q = 0; q < 8; ++q) {
        float wq = __shfl(w, 2 * q + half);
        acc0 = fmaf(wq, bflo(pv[q]), acc0);
        acc1 = fmaf(wq, bfhi(pv[q]), acc1);
    }
    for (int base = 16; base < deg; base += 16) {            // rare
        int j = base + j16;
        int sreg = (j < deg) ? eidx[r0 + j] : eidx[r0];
        u32 qv[8];
        #pragma unroll
        for (int q = 0; q < 8; ++q) {
            int s = __shfl(sreg, 2 * q + half);
            qv[q] = *(const u32*)(h2b + (size_t)s * C2 + 2 * c);
        }
        float wb = (j < deg) ? __expf(lrelu(ssrc[sreg] + sd) - mx) : 0.f;
        den += wb;
        #pragma unroll
        for (int q = 0; q < 8; ++q) {
            float wq = __shfl(wb, 2 * q + half);
            acc0 = fmaf(wq, bflo(qv[q]), acc0);
            acc1 = fmaf(wq, bfhi(qv[q]), acc1);
        }
    }
    #pragma unroll
    for (int off = 1; off <= 8; off <<= 1) den += __shfl_xor(den, off);
    acc0 += __shfl_xor(acc0, 32);          // combine even/odd edge halves
    acc1 += __shfl_xor(acc1, 32);
    float v0 = acc0 / den + b2[2 * c];
    float v1 = acc1 / den + b2[2 * c + 1];
    // stash node vector in per-wave LDS row (same-wave RAW, ordered by lgkmcnt)
    if (half == 0) *(float2*)&vbuf[wid][2 * c] = make_float2(v0, v1);
    __asm__ volatile("s_waitcnt lgkmcnt(0)" ::: "memory");
    // FC: 16 broadcast float4 reads + 64 FMAs
    float y = fcb[lane];
    #pragma unroll
    for (int c4 = 0; c4 < 16; ++c4) {
        float4 vv = *(const float4*)&vbuf[wid][4 * c4];
        y = fmaf(vv.x, Wfc[(4 * c4 + 0) * C2 + lane], y);
        y = fmaf(vv.y, Wfc[(4 * c4 + 1) * C2 + lane], y);
        y = fmaf(vv.z, Wfc[(4 * c4 + 2) * C2 + lane], y);
        y = fmaf(vv.w, Wfc[(4 * c4 + 3) * C2 + lane], y);
    }
    // log_softmax
    float m = y;
    #pragma unroll
    for (int off = 32; off >= 1; off >>= 1) m = fmaxf(m, __shfl_xor(m, off));
    float sv = __expf(y - m);
    #pragma unroll
    for (int off = 32; off >= 1; off >>= 1) sv += __shfl_xor(sv, off);
    out[(size_t)n * C2 + lane] = y - m - logf(sv);
}

extern "C" void kernel_launch(void* const* d_in, const int* in_sizes, int n_in,
                              void* d_out, int out_size, void* d_ws, size_t ws_size,
                              hipStream_t stream) {
    const float* x   = (const float*)d_in[0];
    const int*   ei  = (const int*)d_in[1];
    const float* W1  = (const float*)d_in[2];
    const float* as1 = (const float*)d_in[3];
    const float* ad1 = (const float*)d_in[4];
    const float* b1  = (const float*)d_in[5];
    const float* W2  = (const float*)d_in[6];
    const float* as2 = (const float*)d_in[7];
    const float* ad2 = (const float*)d_in[8];
    const float* b2  = (const float*)d_in[9];
    const float* fcW = (const float*)d_in[10];
    const float* fcb = (const float*)d_in[11];
    float* out = (float*)d_out;

    float* ws = (float*)d_ws;
    size_t o = 0;
    u16* h1b   = (u16*)(ws + o); o += (size_t)NN * C1 / 2;  // bf16 [NN][128] (reused as h2b)
    float* hr1   = ws + o; o += (size_t)NN * C1;            // fp32 [NN][128]
    float* ssrc1 = ws + o; o += (size_t)NN * 4;
    float* sdst1 = ws + o; o += (size_t)NN * 4;
    float* ssrc2 = ws + o; o += NN;
    float* sdst2 = ws + o; o += NN;
    int* ip = (int*)(ws + o);
    int* cnt      = ip; ip += NN;
    int* pscan    = ip; ip += NN;
    int* bsum     = ip; ip += 512;
    int* boff     = ip; ip += 512;
    int* rowstart = ip; ip += NN + 2;
    int* cursor   = ip; ip += NN;
    int* eidx     = ip; ip += TE;
    u16* h2b = h1b;   // h1b dead after agg1; reuse for h2

    const int* esrc = ei;
    const int* edst = ei + EE;

    hipMemsetAsync(cnt, 0, (size_t)NN * sizeof(int), stream);

    // CSR build
    kc_count<<<(TE + 255) / 256, 256, 0, stream>>>(edst, cnt);
    kc_scan1<<<NBLK, 256, 0, stream>>>(cnt, pscan, bsum);
    kc_scan2<<<1, 512, 0, stream>>>(bsum, boff);
    kc_scan3<<<NBLK, 256, 0, stream>>>(pscan, boff, rowstart, cursor);
    kc_fill<<<(TE + 255) / 256, 256, 0, stream>>>(esrc, edst, cursor, eidx);

    // layer 1
    k1_gemm1<<<NB1, 512, 0, stream>>>(x, W1, as1, ad1, h1b, ssrc1, sdst1);
    agg1<<<(NN + 3) / 4, 256, 0, stream>>>(rowstart, eidx, ssrc1, sdst1, h1b, b1, hr1);
    // layer 2
    k5_gemm2<<<NB1, 512, 0, stream>>>(hr1, W2, as2, ad2, h2b, ssrc2, sdst2);
    agg2fc<<<(NN + 3) / 4, 256, 0, stream>>>(rowstart, eidx, ssrc2, sdst2, h2b, b2,
                                             fcW, fcb, out);
}

// Round 7
// 405.732 us; speedup vs baseline: 4.1658x; 1.0198x over previous
//
#include <hip/hip_runtime.h>
#include <hip/hip_bf16.h>
#include <cfloat>

#define NN 100000
#define EE 1000000
#define TE (EE + NN)   // edges incl. self loops
#define C1 128         // HEADS*HID
#define C2 64
#define NBLK 391       // ceil(NN/256)
#define NB1 782        // ceil(NN/128)

typedef unsigned short u16;
typedef unsigned int u32;

__device__ __forceinline__ float lrelu(float v) { return v > 0.f ? v : 0.2f * v; }
__device__ __forceinline__ u16 f2bf(float f) {           // RNE f32 -> bf16 bits
    u32 b = __float_as_uint(f);
    b += 0x7fffu + ((b >> 16) & 1u);
    return (u16)(b >> 16);
}
__device__ __forceinline__ float bflo(u32 p) { return __uint_as_float(p << 16); }
__device__ __forceinline__ float bfhi(u32 p) { return __uint_as_float(p & 0xffff0000u); }

// ================= CSR build (counting sort by dst) =================
// self-loops are handled analytically (+1 in scan, eidx[rowstart]=node).
__global__ __launch_bounds__(256) void kc_count(const int* __restrict__ edst,
                                                int* __restrict__ cnt) {
    int i = blockIdx.x * 256 + threadIdx.x;
    if (i >= EE / 4) return;
    int4 d = ((const int4*)edst)[i];
    atomicAdd(cnt + d.x, 1);
    atomicAdd(cnt + d.y, 1);
    atomicAdd(cnt + d.z, 1);
    atomicAdd(cnt + d.w, 1);
}

__global__ __launch_bounds__(256) void kc_scan1(const int* __restrict__ cnt,
                                                int* __restrict__ pscan,
                                                int* __restrict__ bsum) {
    __shared__ int sm[256];
    int tid = threadIdx.x;
    int i = blockIdx.x * 256 + tid;
    int v = (i < NN) ? (cnt[i] + 1) : 0;   // +1 = self loop
    sm[tid] = v;
    __syncthreads();
    for (int off = 1; off < 256; off <<= 1) {
        int o = 0;
        if (tid >= off) o = sm[tid - off];
        __syncthreads();
        if (tid >= off) sm[tid] += o;
        __syncthreads();
    }
    if (i < NN) pscan[i] = sm[tid] - v;
    if (tid == 255) bsum[blockIdx.x] = sm[255];
}

__global__ __launch_bounds__(512) void kc_scan2(const int* __restrict__ bsum,
                                                int* __restrict__ boff) {
    __shared__ int sm[512];
    int tid = threadIdx.x;
    int v = (tid < NBLK) ? bsum[tid] : 0;
    sm[tid] = v;
    __syncthreads();
    for (int off = 1; off < 512; off <<= 1) {
        int o = 0;
        if (tid >= off) o = sm[tid - off];
        __syncthreads();
        if (tid >= off) sm[tid] += o;
        __syncthreads();
    }
    if (tid < NBLK) boff[tid] = sm[tid] - v;
}

__global__ __launch_bounds__(256) void kc_scan3(const int* __restrict__ pscan,
                                                const int* __restrict__ boff,
                                                int* __restrict__ rowstart,
                                                int* __restrict__ cursor,
                                                int* __restrict__ eidx) {
    int i = blockIdx.x * 256 + threadIdx.x;
    if (i >= NN) return;
    int rs = pscan[i] + boff[blockIdx.x];
    rowstart[i] = rs;
    eidx[rs] = i;          // self loop occupies slot 0 of the segment
    cursor[i] = rs + 1;
    if (i == 0) rowstart[NN] = TE;
}

__global__ __launch_bounds__(256) void kc_fill(const int* __restrict__ esrc,
                                               const int* __restrict__ edst,
                                               int* __restrict__ cursor,
                                               int* __restrict__ eidx) {
    int i = blockIdx.x * 256 + threadIdx.x;
    if (i >= EE / 2) return;
    int2 s2 = ((const int2*)esrc)[i];
    int2 d2 = ((const int2*)edst)[i];
    int p0 = atomicAdd(cursor + d2.x, 1); eidx[p0] = s2.x;
    int p1 = atomicAdd(cursor + d2.y, 1); eidx[p1] = s2.y;
}

// ============ GEMM1: h1 = x @ W1 (+ scores), 128x128 tile, 512 thr ============
__global__ __launch_bounds__(512, 1) void k1_gemm1(const float* __restrict__ x,
    const float* __restrict__ W1, const float* __restrict__ a_src,
    const float* __restrict__ a_dst, u16* __restrict__ h1b,
    float* __restrict__ ssrc, float* __restrict__ sdst) {
    __shared__ float xs[128][129];   // 66 KB, bank (r+k)%32
    __shared__ float Wl[128 * 128];  // 64 KB
    int t = threadIdx.x;
    int rbase = blockIdx.x * 128;
    for (int i = t; i < 128 * 128; i += 512) Wl[i] = W1[i];
    for (int i = t; i < 128 * 128; i += 512) {
        int r = i >> 7, k = i & 127;
        int row = rbase + r; if (row >= NN) row = NN - 1;
        xs[r][k] = x[(size_t)row * 128 + k];
    }
    __syncthreads();
    int tc = t & 15, tr = t >> 4;
    int r0 = tr * 4, cA = tc * 4, cB = 64 + tc * 4;
    float acc[4][8];
    #pragma unroll
    for (int i = 0; i < 4; ++i)
        #pragma unroll
        for (int j = 0; j < 8; ++j) acc[i][j] = 0.f;
    for (int k = 0; k < 128; ++k) {
        float xv[4], wv[8];
        #pragma unroll
        for (int i = 0; i < 4; ++i) xv[i] = xs[r0 + i][k];
        #pragma unroll
        for (int j = 0; j < 4; ++j) wv[j] = Wl[k * 128 + cA + j];
        #pragma unroll
        for (int j = 0; j < 4; ++j) wv[4 + j] = Wl[k * 128 + cB + j];
        #pragma unroll
        for (int i = 0; i < 4; ++i)
            #pragma unroll
            for (int j = 0; j < 8; ++j) acc[i][j] = fmaf(xv[i], wv[j], acc[i][j]);
    }
    float asv[8], adv[8];
    #pragma unroll
    for (int j = 0; j < 4; ++j) {
        asv[j] = a_src[cA + j];     adv[j] = a_dst[cA + j];
        asv[4 + j] = a_src[cB + j]; adv[4 + j] = a_dst[cB + j];
    }
    #pragma unroll
    for (int i = 0; i < 4; ++i) {
        int row = rbase + r0 + i;
        bool ok = row < NN;
        if (ok) {
            *(ushort4*)(h1b + (size_t)row * 128 + cA) = make_ushort4(
                f2bf(acc[i][0]), f2bf(acc[i][1]), f2bf(acc[i][2]), f2bf(acc[i][3]));
            *(ushort4*)(h1b + (size_t)row * 128 + cB) = make_ushort4(
                f2bf(acc[i][4]), f2bf(acc[i][5]), f2bf(acc[i][6]), f2bf(acc[i][7]));
        }
        float psA = 0.f, pdA = 0.f, psB = 0.f, pdB = 0.f;
        #pragma unroll
        for (int j = 0; j < 4; ++j) {
            psA = fmaf(acc[i][j], asv[j], psA);
            pdA = fmaf(acc[i][j], adv[j], pdA);
            psB = fmaf(acc[i][4 + j], asv[4 + j], psB);
            pdB = fmaf(acc[i][4 + j], adv[4 + j], pdB);
        }
        #pragma unroll
        for (int off = 1; off <= 4; off <<= 1) {
            psA += __shfl_xor(psA, off); pdA += __shfl_xor(pdA, off);
            psB += __shfl_xor(psB, off); pdB += __shfl_xor(pdB, off);
        }
        if ((tc & 7) == 0 && ok) {
            int hA = tc >> 3;
            ssrc[row * 4 + hA] = psA;     sdst[row * 4 + hA] = pdA;
            ssrc[row * 4 + 2 + hA] = psB; sdst[row * 4 + 2 + hA] = pdB;
        }
    }
}

// ====== Aggregation layer 1: one wave/node; u64 gathers (4 ch/lane, 2 edges/step) ======
// score duty: head h4=lane>>4, edge j16=lane&15.  channel duty: c=lane&31 ->
// channels 4c..4c+3 (head hh=c>>3) of edge parity half=lane>>5.
__global__ __launch_bounds__(256) void agg1(const int* __restrict__ rowstart,
    const int* __restrict__ eidx, const float* __restrict__ ssrc,
    const float* __restrict__ sdst, const u16* __restrict__ h1b,
    const float* __restrict__ b1, float* __restrict__ hr) {
    int lane = threadIdx.x & 63;
    int n = blockIdx.x * 4 + (threadIdx.x >> 6);
    if (n >= NN) return;
    int r0 = rowstart[n], deg = rowstart[n + 1] - r0;
    int h4 = lane >> 4, j16 = lane & 15;
    int half = lane >> 5, c = lane & 31, hh = c >> 3;
    float sd = sdst[n * 4 + h4];
    // batch 0: issue 8 uint2 gathers (edges 2q+half)
    int s0 = (j16 < deg) ? eidx[r0 + j16] : eidx[r0];
    uint2 pv[8];
    #pragma unroll
    for (int q = 0; q < 8; ++q) {
        int s = __shfl(s0, 2 * q + half);
        pv[q] = *(const uint2*)(h1b + (size_t)s * C1 + 4 * c);
    }
    // softmax max while gathers are in flight
    float sv0 = (j16 < deg) ? lrelu(ssrc[s0 * 4 + h4] + sd) : -FLT_MAX;
    float mx = sv0;
    #pragma unroll
    for (int off = 1; off <= 8; off <<= 1) mx = fmaxf(mx, __shfl_xor(mx, off));
    for (int base = 16; base < deg; base += 16) {            // rare (deg>16)
        int j = base + j16;
        float sv = (j < deg) ? lrelu(ssrc[eidx[r0 + j] * 4 + h4] + sd) : -FLT_MAX;
        #pragma unroll
        for (int off = 1; off <= 8; off <<= 1) sv = fmaxf(sv, __shfl_xor(sv, off));
        mx = fmaxf(mx, sv);
    }
    float w = (j16 < deg) ? __expf(sv0 - mx) : 0.f;
    float den = w;
    float a0 = 0.f, a1 = 0.f, a2 = 0.f, a3 = 0.f;
    #pragma unroll
    for (int q = 0; q < 8; ++q) {
        float wq = __shfl(w, (hh << 4) + 2 * q + half);
        a0 = fmaf(wq, bflo(pv[q].x), a0);
        a1 = fmaf(wq, bfhi(pv[q].x), a1);
        a2 = fmaf(wq, bflo(pv[q].y), a2);
        a3 = fmaf(wq, bfhi(pv[q].y), a3);
    }
    for (int base = 16; base < deg; base += 16) {            // rare (deg>16)
        int j = base + j16;
        int sreg = (j < deg) ? eidx[r0 + j] : eidx[r0];
        uint2 qv[8];
        #pragma unroll
        for (int q = 0; q < 8; ++q) {
            int s = __shfl(sreg, 2 * q + half);
            qv[q] = *(const uint2*)(h1b + (size_t)s * C1 + 4 * c);
        }
        float wb = (j < deg) ? __expf(lrelu(ssrc[sreg * 4 + h4] + sd) - mx) : 0.f;
        den += wb;
        #pragma unroll
        for (int q = 0; q < 8; ++q) {
            float wq = __shfl(wb, (hh << 4) + 2 * q + half);
            a0 = fmaf(wq, bflo(qv[q].x), a0);
            a1 = fmaf(wq, bfhi(qv[q].x), a1);
            a2 = fmaf(wq, bflo(qv[q].y), a2);
            a3 = fmaf(wq, bfhi(qv[q].y), a3);
        }
    }
    #pragma unroll
    for (int off = 1; off <= 8; off <<= 1) den += __shfl_xor(den, off);
    float dh = __shfl(den, hh << 4);       // den of the channel-duty head
    a0 += __shfl_xor(a0, 32);
    a1 += __shfl_xor(a1, 32);
    a2 += __shfl_xor(a2, 32);
    a3 += __shfl_xor(a3, 32);
    if (half == 0) {
        float4 bv = *(const float4*)(b1 + 4 * c);
        float v0 = a0 / dh + bv.x, v1 = a1 / dh + bv.y;
        float v2 = a2 / dh + bv.z, v3 = a3 / dh + bv.w;
        *(float4*)(hr + (size_t)n * C1 + 4 * c) = make_float4(
            v0 > 0.f ? v0 : 0.f, v1 > 0.f ? v1 : 0.f,
            v2 > 0.f ? v2 : 0.f, v3 > 0.f ? v3 : 0.f);
    }
}

// ============ GEMM2: h2 = hr @ W2 (+ scores), 128x64 tile, 512 thr ============
__global__ __launch_bounds__(512, 1) void k5_gemm2(const float* __restrict__ B,
    const float* __restrict__ W2, const float* __restrict__ a_src,
    const float* __restrict__ a_dst, u16* __restrict__ h2b,
    float* __restrict__ ssrc, float* __restrict__ sdst) {
    __shared__ float xs[128][129];  // 66 KB
    __shared__ float Wl[128 * 64];  // 32 KB
    int t = threadIdx.x;
    int rbase = blockIdx.x * 128;
    for (int i = t; i < 128 * 64; i += 512) Wl[i] = W2[i];
    for (int i = t; i < 128 * 128; i += 512) {
        int r = i >> 7, k = i & 127;
        int row = rbase + r; if (row >= NN) row = NN - 1;
        xs[r][k] = B[(size_t)row * 128 + k];
    }
    __syncthreads();
    int tc = t & 15, tr = t >> 4;
    int r0 = tr * 4, c0 = tc * 4;
    float acc[4][4];
    #pragma unroll
    for (int i = 0; i < 4; ++i)
        #pragma unroll
        for (int j = 0; j < 4; ++j) acc[i][j] = 0.f;
    for (int k = 0; k < 128; ++k) {
        float xv[4], wv[4];
        #pragma unroll
        for (int i = 0; i < 4; ++i) xv[i] = xs[r0 + i][k];
        #pragma unroll
        for (int j = 0; j < 4; ++j) wv[j] = Wl[k * 64 + c0 + j];
        #pragma unroll
        for (int i = 0; i < 4; ++i)
            #pragma unroll
            for (int j = 0; j < 4; ++j) acc[i][j] = fmaf(xv[i], wv[j], acc[i][j]);
    }
    float asv[4], adv[4];
    #pragma unroll
    for (int j = 0; j < 4; ++j) { asv[j] = a_src[c0 + j]; adv[j] = a_dst[c0 + j]; }
    #pragma unroll
    for (int i = 0; i < 4; ++i) {
        int row = rbase + r0 + i;
        bool ok = row < NN;
        if (ok) {
            *(ushort4*)(h2b + (size_t)row * 64 + c0) = make_ushort4(
                f2bf(acc[i][0]), f2bf(acc[i][1]), f2bf(acc[i][2]), f2bf(acc[i][3]));
        }
        float ps = 0.f, pd = 0.f;
        #pragma unroll
        for (int j = 0; j < 4; ++j) {
            ps = fmaf(acc[i][j], asv[j], ps);
            pd = fmaf(acc[i][j], adv[j], pd);
        }
        #pragma unroll
        for (int off = 1; off <= 8; off <<= 1) {
            ps += __shfl_xor(ps, off); pd += __shfl_xor(pd, off);
        }
        if (tc == 0 && ok) { ssrc[row] = ps; sdst[row] = pd; }
    }
}

// ====== Aggregation layer 2 + FC + log_softmax; u64 gathers (4 edges/step) ======
__global__ __launch_bounds__(256) void agg2fc(const int* __restrict__ rowstart,
    const int* __restrict__ eidx, const float* __restrict__ ssrc,
    const float* __restrict__ sdst, const u16* __restrict__ h2b,
    const float* __restrict__ b2, const float* __restrict__ fcW,
    const float* __restrict__ fcb, float* __restrict__ out) {
    __shared__ float Wfc[C2 * C2];              // 16 KB
    __shared__ __align__(16) float vbuf[4][64]; // per-wave node vector
    for (int i = threadIdx.x; i < C2 * C2; i += 256) Wfc[i] = fcW[i];
    __syncthreads();
    int lane = threadIdx.x & 63;
    int wid = threadIdx.x >> 6;
    int n = blockIdx.x * 4 + wid;
    if (n >= NN) return;
    int r0 = rowstart[n], deg = rowstart[n + 1] - r0;
    int j16 = lane & 15, quarter = lane >> 4, c16 = lane & 15;
    float sd = sdst[n];
    // batch 0: issue the 4 uint2 gathers (edges 4q+quarter, channels 4*c16..+3)
    int s0 = (j16 < deg) ? eidx[r0 + j16] : eidx[r0];
    uint2 pv[4];
    #pragma unroll
    for (int q = 0; q < 4; ++q) {
        int s = __shfl(s0, 4 * q + quarter);
        pv[q] = *(const uint2*)(h2b + (size_t)s * C2 + 4 * c16);
    }
    float sv0 = (j16 < deg) ? lrelu(ssrc[s0] + sd) : -FLT_MAX;
    float mx = sv0;
    #pragma unroll
    for (int off = 1; off <= 8; off <<= 1) mx = fmaxf(mx, __shfl_xor(mx, off));
    for (int base = 16; base < deg; base += 16) {            // rare
        int j = base + j16;
        float sv = (j < deg) ? lrelu(ssrc[eidx[r0 + j]] + sd) : -FLT_MAX;
        #pragma unroll
        for (int off = 1; off <= 8; off <<= 1) sv = fmaxf(sv, __shfl_xor(sv, off));
        mx = fmaxf(mx, sv);
    }
    float w = (j16 < deg) ? __expf(sv0 - mx) : 0.f;
    float den = w;
    float a0 = 0.f, a1 = 0.f, a2 = 0.f, a3 = 0.f;
    #pragma unroll
    for (int q = 0; q < 4; ++q) {
        float wq = __shfl(w, 4 * q + quarter);
        a0 = fmaf(wq, bflo(pv[q].x), a0);
        a1 = fmaf(wq, bfhi(pv[q].x), a1);
        a2 = fmaf(wq, bflo(pv[q].y), a2);
        a3 = fmaf(wq, bfhi(pv[q].y), a3);
    }
    for (int base = 16; base < deg; base += 16) {            // rare
        int j = base + j16;
        int sreg = (j < deg) ? eidx[r0 + j] : eidx[r0];
        uint2 qv[4];
        #pragma unroll
        for (int q = 0; q < 4; ++q) {
            int s = __shfl(sreg, 4 * q + quarter);
            qv[q] = *(const uint2*)(h2b + (size_t)s * C2 + 4 * c16);
        }
        float wb = (j < deg) ? __expf(lrelu(ssrc[sreg] + sd) - mx) : 0.f;
        den += wb;
        #pragma unroll
        for (int q = 0; q < 4; ++q) {
            float wq = __shfl(wb, 4 * q + quarter);
            a0 = fmaf(wq, bflo(qv[q].x), a0);
            a1 = fmaf(wq, bfhi(qv[q].x), a1);
            a2 = fmaf(wq, bflo(qv[q].y), a2);
            a3 = fmaf(wq, bfhi(qv[q].y), a3);
        }
    }
    #pragma unroll
    for (int off = 1; off <= 8; off <<= 1) den += __shfl_xor(den, off);
    // combine the 4 edge-quarters
    a0 += __shfl_xor(a0, 16); a0 += __shfl_xor(a0, 32);
    a1 += __shfl_xor(a1, 16); a1 += __shfl_xor(a1, 32);
    a2 += __shfl_xor(a2, 16); a2 += __shfl_xor(a2, 32);
    a3 += __shfl_xor(a3, 16); a3 += __shfl_xor(a3, 32);
    if (quarter == 0) {
        float4 bv = *(const float4*)(b2 + 4 * c16);
        vbuf[wid][4 * c16 + 0] = a0 / den + bv.x;
        vbuf[wid][4 * c16 + 1] = a1 / den + bv.y;
        vbuf[wid][4 * c16 + 2] = a2 / den + bv.z;
        vbuf[wid][4 * c16 + 3] = a3 / den + bv.w;
    }
    __asm__ volatile("s_waitcnt lgkmcnt(0)" ::: "memory");
    // FC: 16 broadcast float4 reads + 64 FMAs
    float y = fcb[lane];
    #pragma unroll
    for (int c4 = 0; c4 < 16; ++c4) {
        float4 vv = *(const float4*)&vbuf[wid][4 * c4];
        y = fmaf(vv.x, Wfc[(4 * c4 + 0) * C2 + lane], y);
        y = fmaf(vv.y, Wfc[(4 * c4 + 1) * C2 + lane], y);
        y = fmaf(vv.z, Wfc[(4 * c4 + 2) * C2 + lane], y);
        y = fmaf(vv.w, Wfc[(4 * c4 + 3) * C2 + lane], y);
    }
    // log_softmax
    float m = y;
    #pragma unroll
    for (int off = 32; off >= 1; off >>= 1) m = fmaxf(m, __shfl_xor(m, off));
    float sv = __expf(y - m);
    #pragma unroll
    for (int off = 32; off >= 1; off >>= 1) sv += __shfl_xor(sv, off);
    out[(size_t)n * C2 + lane] = y - m - logf(sv);
}

extern "C" void kernel_launch(void* const* d_in, const int* in_sizes, int n_in,
                              void* d_out, int out_size, void* d_ws, size_t ws_size,
                              hipStream_t stream) {
    const float* x   = (const float*)d_in[0];
    const int*   ei  = (const int*)d_in[1];
    const float* W1  = (const float*)d_in[2];
    const float* as1 = (const float*)d_in[3];
    const float* ad1 = (const float*)d_in[4];
    const float* b1  = (const float*)d_in[5];
    const float* W2  = (const float*)d_in[6];
    const float* as2 = (const float*)d_in[7];
    const float* ad2 = (const float*)d_in[8];
    const float* b2  = (const float*)d_in[9];
    const float* fcW = (const float*)d_in[10];
    const float* fcb = (const float*)d_in[11];
    float* out = (float*)d_out;

    float* ws = (float*)d_ws;
    size_t o = 0;
    u16* h1b   = (u16*)(ws + o); o += (size_t)NN * C1 / 2;  // bf16 [NN][128] (reused as h2b)
    float* hr1   = ws + o; o += (size_t)NN * C1;            // fp32 [NN][128]
    float* ssrc1 = ws + o; o += (size_t)NN * 4;
    float* sdst1 = ws + o; o += (size_t)NN * 4;
    float* ssrc2 = ws + o; o += NN;
    float* sdst2 = ws + o; o += NN;
    int* ip = (int*)(ws + o);
    int* cnt      = ip; ip += NN;
    int* pscan    = ip; ip += NN;
    int* bsum     = ip; ip += 512;
    int* boff     = ip; ip += 512;
    int* rowstart = ip; ip += NN + 2;
    int* cursor   = ip; ip += NN;
    int* eidx     = ip; ip += TE;
    u16* h2b = h1b;   // h1b dead after agg1; reuse for h2

    const int* esrc = ei;
    const int* edst = ei + EE;

    hipMemsetAsync(cnt, 0, (size_t)NN * sizeof(int), stream);

    // CSR build (self-loops synthesized in scan3)
    kc_count<<<(EE / 4 + 255) / 256, 256, 0, stream>>>(edst, cnt);
    kc_scan1<<<NBLK, 256, 0, stream>>>(cnt, pscan, bsum);
    kc_scan2<<<1, 512, 0, stream>>>(bsum, boff);
    kc_scan3<<<NBLK, 256, 0, stream>>>(pscan, boff, rowstart, cursor, eidx);
    kc_fill<<<(EE / 2 + 255) / 256, 256, 0, stream>>>(esrc, edst, cursor, eidx);

    // layer 1
    k1_gemm1<<<NB1, 512, 0, stream>>>(x, W1, as1, ad1, h1b, ssrc1, sdst1);
    agg1<<<(NN + 3) / 4, 256, 0, stream>>>(rowstart, eidx, ssrc1, sdst1, h1b, b1, hr1);
    // layer 2
    k5_gemm2<<<NB1, 512, 0, stream>>>(hr1, W2, as2, ad2, h2b, ssrc2, sdst2);
    agg2fc<<<(NN + 3) / 4, 256, 0, stream>>>(rowstart, eidx, ssrc2, sdst2, h2b, b2,
                                             fcW, fcb, out);
}

// Round 8
// 360.849 us; speedup vs baseline: 4.6840x; 1.1244x over previous
//
#include <hip/hip_runtime.h>
#include <hip/hip_bf16.h>
#include <cfloat>

#define NN 100000
#define EE 1000000
#define TE (EE + NN)   // edges incl. self loops
#define C1 128         // HEADS*HID
#define C2 64
#define NBLK 391       // ceil(NN/256)
#define NB1 782        // ceil(NN/128)

typedef unsigned short u16;
typedef unsigned int u32;

__device__ __forceinline__ float lrelu(float v) { return v > 0.f ? v : 0.2f * v; }
__device__ __forceinline__ u16 f2bf(float f) {           // RNE f32 -> bf16 bits
    u32 b = __float_as_uint(f);
    b += 0x7fffu + ((b >> 16) & 1u);
    return (u16)(b >> 16);
}
__device__ __forceinline__ float bflo(u32 p) { return __uint_as_float(p << 16); }
__device__ __forceinline__ float bfhi(u32 p) { return __uint_as_float(p & 0xffff0000u); }

// ============ precompute: W2p = W2@fcW, us/ud = W2@a2^T, b2p = b2@fcW+fcb ============
__global__ __launch_bounds__(64) void kprep(const float* __restrict__ W2,
    const float* __restrict__ as2, const float* __restrict__ ad2,
    const float* __restrict__ b2, const float* __restrict__ fcW,
    const float* __restrict__ fcb, float* __restrict__ W2p,
    float* __restrict__ us, float* __restrict__ ud, float* __restrict__ b2p) {
    int b = blockIdx.x, t = threadIdx.x;
    if (b < 128) {
        float s = 0.f;
        for (int k = 0; k < 64; ++k) s = fmaf(W2[b * 64 + k], fcW[k * 64 + t], s);
        W2p[b * 64 + t] = s;
    } else if (b < 130) {
        int r = (b - 128) * 64 + t;
        float s = 0.f, d = 0.f;
        for (int k = 0; k < 64; ++k) {
            float wv = W2[r * 64 + k];
            s = fmaf(wv, as2[k], s);
            d = fmaf(wv, ad2[k], d);
        }
        us[r] = s; ud[r] = d;
    } else {
        float s = fcb[t];
        for (int k = 0; k < 64; ++k) s = fmaf(b2[k], fcW[k * 64 + t], s);
        b2p[t] = s;
    }
}

// ================= CSR build (counting sort by dst) =================
__global__ __launch_bounds__(256) void kc_count(const int* __restrict__ edst,
                                                int* __restrict__ cnt) {
    int i = blockIdx.x * 256 + threadIdx.x;
    if (i >= EE / 4) return;
    int4 d = ((const int4*)edst)[i];
    atomicAdd(cnt + d.x, 1);
    atomicAdd(cnt + d.y, 1);
    atomicAdd(cnt + d.z, 1);
    atomicAdd(cnt + d.w, 1);
}

__global__ __launch_bounds__(256) void kc_scan1(const int* __restrict__ cnt,
                                                int* __restrict__ pscan,
                                                int* __restrict__ bsum) {
    __shared__ int sm[256];
    int tid = threadIdx.x;
    int i = blockIdx.x * 256 + tid;
    int v = (i < NN) ? (cnt[i] + 1) : 0;   // +1 = self loop
    sm[tid] = v;
    __syncthreads();
    for (int off = 1; off < 256; off <<= 1) {
        int o = 0;
        if (tid >= off) o = sm[tid - off];
        __syncthreads();
        if (tid >= off) sm[tid] += o;
        __syncthreads();
    }
    if (i < NN) pscan[i] = sm[tid] - v;
    if (tid == 255) bsum[blockIdx.x] = sm[255];
}

__global__ __launch_bounds__(512) void kc_scan2(const int* __restrict__ bsum,
                                                int* __restrict__ boff) {
    __shared__ int sm[512];
    int tid = threadIdx.x;
    int v = (tid < NBLK) ? bsum[tid] : 0;
    sm[tid] = v;
    __syncthreads();
    for (int off = 1; off < 512; off <<= 1) {
        int o = 0;
        if (tid >= off) o = sm[tid - off];
        __syncthreads();
        if (tid >= off) sm[tid] += o;
        __syncthreads();
    }
    if (tid < NBLK) boff[tid] = sm[tid] - v;
}

__global__ __launch_bounds__(256) void kc_scan3(const int* __restrict__ pscan,
                                                const int* __restrict__ boff,
                                                int* __restrict__ rowstart,
                                                int* __restrict__ cursor,
                                                int* __restrict__ eidx) {
    int i = blockIdx.x * 256 + threadIdx.x;
    if (i >= NN) return;
    int rs = pscan[i] + boff[blockIdx.x];
    rowstart[i] = rs;
    eidx[rs] = i;          // self loop occupies slot 0 of the segment
    cursor[i] = rs + 1;
    if (i == 0) rowstart[NN] = TE;
}

__global__ __launch_bounds__(256) void kc_fill(const int* __restrict__ esrc,
                                               const int* __restrict__ edst,
                                               int* __restrict__ cursor,
                                               int* __restrict__ eidx) {
    int i = blockIdx.x * 256 + threadIdx.x;
    if (i >= EE / 2) return;
    int2 s2 = ((const int2*)esrc)[i];
    int2 d2 = ((const int2*)edst)[i];
    int p0 = atomicAdd(cursor + d2.x, 1); eidx[p0] = s2.x;
    int p1 = atomicAdd(cursor + d2.y, 1); eidx[p1] = s2.y;
}

// ============ GEMM1: h1 = x @ W1 (+ scores), 128x128 tile, 512 thr ============
__global__ __launch_bounds__(512, 1) void k1_gemm1(const float* __restrict__ x,
    const float* __restrict__ W1, const float* __restrict__ a_src,
    const float* __restrict__ a_dst, u16* __restrict__ h1b,
    float* __restrict__ ssrc, float* __restrict__ sdst) {
    __shared__ float xs[128][129];   // 66 KB, bank (r+k)%32
    __shared__ float Wl[128 * 128];  // 64 KB
    int t = threadIdx.x;
    int rbase = blockIdx.x * 128;
    for (int i = t; i < 128 * 128; i += 512) Wl[i] = W1[i];
    for (int i = t; i < 128 * 128; i += 512) {
        int r = i >> 7, k = i & 127;
        int row = rbase + r; if (row >= NN) row = NN - 1;
        xs[r][k] = x[(size_t)row * 128 + k];
    }
    __syncthreads();
    int tc = t & 15, tr = t >> 4;
    int r0 = tr * 4, cA = tc * 4, cB = 64 + tc * 4;
    float acc[4][8];
    #pragma unroll
    for (int i = 0; i < 4; ++i)
        #pragma unroll
        for (int j = 0; j < 8; ++j) acc[i][j] = 0.f;
    for (int k = 0; k < 128; ++k) {
        float xv[4], wv[8];
        #pragma unroll
        for (int i = 0; i < 4; ++i) xv[i] = xs[r0 + i][k];
        #pragma unroll
        for (int j = 0; j < 4; ++j) wv[j] = Wl[k * 128 + cA + j];
        #pragma unroll
        for (int j = 0; j < 4; ++j) wv[4 + j] = Wl[k * 128 + cB + j];
        #pragma unroll
        for (int i = 0; i < 4; ++i)
            #pragma unroll
            for (int j = 0; j < 8; ++j) acc[i][j] = fmaf(xv[i], wv[j], acc[i][j]);
    }
    float asv[8], adv[8];
    #pragma unroll
    for (int j = 0; j < 4; ++j) {
        asv[j] = a_src[cA + j];     adv[j] = a_dst[cA + j];
        asv[4 + j] = a_src[cB + j]; adv[4 + j] = a_dst[cB + j];
    }
    #pragma unroll
    for (int i = 0; i < 4; ++i) {
        int row = rbase + r0 + i;
        bool ok = row < NN;
        if (ok) {
            *(ushort4*)(h1b + (size_t)row * 128 + cA) = make_ushort4(
                f2bf(acc[i][0]), f2bf(acc[i][1]), f2bf(acc[i][2]), f2bf(acc[i][3]));
            *(ushort4*)(h1b + (size_t)row * 128 + cB) = make_ushort4(
                f2bf(acc[i][4]), f2bf(acc[i][5]), f2bf(acc[i][6]), f2bf(acc[i][7]));
        }
        float psA = 0.f, pdA = 0.f, psB = 0.f, pdB = 0.f;
        #pragma unroll
        for (int j = 0; j < 4; ++j) {
            psA = fmaf(acc[i][j], asv[j], psA);
            pdA = fmaf(acc[i][j], adv[j], pdA);
            psB = fmaf(acc[i][4 + j], asv[4 + j], psB);
            pdB = fmaf(acc[i][4 + j], adv[4 + j], pdB);
        }
        #pragma unroll
        for (int off = 1; off <= 4; off <<= 1) {
            psA += __shfl_xor(psA, off); pdA += __shfl_xor(pdA, off);
            psB += __shfl_xor(psB, off); pdB += __shfl_xor(pdB, off);
        }
        if ((tc & 7) == 0 && ok) {
            int hA = tc >> 3;
            ssrc[row * 4 + hA] = psA;     sdst[row * 4 + hA] = pdA;
            ssrc[row * 4 + 2 + hA] = psB; sdst[row * 4 + 2 + hA] = pdB;
        }
    }
}

// ====== Aggregation layer 1: one wave/node; u64 gathers (4 ch/lane, 2 edges/step) ======
__global__ __launch_bounds__(256) void agg1(const int* __restrict__ rowstart,
    const int* __restrict__ eidx, const float* __restrict__ ssrc,
    const float* __restrict__ sdst, const u16* __restrict__ h1b,
    const float* __restrict__ b1, float* __restrict__ hr) {
    int lane = threadIdx.x & 63;
    int n = blockIdx.x * 4 + (threadIdx.x >> 6);
    if (n >= NN) return;
    int r0 = rowstart[n], deg = rowstart[n + 1] - r0;
    int h4 = lane >> 4, j16 = lane & 15;
    int half = lane >> 5, c = lane & 31, hh = c >> 3;
    float sd = sdst[n * 4 + h4];
    int s0 = (j16 < deg) ? eidx[r0 + j16] : eidx[r0];
    uint2 pv[8];
    #pragma unroll
    for (int q = 0; q < 8; ++q) {
        int s = __shfl(s0, 2 * q + half);
        pv[q] = *(const uint2*)(h1b + (size_t)s * C1 + 4 * c);
    }
    float sv0 = (j16 < deg) ? lrelu(ssrc[s0 * 4 + h4] + sd) : -FLT_MAX;
    float mx = sv0;
    #pragma unroll
    for (int off = 1; off <= 8; off <<= 1) mx = fmaxf(mx, __shfl_xor(mx, off));
    for (int base = 16; base < deg; base += 16) {            // rare (deg>16)
        int j = base + j16;
        float sv = (j < deg) ? lrelu(ssrc[eidx[r0 + j] * 4 + h4] + sd) : -FLT_MAX;
        #pragma unroll
        for (int off = 1; off <= 8; off <<= 1) sv = fmaxf(sv, __shfl_xor(sv, off));
        mx = fmaxf(mx, sv);
    }
    float w = (j16 < deg) ? __expf(sv0 - mx) : 0.f;
    float den = w;
    float a0 = 0.f, a1 = 0.f, a2 = 0.f, a3 = 0.f;
    #pragma unroll
    for (int q = 0; q < 8; ++q) {
        float wq = __shfl(w, (hh << 4) + 2 * q + half);
        a0 = fmaf(wq, bflo(pv[q].x), a0);
        a1 = fmaf(wq, bfhi(pv[q].x), a1);
        a2 = fmaf(wq, bflo(pv[q].y), a2);
        a3 = fmaf(wq, bfhi(pv[q].y), a3);
    }
    for (int base = 16; base < deg; base += 16) {            // rare (deg>16)
        int j = base + j16;
        int sreg = (j < deg) ? eidx[r0 + j] : eidx[r0];
        uint2 qv[8];
        #pragma unroll
        for (int q = 0; q < 8; ++q) {
            int s = __shfl(sreg, 2 * q + half);
            qv[q] = *(const uint2*)(h1b + (size_t)s * C1 + 4 * c);
        }
        float wb = (j < deg) ? __expf(lrelu(ssrc[sreg * 4 + h4] + sd) - mx) : 0.f;
        den += wb;
        #pragma unroll
        for (int q = 0; q < 8; ++q) {
            float wq = __shfl(wb, (hh << 4) + 2 * q + half);
            a0 = fmaf(wq, bflo(qv[q].x), a0);
            a1 = fmaf(wq, bfhi(qv[q].x), a1);
            a2 = fmaf(wq, bflo(qv[q].y), a2);
            a3 = fmaf(wq, bfhi(qv[q].y), a3);
        }
    }
    #pragma unroll
    for (int off = 1; off <= 8; off <<= 1) den += __shfl_xor(den, off);
    float dh = __shfl(den, hh << 4);
    a0 += __shfl_xor(a0, 32);
    a1 += __shfl_xor(a1, 32);
    a2 += __shfl_xor(a2, 32);
    a3 += __shfl_xor(a3, 32);
    if (half == 0) {
        float4 bv = *(const float4*)(b1 + 4 * c);
        float v0 = a0 / dh + bv.x, v1 = a1 / dh + bv.y;
        float v2 = a2 / dh + bv.z, v3 = a3 / dh + bv.w;
        *(float4*)(hr + (size_t)n * C1 + 4 * c) = make_float4(
            v0 > 0.f ? v0 : 0.f, v1 > 0.f ? v1 : 0.f,
            v2 > 0.f ? v2 : 0.f, v3 > 0.f ? v3 : 0.f);
    }
}

// ==== GEMM2': h3 = hr @ (W2@fcW); scores = hr·us, hr·ud (h2 never built) ====
__global__ __launch_bounds__(512, 1) void k5_gemm2p(const float* __restrict__ B,
    const float* __restrict__ W2p, const float* __restrict__ usv,
    const float* __restrict__ udv, u16* __restrict__ h3b,
    float* __restrict__ ssrc, float* __restrict__ sdst) {
    __shared__ float xs[128][129];  // 66 KB
    __shared__ float Wl[128 * 64];  // 32 KB
    __shared__ float usl[128], udl[128];
    int t = threadIdx.x;
    int rbase = blockIdx.x * 128;
    for (int i = t; i < 128 * 64; i += 512) Wl[i] = W2p[i];
    if (t < 128) { usl[t] = usv[t]; udl[t] = udv[t]; }
    for (int i = t; i < 128 * 128; i += 512) {
        int r = i >> 7, k = i & 127;
        int row = rbase + r; if (row >= NN) row = NN - 1;
        xs[r][k] = B[(size_t)row * 128 + k];
    }
    __syncthreads();
    int tc = t & 15, tr = t >> 4;
    int r0 = tr * 4, c0 = tc * 4;
    float acc[4][4];
    #pragma unroll
    for (int i = 0; i < 4; ++i)
        #pragma unroll
        for (int j = 0; j < 4; ++j) acc[i][j] = 0.f;
    for (int k = 0; k < 128; ++k) {
        float xv[4], wv[4];
        #pragma unroll
        for (int i = 0; i < 4; ++i) xv[i] = xs[r0 + i][k];
        #pragma unroll
        for (int j = 0; j < 4; ++j) wv[j] = Wl[k * 64 + c0 + j];
        #pragma unroll
        for (int i = 0; i < 4; ++i)
            #pragma unroll
            for (int j = 0; j < 4; ++j) acc[i][j] = fmaf(xv[i], wv[j], acc[i][j]);
    }
    #pragma unroll
    for (int i = 0; i < 4; ++i) {
        int row = rbase + r0 + i;
        if (row < NN) {
            *(ushort4*)(h3b + (size_t)row * 64 + c0) = make_ushort4(
                f2bf(acc[i][0]), f2bf(acc[i][1]), f2bf(acc[i][2]), f2bf(acc[i][3]));
        }
    }
    // score phase: thread t -> row rr = t>>2, quarter q = t&3 over k = 32q..32q+31
    int rr = t >> 2, q = t & 3;
    float ssa = 0.f, dda = 0.f;
    #pragma unroll 8
    for (int kk = 0; kk < 32; ++kk) {
        float xv = xs[rr][32 * q + kk];
        ssa = fmaf(xv, usl[32 * q + kk], ssa);
        dda = fmaf(xv, udl[32 * q + kk], dda);
    }
    ssa += __shfl_xor(ssa, 1); ssa += __shfl_xor(ssa, 2);
    dda += __shfl_xor(dda, 1); dda += __shfl_xor(dda, 2);
    if (q == 0 && rbase + rr < NN) {
        ssrc[rbase + rr] = ssa;
        sdst[rbase + rr] = dda;
    }
}

// ====== Aggregation layer 2 + log_softmax (FC pre-folded into h3) ======
__global__ __launch_bounds__(256) void agg2ls(const int* __restrict__ rowstart,
    const int* __restrict__ eidx, const float* __restrict__ ssrc,
    const float* __restrict__ sdst, const u16* __restrict__ h3b,
    const float* __restrict__ b2p, float* __restrict__ out) {
    int lane = threadIdx.x & 63;
    int n = blockIdx.x * 4 + (threadIdx.x >> 6);
    if (n >= NN) return;
    int r0 = rowstart[n], deg = rowstart[n + 1] - r0;
    int j16 = lane & 15, quarter = lane >> 4, c16 = lane & 15;
    float sd = sdst[n];
    // issue the 4 uint2 gathers first (edges 4q+quarter, channels 4*c16..+3)
    int s0 = (j16 < deg) ? eidx[r0 + j16] : eidx[r0];
    uint2 pv[4];
    #pragma unroll
    for (int q = 0; q < 4; ++q) {
        int s = __shfl(s0, 4 * q + quarter);
        pv[q] = *(const uint2*)(h3b + (size_t)s * C2 + 4 * c16);
    }
    float sv0 = (j16 < deg) ? lrelu(ssrc[s0] + sd) : -FLT_MAX;
    float mx = sv0;
    #pragma unroll
    for (int off = 1; off <= 8; off <<= 1) mx = fmaxf(mx, __shfl_xor(mx, off));
    for (int base = 16; base < deg; base += 16) {            // rare
        int j = base + j16;
        float sv = (j < deg) ? lrelu(ssrc[eidx[r0 + j]] + sd) : -FLT_MAX;
        #pragma unroll
        for (int off = 1; off <= 8; off <<= 1) sv = fmaxf(sv, __shfl_xor(sv, off));
        mx = fmaxf(mx, sv);
    }
    float w = (j16 < deg) ? __expf(sv0 - mx) : 0.f;
    float den = w;
    float a0 = 0.f, a1 = 0.f, a2 = 0.f, a3 = 0.f;
    #pragma unroll
    for (int q = 0; q < 4; ++q) {
        float wq = __shfl(w, 4 * q + quarter);
        a0 = fmaf(wq, bflo(pv[q].x), a0);
        a1 = fmaf(wq, bfhi(pv[q].x), a1);
        a2 = fmaf(wq, bflo(pv[q].y), a2);
        a3 = fmaf(wq, bfhi(pv[q].y), a3);
    }
    for (int base = 16; base < deg; base += 16) {            // rare
        int j = base + j16;
        int sreg = (j < deg) ? eidx[r0 + j] : eidx[r0];
        uint2 qv[4];
        #pragma unroll
        for (int q = 0; q < 4; ++q) {
            int s = __shfl(sreg, 4 * q + quarter);
            qv[q] = *(const uint2*)(h3b + (size_t)s * C2 + 4 * c16);
        }
        float wb = (j < deg) ? __expf(lrelu(ssrc[sreg] + sd) - mx) : 0.f;
        den += wb;
        #pragma unroll
        for (int q = 0; q < 4; ++q) {
            float wq = __shfl(wb, 4 * q + quarter);
            a0 = fmaf(wq, bflo(qv[q].x), a0);
            a1 = fmaf(wq, bfhi(qv[q].x), a1);
            a2 = fmaf(wq, bflo(qv[q].y), a2);
            a3 = fmaf(wq, bfhi(qv[q].y), a3);
        }
    }
    #pragma unroll
    for (int off = 1; off <= 8; off <<= 1) den += __shfl_xor(den, off);
    a0 += __shfl_xor(a0, 16); a0 += __shfl_xor(a0, 32);
    a1 += __shfl_xor(a1, 16); a1 += __shfl_xor(a1, 32);
    a2 += __shfl_xor(a2, 16); a2 += __shfl_xor(a2, 32);
    a3 += __shfl_xor(a3, 16); a3 += __shfl_xor(a3, 32);
    // every lane now holds full sums for channels 4*c16..4*c16+3
    float4 bv = *(const float4*)(b2p + 4 * c16);
    float rd = 1.f / den;
    float v0 = a0 * rd + bv.x, v1 = a1 * rd + bv.y;
    float v2 = a2 * rd + bv.z, v3 = a3 * rd + bv.w;
    // log_softmax over 64 channels, in-layout (reduce across c16 groups)
    float m4 = fmaxf(fmaxf(v0, v1), fmaxf(v2, v3));
    #pragma unroll
    for (int off = 1; off <= 8; off <<= 1) m4 = fmaxf(m4, __shfl_xor(m4, off));
    float se = __expf(v0 - m4) + __expf(v1 - m4) + __expf(v2 - m4) + __expf(v3 - m4);
    #pragma unroll
    for (int off = 1; off <= 8; off <<= 1) se += __shfl_xor(se, off);
    float lse = m4 + logf(se);
    if (quarter == 0) {
        *(float4*)(out + (size_t)n * C2 + 4 * c16) =
            make_float4(v0 - lse, v1 - lse, v2 - lse, v3 - lse);
    }
}

extern "C" void kernel_launch(void* const* d_in, const int* in_sizes, int n_in,
                              void* d_out, int out_size, void* d_ws, size_t ws_size,
                              hipStream_t stream) {
    const float* x   = (const float*)d_in[0];
    const int*   ei  = (const int*)d_in[1];
    const float* W1  = (const float*)d_in[2];
    const float* as1 = (const float*)d_in[3];
    const float* ad1 = (const float*)d_in[4];
    const float* b1  = (const float*)d_in[5];
    const float* W2  = (const float*)d_in[6];
    const float* as2 = (const float*)d_in[7];
    const float* ad2 = (const float*)d_in[8];
    const float* b2  = (const float*)d_in[9];
    const float* fcW = (const float*)d_in[10];
    const float* fcb = (const float*)d_in[11];
    float* out = (float*)d_out;

    float* ws = (float*)d_ws;
    size_t o = 0;
    u16* h1b   = (u16*)(ws + o); o += (size_t)NN * C1 / 2;  // bf16 [NN][128] (reused as h3b)
    float* hr1   = ws + o; o += (size_t)NN * C1;            // fp32 [NN][128]
    float* ssrc1 = ws + o; o += (size_t)NN * 4;
    float* sdst1 = ws + o; o += (size_t)NN * 4;
    float* ssrc2 = ws + o; o += NN;
    float* sdst2 = ws + o; o += NN;
    float* W2p   = ws + o; o += 128 * 64;
    float* usv   = ws + o; o += 128;
    float* udv   = ws + o; o += 128;
    float* b2p   = ws + o; o += 64;
    int* ip = (int*)(ws + o);
    int* cnt      = ip; ip += NN;
    int* pscan    = ip; ip += NN;
    int* bsum     = ip; ip += 512;
    int* boff     = ip; ip += 512;
    int* rowstart = ip; ip += NN + 2;
    int* cursor   = ip; ip += NN;
    int* eidx     = ip; ip += TE;
    u16* h3b = h1b;   // h1b dead after agg1; reuse for h3

    const int* esrc = ei;
    const int* edst = ei + EE;

    hipMemsetAsync(cnt, 0, (size_t)NN * sizeof(int), stream);

    // fold FC into layer-2 weights; score vectors from W2
    kprep<<<131, 64, 0, stream>>>(W2, as2, ad2, b2, fcW, fcb, W2p, usv, udv, b2p);

    // CSR build (self-loops synthesized in scan3)
    kc_count<<<(EE / 4 + 255) / 256, 256, 0, stream>>>(edst, cnt);
    kc_scan1<<<NBLK, 256, 0, stream>>>(cnt, pscan, bsum);
    kc_scan2<<<1, 512, 0, stream>>>(bsum, boff);
    kc_scan3<<<NBLK, 256, 0, stream>>>(pscan, boff, rowstart, cursor, eidx);
    kc_fill<<<(EE / 2 + 255) / 256, 256, 0, stream>>>(esrc, edst, cursor, eidx);

    // layer 1
    k1_gemm1<<<NB1, 512, 0, stream>>>(x, W1, as1, ad1, h1b, ssrc1, sdst1);
    agg1<<<(NN + 3) / 4, 256, 0, stream>>>(rowstart, eidx, ssrc1, sdst1, h1b, b1, hr1);
    // layer 2 (FC pre-folded)
    k5_gemm2p<<<NB1, 512, 0, stream>>>(hr1, W2p, usv, udv, h3b, ssrc2, sdst2);
    agg2ls<<<(NN + 3) / 4, 256, 0, stream>>>(rowstart, eidx, ssrc2, sdst2, h3b, b2p, out);
}

// Round 9
// 271.151 us; speedup vs baseline: 6.2335x; 1.3308x over previous
//
#include <hip/hip_runtime.h>
#include <hip/hip_bf16.h>
#include <cfloat>

#define NN 100000
#define EE 1000000
#define TE (EE + NN)   // edges incl. self loops
#define C1 128         // HEADS*HID
#define C2 64
#define NBLK 391       // ceil(NN/256)
#define NB1 782        // ceil(NN/128)

typedef unsigned short u16;
typedef unsigned int u32;
using bf16x8 = __attribute__((ext_vector_type(8))) short;
using f32x4  = __attribute__((ext_vector_type(4))) float;

__device__ __forceinline__ float lrelu(float v) { return v > 0.f ? v : 0.2f * v; }
__device__ __forceinline__ u16 f2bf(float f) {           // RNE f32 -> bf16 bits
    u32 b = __float_as_uint(f);
    b += 0x7fffu + ((b >> 16) & 1u);
    return (u16)(b >> 16);
}
__device__ __forceinline__ float bflo(u32 p) { return __uint_as_float(p << 16); }
__device__ __forceinline__ float bfhi(u32 p) { return __uint_as_float(p & 0xffff0000u); }

// ==== precompute: W2pbt = (W2@fcW)^T bf16, W1bt = W1^T bf16, us/ud, b2p ====
__global__ __launch_bounds__(64) void kprep(const float* __restrict__ W2,
    const float* __restrict__ as2, const float* __restrict__ ad2,
    const float* __restrict__ b2, const float* __restrict__ fcW,
    const float* __restrict__ fcb, const float* __restrict__ W1,
    u16* __restrict__ W2pbt, u16* __restrict__ W1bt,
    float* __restrict__ us, float* __restrict__ ud, float* __restrict__ b2p) {
    int b = blockIdx.x, t = threadIdx.x;
    if (b < 128) {                     // row b of W2p -> transposed bf16
        float s = 0.f;
        for (int k = 0; k < 64; ++k) s = fmaf(W2[b * 64 + k], fcW[k * 64 + t], s);
        W2pbt[t * 128 + b] = f2bf(s);
    } else if (b < 130) {
        int r = (b - 128) * 64 + t;
        float s = 0.f, d = 0.f;
        for (int k = 0; k < 64; ++k) {
            float wv = W2[r * 64 + k];
            s = fmaf(wv, as2[k], s);
            d = fmaf(wv, ad2[k], d);
        }
        us[r] = s; ud[r] = d;
    } else if (b == 130) {
        float s = fcb[t];
        for (int k = 0; k < 64; ++k) s = fmaf(b2[k], fcW[k * 64 + t], s);
        b2p[t] = s;
    } else {                           // b-131 = col c of W1 -> W1bt[c][k]
        int c = b - 131;
        W1bt[c * 128 + t]      = f2bf(W1[t * 128 + c]);
        W1bt[c * 128 + 64 + t] = f2bf(W1[(64 + t) * 128 + c]);
    }
}

// ================= CSR build (counting sort by dst) =================
__global__ __launch_bounds__(256) void kc_count(const int* __restrict__ edst,
                                                int* __restrict__ cnt) {
    int i = blockIdx.x * 256 + threadIdx.x;
    if (i >= EE / 4) return;
    int4 d = ((const int4*)edst)[i];
    atomicAdd(cnt + d.x, 1);
    atomicAdd(cnt + d.y, 1);
    atomicAdd(cnt + d.z, 1);
    atomicAdd(cnt + d.w, 1);
}

__global__ __launch_bounds__(256) void kc_scan1(const int* __restrict__ cnt,
                                                int* __restrict__ pscan,
                                                int* __restrict__ bsum) {
    __shared__ int sm[256];
    int tid = threadIdx.x;
    int i = blockIdx.x * 256 + tid;
    int v = (i < NN) ? (cnt[i] + 1) : 0;   // +1 = self loop
    sm[tid] = v;
    __syncthreads();
    for (int off = 1; off < 256; off <<= 1) {
        int o = 0;
        if (tid >= off) o = sm[tid - off];
        __syncthreads();
        if (tid >= off) sm[tid] += o;
        __syncthreads();
    }
    if (i < NN) pscan[i] = sm[tid] - v;
    if (tid == 255) bsum[blockIdx.x] = sm[255];
}

__global__ __launch_bounds__(512) void kc_scan2(const int* __restrict__ bsum,
                                                int* __restrict__ boff) {
    __shared__ int sm[512];
    int tid = threadIdx.x;
    int v = (tid < NBLK) ? bsum[tid] : 0;
    sm[tid] = v;
    __syncthreads();
    for (int off = 1; off < 512; off <<= 1) {
        int o = 0;
        if (tid >= off) o = sm[tid - off];
        __syncthreads();
        if (tid >= off) sm[tid] += o;
        __syncthreads();
    }
    if (tid < NBLK) boff[tid] = sm[tid] - v;
}

__global__ __launch_bounds__(256) void kc_scan3(const int* __restrict__ pscan,
                                                const int* __restrict__ boff,
                                                int* __restrict__ rowstart,
                                                int* __restrict__ cursor,
                                                int* __restrict__ eidx) {
    int i = blockIdx.x * 256 + threadIdx.x;
    if (i >= NN) return;
    int rs = pscan[i] + boff[blockIdx.x];
    rowstart[i] = rs;
    eidx[rs] = i;          // self loop occupies slot 0 of the segment
    cursor[i] = rs + 1;
    if (i == 0) rowstart[NN] = TE;
}

__global__ __launch_bounds__(256) void kc_fill(const int* __restrict__ esrc,
                                               const int* __restrict__ edst,
                                               int* __restrict__ cursor,
                                               int* __restrict__ eidx) {
    int i = blockIdx.x * 256 + threadIdx.x;
    if (i >= EE / 2) return;
    int2 s2 = ((const int2*)esrc)[i];
    int2 d2 = ((const int2*)edst)[i];
    int p0 = atomicAdd(cursor + d2.x, 1); eidx[p0] = s2.x;
    int p1 = atomicAdd(cursor + d2.y, 1); eidx[p1] = s2.y;
}

// ============ GEMM1 (MFMA): h1 = x @ W1, 128x128x128 per block ============
// 4 waves: wave (wr,wc) owns 64x64 quadrant; 16x16x32 bf16 MFMA, 4 k-steps.
__global__ __launch_bounds__(256, 1) void k1_mfma(const float* __restrict__ x,
    const u16* __restrict__ W1bt, u16* __restrict__ h1b) {
    __shared__ u16 As[128][136];   // A[row][k], +8 pad
    __shared__ u16 Bs[128][136];   // B^T: [col][k]
    int t = threadIdx.x;
    int rbase = blockIdx.x * 128;
    #pragma unroll
    for (int j = 0; j < 8; ++j) {          // stage W1^T (bf16, linear)
        int i = t + 256 * j, row = i >> 4, seg = i & 15;
        *reinterpret_cast<uint4*>(&Bs[row][seg * 8]) =
            *reinterpret_cast<const uint4*>(W1bt + row * 128 + seg * 8);
    }
    #pragma unroll
    for (int j = 0; j < 16; ++j) {         // stage x tile, fp32->bf16
        int i = t + 256 * j, row = i >> 5, c4 = i & 31;
        int gr = rbase + row; if (gr >= NN) gr = NN - 1;
        float4 v = *reinterpret_cast<const float4*>(x + (size_t)gr * 128 + c4 * 4);
        ushort4 o2 = make_ushort4(f2bf(v.x), f2bf(v.y), f2bf(v.z), f2bf(v.w));
        *reinterpret_cast<ushort4*>(&As[row][c4 * 4]) = o2;
    }
    __syncthreads();
    int lane = t & 63, wv = t >> 6, wr = wv >> 1, wc = wv & 1;
    int fr = lane & 15, fg = lane >> 4;
    f32x4 acc[4][4];
    #pragma unroll
    for (int m = 0; m < 4; ++m)
        #pragma unroll
        for (int n = 0; n < 4; ++n) acc[m][n] = (f32x4){0.f, 0.f, 0.f, 0.f};
    #pragma unroll
    for (int kk = 0; kk < 4; ++kk) {
        bf16x8 af[4], bfr[4];
        #pragma unroll
        for (int m = 0; m < 4; ++m)
            af[m] = *reinterpret_cast<const bf16x8*>(&As[wr * 64 + m * 16 + fr][kk * 32 + fg * 8]);
        #pragma unroll
        for (int n = 0; n < 4; ++n)
            bfr[n] = *reinterpret_cast<const bf16x8*>(&Bs[wc * 64 + n * 16 + fr][kk * 32 + fg * 8]);
        #pragma unroll
        for (int m = 0; m < 4; ++m)
            #pragma unroll
            for (int n = 0; n < 4; ++n)
                acc[m][n] = __builtin_amdgcn_mfma_f32_16x16x32_bf16(af[m], bfr[n], acc[m][n], 0, 0, 0);
    }
    #pragma unroll
    for (int m = 0; m < 4; ++m)
        #pragma unroll
        for (int r = 0; r < 4; ++r) {
            int row = rbase + wr * 64 + m * 16 + fg * 4 + r;
            if (row < NN) {
                #pragma unroll
                for (int n = 0; n < 4; ++n)
                    h1b[(size_t)row * 128 + wc * 64 + n * 16 + fr] = f2bf(acc[m][n][r]);
            }
        }
}

// ======== layer-1 attention scores from h1b (4 heads x 32 ch) ========
__global__ __launch_bounds__(256) void kscore1(const u16* __restrict__ h1b,
    const float* __restrict__ as1, const float* __restrict__ ad1,
    float* __restrict__ ssrc, float* __restrict__ sdst) {
    __shared__ float asl[128], adl[128];
    if (threadIdx.x < 128) { asl[threadIdx.x] = as1[threadIdx.x]; adl[threadIdx.x] = ad1[threadIdx.x]; }
    __syncthreads();
    int g = blockIdx.x * 256 + threadIdx.x;
    if (g >= NN * 4) return;
    int row = g >> 2, h = g & 3;
    const u16* hp = h1b + (size_t)row * 128 + h * 32;
    float ps = 0.f, pd = 0.f;
    #pragma unroll
    for (int q = 0; q < 4; ++q) {
        uint4 pk = *reinterpret_cast<const uint4*>(hp + q * 8);
        u32 wsv[4] = {pk.x, pk.y, pk.z, pk.w};
        #pragma unroll
        for (int e = 0; e < 4; ++e) {
            int c = h * 32 + q * 8 + e * 2;
            float lo = bflo(wsv[e]), hi = bfhi(wsv[e]);
            ps = fmaf(lo, asl[c], ps); ps = fmaf(hi, asl[c + 1], ps);
            pd = fmaf(lo, adl[c], pd); pd = fmaf(hi, adl[c + 1], pd);
        }
    }
    ssrc[g] = ps;
    sdst[g] = pd;
}

// ====== Aggregation layer 1 + layer-2 scores; writes bf16 hrb ======
__global__ __launch_bounds__(256) void agg1(const int* __restrict__ rowstart,
    const int* __restrict__ eidx, const float* __restrict__ ssrc,
    const float* __restrict__ sdst, const u16* __restrict__ h1b,
    const float* __restrict__ b1, const float* __restrict__ usv,
    const float* __restrict__ udv, u16* __restrict__ hrb,
    float* __restrict__ ssrc2, float* __restrict__ sdst2) {
    int lane = threadIdx.x & 63;
    int n = blockIdx.x * 4 + (threadIdx.x >> 6);
    if (n >= NN) return;
    int r0 = rowstart[n], deg = rowstart[n + 1] - r0;
    int h4 = lane >> 4, j16 = lane & 15;
    int half = lane >> 5, c = lane & 31, hh = c >> 3;
    float sd = sdst[n * 4 + h4];
    int s0 = (j16 < deg) ? eidx[r0 + j16] : eidx[r0];
    uint2 pv[8];
    #pragma unroll
    for (int q = 0; q < 8; ++q) {
        int s = __shfl(s0, 2 * q + half);
        pv[q] = *(const uint2*)(h1b + (size_t)s * C1 + 4 * c);
    }
    float sv0 = (j16 < deg) ? lrelu(ssrc[s0 * 4 + h4] + sd) : -FLT_MAX;
    float mx = sv0;
    #pragma unroll
    for (int off = 1; off <= 8; off <<= 1) mx = fmaxf(mx, __shfl_xor(mx, off));
    for (int base = 16; base < deg; base += 16) {            // rare (deg>16)
        int j = base + j16;
        float sv = (j < deg) ? lrelu(ssrc[eidx[r0 + j] * 4 + h4] + sd) : -FLT_MAX;
        #pragma unroll
        for (int off = 1; off <= 8; off <<= 1) sv = fmaxf(sv, __shfl_xor(sv, off));
        mx = fmaxf(mx, sv);
    }
    float w = (j16 < deg) ? __expf(sv0 - mx) : 0.f;
    float den = w;
    float a0 = 0.f, a1 = 0.f, a2 = 0.f, a3 = 0.f;
    #pragma unroll
    for (int q = 0; q < 8; ++q) {
        float wq = __shfl(w, (hh << 4) + 2 * q + half);
        a0 = fmaf(wq, bflo(pv[q].x), a0);
        a1 = fmaf(wq, bfhi(pv[q].x), a1);
        a2 = fmaf(wq, bflo(pv[q].y), a2);
        a3 = fmaf(wq, bfhi(pv[q].y), a3);
    }
    for (int base = 16; base < deg; base += 16) {            // rare (deg>16)
        int j = base + j16;
        int sreg = (j < deg) ? eidx[r0 + j] : eidx[r0];
        uint2 qv[8];
        #pragma unroll
        for (int q = 0; q < 8; ++q) {
            int s = __shfl(sreg, 2 * q + half);
            qv[q] = *(const uint2*)(h1b + (size_t)s * C1 + 4 * c);
        }
        float wb = (j < deg) ? __expf(lrelu(ssrc[sreg * 4 + h4] + sd) - mx) : 0.f;
        den += wb;
        #pragma unroll
        for (int q = 0; q < 8; ++q) {
            float wq = __shfl(wb, (hh << 4) + 2 * q + half);
            a0 = fmaf(wq, bflo(qv[q].x), a0);
            a1 = fmaf(wq, bfhi(qv[q].x), a1);
            a2 = fmaf(wq, bflo(qv[q].y), a2);
            a3 = fmaf(wq, bfhi(qv[q].y), a3);
        }
    }
    #pragma unroll
    for (int off = 1; off <= 8; off <<= 1) den += __shfl_xor(den, off);
    float dh = __shfl(den, hh << 4);
    a0 += __shfl_xor(a0, 32);
    a1 += __shfl_xor(a1, 32);
    a2 += __shfl_xor(a2, 32);
    a3 += __shfl_xor(a3, 32);
    float4 bv = *(const float4*)(b1 + 4 * c);
    float rv = 1.f / dh;
    float v0 = fmaf(a0, rv, bv.x); v0 = v0 > 0.f ? v0 : 0.f;
    float v1 = fmaf(a1, rv, bv.y); v1 = v1 > 0.f ? v1 : 0.f;
    float v2 = fmaf(a2, rv, bv.z); v2 = v2 > 0.f ? v2 : 0.f;
    float v3 = fmaf(a3, rv, bv.w); v3 = v3 > 0.f ? v3 : 0.f;
    // layer-2 scores: dot(relu_h, us/ud) over 128 channels (32-lane reduce)
    float4 u_s = *(const float4*)(usv + 4 * c);
    float4 u_d = *(const float4*)(udv + 4 * c);
    float ps = v0 * u_s.x + v1 * u_s.y + v2 * u_s.z + v3 * u_s.w;
    float pd = v0 * u_d.x + v1 * u_d.y + v2 * u_d.z + v3 * u_d.w;
    #pragma unroll
    for (int off = 1; off <= 16; off <<= 1) {
        ps += __shfl_xor(ps, off); pd += __shfl_xor(pd, off);
    }
    if (lane == 0) { ssrc2[n] = ps; sdst2[n] = pd; }
    if (half == 0) {
        ushort4 hs = make_ushort4(f2bf(v0), f2bf(v1), f2bf(v2), f2bf(v3));
        *reinterpret_cast<ushort4*>(hrb + (size_t)n * C1 + 4 * c) = hs;
    }
}

// ============ GEMM2 (MFMA): h3 = hrb @ (W2@fcW), 128x64x128 per block ============
__global__ __launch_bounds__(256, 1) void k5_mfma(const u16* __restrict__ hrb,
    const u16* __restrict__ W2pbt, u16* __restrict__ h3b) {
    __shared__ u16 As[128][136];
    __shared__ u16 Bs[64][136];
    int t = threadIdx.x;
    int rbase = blockIdx.x * 128;
    #pragma unroll
    for (int j = 0; j < 4; ++j) {          // stage (W2@fcW)^T bf16
        int i = t + 256 * j, row = i >> 4, seg = i & 15;
        *reinterpret_cast<uint4*>(&Bs[row][seg * 8]) =
            *reinterpret_cast<const uint4*>(W2pbt + row * 128 + seg * 8);
    }
    #pragma unroll
    for (int j = 0; j < 8; ++j) {          // stage hrb tile (bf16, linear)
        int i = t + 256 * j, row = i >> 4, seg = i & 15;
        int gr = rbase + row; if (gr >= NN) gr = NN - 1;
        *reinterpret_cast<uint4*>(&As[row][seg * 8]) =
            *reinterpret_cast<const uint4*>(hrb + (size_t)gr * 128 + seg * 8);
    }
    __syncthreads();
    int lane = t & 63, wv = t >> 6, wr = wv >> 1, wc = wv & 1;
    int fr = lane & 15, fg = lane >> 4;
    f32x4 acc[4][2];
    #pragma unroll
    for (int m = 0; m < 4; ++m)
        #pragma unroll
        for (int n = 0; n < 2; ++n) acc[m][n] = (f32x4){0.f, 0.f, 0.f, 0.f};
    #pragma unroll
    for (int kk = 0; kk < 4; ++kk) {
        bf16x8 af[4], bfr[2];
        #pragma unroll
        for (int m = 0; m < 4; ++m)
            af[m] = *reinterpret_cast<const bf16x8*>(&As[wr * 64 + m * 16 + fr][kk * 32 + fg * 8]);
        #pragma unroll
        for (int n = 0; n < 2; ++n)
            bfr[n] = *reinterpret_cast<const bf16x8*>(&Bs[wc * 32 + n * 16 + fr][kk * 32 + fg * 8]);
        #pragma unroll
        for (int m = 0; m < 4; ++m)
            #pragma unroll
            for (int n = 0; n < 2; ++n)
                acc[m][n] = __builtin_amdgcn_mfma_f32_16x16x32_bf16(af[m], bfr[n], acc[m][n], 0, 0, 0);
    }
    #pragma unroll
    for (int m = 0; m < 4; ++m)
        #pragma unroll
        for (int r = 0; r < 4; ++r) {
            int row = rbase + wr * 64 + m * 16 + fg * 4 + r;
            if (row < NN) {
                #pragma unroll
                for (int n = 0; n < 2; ++n)
                    h3b[(size_t)row * 64 + wc * 32 + n * 16 + fr] = f2bf(acc[m][n][r]);
            }
        }
}

// ====== Aggregation layer 2 + log_softmax (FC pre-folded into h3) ======
__global__ __launch_bounds__(256) void agg2ls(const int* __restrict__ rowstart,
    const int* __restrict__ eidx, const float* __restrict__ ssrc,
    const float* __restrict__ sdst, const u16* __restrict__ h3b,
    const float* __restrict__ b2p, float* __restrict__ out) {
    int lane = threadIdx.x & 63;
    int n = blockIdx.x * 4 + (threadIdx.x >> 6);
    if (n >= NN) return;
    int r0 = rowstart[n], deg = rowstart[n + 1] - r0;
    int j16 = lane & 15, quarter = lane >> 4, c16 = lane & 15;
    float sd = sdst[n];
    int s0 = (j16 < deg) ? eidx[r0 + j16] : eidx[r0];
    uint2 pv[4];
    #pragma unroll
    for (int q = 0; q < 4; ++q) {
        int s = __shfl(s0, 4 * q + quarter);
        pv[q] = *(const uint2*)(h3b + (size_t)s * C2 + 4 * c16);
    }
    float sv0 = (j16 < deg) ? lrelu(ssrc[s0] + sd) : -FLT_MAX;
    float mx = sv0;
    #pragma unroll
    for (int off = 1; off <= 8; off <<= 1) mx = fmaxf(mx, __shfl_xor(mx, off));
    for (int base = 16; base < deg; base += 16) {            // rare
        int j = base + j16;
        float sv = (j < deg) ? lrelu(ssrc[eidx[r0 + j]] + sd) : -FLT_MAX;
        #pragma unroll
        for (int off = 1; off <= 8; off <<= 1) sv = fmaxf(sv, __shfl_xor(sv, off));
        mx = fmaxf(mx, sv);
    }
    float w = (j16 < deg) ? __expf(sv0 - mx) : 0.f;
    float den = w;
    float a0 = 0.f, a1 = 0.f, a2 = 0.f, a3 = 0.f;
    #pragma unroll
    for (int q = 0; q < 4; ++q) {
        float wq = __shfl(w, 4 * q + quarter);
        a0 = fmaf(wq, bflo(pv[q].x), a0);
        a1 = fmaf(wq, bfhi(pv[q].x), a1);
        a2 = fmaf(wq, bflo(pv[q].y), a2);
        a3 = fmaf(wq, bfhi(pv[q].y), a3);
    }
    for (int base = 16; base < deg; base += 16) {            // rare
        int j = base + j16;
        int sreg = (j < deg) ? eidx[r0 + j] : eidx[r0];
        uint2 qv[4];
        #pragma unroll
        for (int q = 0; q < 4; ++q) {
            int s = __shfl(sreg, 4 * q + quarter);
            qv[q] = *(const uint2*)(h3b + (size_t)s * C2 + 4 * c16);
        }
        float wb = (j < deg) ? __expf(lrelu(ssrc[sreg] + sd) - mx) : 0.f;
        den += wb;
        #pragma unroll
        for (int q = 0; q < 4; ++q) {
            float wq = __shfl(wb, 4 * q + quarter);
            a0 = fmaf(wq, bflo(qv[q].x), a0);
            a1 = fmaf(wq, bfhi(qv[q].x), a1);
            a2 = fmaf(wq, bflo(qv[q].y), a2);
            a3 = fmaf(wq, bfhi(qv[q].y), a3);
        }
    }
    #pragma unroll
    for (int off = 1; off <= 8; off <<= 1) den += __shfl_xor(den, off);
    a0 += __shfl_xor(a0, 16); a0 += __shfl_xor(a0, 32);
    a1 += __shfl_xor(a1, 16); a1 += __shfl_xor(a1, 32);
    a2 += __shfl_xor(a2, 16); a2 += __shfl_xor(a2, 32);
    a3 += __shfl_xor(a3, 16); a3 += __shfl_xor(a3, 32);
    float4 bv = *(const float4*)(b2p + 4 * c16);
    float rd = 1.f / den;
    float v0 = a0 * rd + bv.x, v1 = a1 * rd + bv.y;
    float v2 = a2 * rd + bv.z, v3 = a3 * rd + bv.w;
    float m4 = fmaxf(fmaxf(v0, v1), fmaxf(v2, v3));
    #pragma unroll
    for (int off = 1; off <= 8; off <<= 1) m4 = fmaxf(m4, __shfl_xor(m4, off));
    float se = __expf(v0 - m4) + __expf(v1 - m4) + __expf(v2 - m4) + __expf(v3 - m4);
    #pragma unroll
    for (int off = 1; off <= 8; off <<= 1) se += __shfl_xor(se, off);
    float lse = m4 + logf(se);
    if (quarter == 0) {
        *(float4*)(out + (size_t)n * C2 + 4 * c16) =
            make_float4(v0 - lse, v1 - lse, v2 - lse, v3 - lse);
    }
}

extern "C" void kernel_launch(void* const* d_in, const int* in_sizes, int n_in,
                              void* d_out, int out_size, void* d_ws, size_t ws_size,
                              hipStream_t stream) {
    const float* x   = (const float*)d_in[0];
    const int*   ei  = (const int*)d_in[1];
    const float* W1  = (const float*)d_in[2];
    const float* as1 = (const float*)d_in[3];
    const float* ad1 = (const float*)d_in[4];
    const float* b1  = (const float*)d_in[5];
    const float* W2  = (const float*)d_in[6];
    const float* as2 = (const float*)d_in[7];
    const float* ad2 = (const float*)d_in[8];
    const float* b2  = (const float*)d_in[9];
    const float* fcW = (const float*)d_in[10];
    const float* fcb = (const float*)d_in[11];
    float* out = (float*)d_out;

    float* ws = (float*)d_ws;
    size_t o = 0;
    u16* h1b   = (u16*)(ws + o); o += (size_t)NN * C1 / 2;  // bf16 [NN][128] (reused as h3b)
    u16* hrb   = (u16*)(ws + o); o += (size_t)NN * C1 / 2;  // bf16 [NN][128]
    float* ssrc1 = ws + o; o += (size_t)NN * 4;
    float* sdst1 = ws + o; o += (size_t)NN * 4;
    float* ssrc2 = ws + o; o += NN;
    float* sdst2 = ws + o; o += NN;
    float* usv   = ws + o; o += 128;
    float* udv   = ws + o; o += 128;
    float* b2p   = ws + o; o += 64;
    u16* W2pbt = (u16*)(ws + o); o += 64 * 128 / 2;
    u16* W1bt  = (u16*)(ws + o); o += 128 * 128 / 2;
    int* ip = (int*)(ws + o);
    int* cnt      = ip; ip += NN;
    int* pscan    = ip; ip += NN;
    int* bsum     = ip; ip += 512;
    int* boff     = ip; ip += 512;
    int* rowstart = ip; ip += NN + 2;
    int* cursor   = ip; ip += NN;
    int* eidx     = ip; ip += TE;
    u16* h3b = h1b;   // h1b dead after agg1; reuse for h3

    const int* esrc = ei;
    const int* edst = ei + EE;

    hipMemsetAsync(cnt, 0, (size_t)NN * sizeof(int), stream);

    // fold FC into layer-2 weights; bf16-transposed weight copies
    kprep<<<259, 64, 0, stream>>>(W2, as2, ad2, b2, fcW, fcb, W1,
                                  W2pbt, W1bt, usv, udv, b2p);

    // CSR build (self-loops synthesized in scan3)
    kc_count<<<(EE / 4 + 255) / 256, 256, 0, stream>>>(edst, cnt);
    kc_scan1<<<NBLK, 256, 0, stream>>>(cnt, pscan, bsum);
    kc_scan2<<<1, 512, 0, stream>>>(bsum, boff);
    kc_scan3<<<NBLK, 256, 0, stream>>>(pscan, boff, rowstart, cursor, eidx);
    kc_fill<<<(EE / 2 + 255) / 256, 256, 0, stream>>>(esrc, edst, cursor, eidx);

    // layer 1
    k1_mfma<<<NB1, 256, 0, stream>>>(x, W1bt, h1b);
    kscore1<<<(NN * 4 + 255) / 256, 256, 0, stream>>>(h1b, as1, ad1, ssrc1, sdst1);
    agg1<<<(NN + 3) / 4, 256, 0, stream>>>(rowstart, eidx, ssrc1, sdst1, h1b, b1,
                                           usv, udv, hrb, ssrc2, sdst2);
    // layer 2 (FC pre-folded)
    k5_mfma<<<NB1, 256, 0, stream>>>(hrb, W2pbt, h3b);
    agg2ls<<<(NN + 3) / 4, 256, 0, stream>>>(rowstart, eidx, ssrc2, sdst2, h3b, b2p, out);
}

// Round 10
// 212.532 us; speedup vs baseline: 7.9527x; 1.2758x over previous
//
#include <hip/hip_runtime.h>
#include <hip/hip_bf16.h>
#include <cfloat>

#define NN 100000
#define EE 1000000
#define TE (EE + NN)   // edges incl. self loops
#define C1 128         // HEADS*HID
#define C2 64
#define NB1 782        // ceil(NN/128)
#define NBKT 782       // buckets of 128 dst nodes
#define BCAP 4096      // per-bucket edge capacity (expected ~1280)

typedef unsigned short u16;
typedef unsigned int u32;
using bf16x8 = __attribute__((ext_vector_type(8))) short;
using f32x4  = __attribute__((ext_vector_type(4))) float;

__device__ __forceinline__ float lrelu(float v) { return v > 0.f ? v : 0.2f * v; }
__device__ __forceinline__ u16 f2bf(float f) {           // RNE f32 -> bf16 bits
    u32 b = __float_as_uint(f);
    b += 0x7fffu + ((b >> 16) & 1u);
    return (u16)(b >> 16);
}
__device__ __forceinline__ float bflo(u32 p) { return __uint_as_float(p << 16); }
__device__ __forceinline__ float bfhi(u32 p) { return __uint_as_float(p & 0xffff0000u); }

// ==== precompute: W2pbt = (W2@fcW)^T bf16, W1bt = W1^T bf16, us/ud, b2p ====
__global__ __launch_bounds__(64) void kprep(const float* __restrict__ W2,
    const float* __restrict__ as2, const float* __restrict__ ad2,
    const float* __restrict__ b2, const float* __restrict__ fcW,
    const float* __restrict__ fcb, const float* __restrict__ W1,
    u16* __restrict__ W2pbt, u16* __restrict__ W1bt,
    float* __restrict__ us, float* __restrict__ ud, float* __restrict__ b2p) {
    int b = blockIdx.x, t = threadIdx.x;
    if (b < 128) {                     // row b of W2p -> transposed bf16
        float s = 0.f;
        for (int k = 0; k < 64; ++k) s = fmaf(W2[b * 64 + k], fcW[k * 64 + t], s);
        W2pbt[t * 128 + b] = f2bf(s);
    } else if (b < 130) {
        int r = (b - 128) * 64 + t;
        float s = 0.f, d = 0.f;
        for (int k = 0; k < 64; ++k) {
            float wv = W2[r * 64 + k];
            s = fmaf(wv, as2[k], s);
            d = fmaf(wv, ad2[k], d);
        }
        us[r] = s; ud[r] = d;
    } else if (b == 130) {
        float s = fcb[t];
        for (int k = 0; k < 64; ++k) s = fmaf(b2[k], fcW[k * 64 + t], s);
        b2p[t] = s;
    } else {                           // b-131 = col c of W1 -> W1bt[c][k]
        int c = b - 131;
        W1bt[c * 128 + t]      = f2bf(W1[t * 128 + c]);
        W1bt[c * 128 + 64 + t] = f2bf(W1[(64 + t) * 128 + c]);
    }
}

// ========== CSR build, bucketed (2 passes; no random-line HBM traffic) ==========
// Pass A: scatter edges into dst/128 buckets. bcnt padded 1 counter / 64B line.
__global__ __launch_bounds__(256) void kpassA(const int* __restrict__ esrc,
    const int* __restrict__ edst, int* __restrict__ bcnt, u32* __restrict__ bbuf) {
    int i = blockIdx.x * 256 + threadIdx.x;
    if (i >= EE / 4) return;
    int4 s4 = ((const int4*)esrc)[i];
    int4 d4 = ((const int4*)edst)[i];
    int d, s, b, pos;
    d = d4.x; s = s4.x; b = d >> 7;
    pos = atomicAdd(bcnt + b * 16, 1);
    if (pos < BCAP) bbuf[(size_t)b * BCAP + pos] = (u32)s | ((u32)(d & 127) << 17);
    d = d4.y; s = s4.y; b = d >> 7;
    pos = atomicAdd(bcnt + b * 16, 1);
    if (pos < BCAP) bbuf[(size_t)b * BCAP + pos] = (u32)s | ((u32)(d & 127) << 17);
    d = d4.z; s = s4.z; b = d >> 7;
    pos = atomicAdd(bcnt + b * 16, 1);
    if (pos < BCAP) bbuf[(size_t)b * BCAP + pos] = (u32)s | ((u32)(d & 127) << 17);
    d = d4.w; s = s4.w; b = d >> 7;
    pos = atomicAdd(bcnt + b * 16, 1);
    if (pos < BCAP) bbuf[(size_t)b * BCAP + pos] = (u32)s | ((u32)(d & 127) << 17);
}

// scan of (bucket edges + bucket self-loops) -> bucket base offsets in eidx
__global__ __launch_bounds__(1024) void kbscan(const int* __restrict__ bcnt,
                                               int* __restrict__ bbase) {
    __shared__ int sm[1024];
    int t = threadIdx.x;
    int v = 0;
    if (t < NBKT) {
        int node0 = t * 128;
        int nn = NN - node0; if (nn > 128) nn = 128;
        int m = bcnt[t * 16]; if (m > BCAP) m = BCAP;
        v = m + nn;
    }
    sm[t] = v;
    __syncthreads();
    for (int off = 1; off < 1024; off <<= 1) {
        int o = 0;
        if (t >= off) o = sm[t - off];
        __syncthreads();
        if (t >= off) sm[t] += o;
        __syncthreads();
    }
    if (t < NBKT) bbase[t] = sm[t] - v;
}

// Pass B: per bucket - LDS degree count, scan, LDS scatter, coalesced eidx write.
__global__ __launch_bounds__(256) void kpassB(const int* __restrict__ bcnt,
    const int* __restrict__ bbase, const u32* __restrict__ bbuf,
    int* __restrict__ rowstart, int* __restrict__ eidx) {
    __shared__ int deg[128], lsc[128], cur[128];
    __shared__ int elocal[BCAP + 128];
    int b = blockIdx.x, t = threadIdx.x;
    int node0 = b * 128;
    int nNodes = NN - node0; if (nNodes > 128) nNodes = 128;
    int M = bcnt[b * 16]; if (M > BCAP) M = BCAP;
    int base = bbase[b];
    if (t < 128) deg[t] = 0;
    __syncthreads();
    const u32* bp = bbuf + (size_t)b * BCAP;
    for (int i = t; i < M; i += 256) atomicAdd(&deg[bp[i] >> 17], 1);
    __syncthreads();
    int v = 0;
    if (t < 128) { v = (t < nNodes) ? (1 + deg[t]) : 0; lsc[t] = v; }
    __syncthreads();
    for (int off = 1; off < 128; off <<= 1) {
        int o = 0;
        if (t < 128 && t >= off) o = lsc[t - off];
        __syncthreads();
        if (t < 128 && t >= off) lsc[t] += o;
        __syncthreads();
    }
    if (t < nNodes) {
        int st = lsc[t] - v;              // exclusive
        rowstart[node0 + t] = base + st;
        elocal[st] = node0 + t;           // self loop in slot 0
        cur[t] = st + 1;
    }
    if (b == NBKT - 1 && t == 0) rowstart[NN] = TE;
    __syncthreads();
    for (int i = t; i < M; i += 256) {
        u32 p = bp[i];
        int pos = atomicAdd(&cur[p >> 17], 1);
        elocal[pos] = (int)(p & 0x1FFFFu);
    }
    __syncthreads();
    int total = M + nNodes;
    for (int i = t; i < total; i += 256) eidx[base + i] = elocal[i];
}

// ============ GEMM1 (MFMA): h1 = x @ W1, 128x128x128 per block ============
__global__ __launch_bounds__(256, 1) void k1_mfma(const float* __restrict__ x,
    const u16* __restrict__ W1bt, u16* __restrict__ h1b) {
    __shared__ u16 As[128][136];   // A[row][k], +8 pad
    __shared__ u16 Bs[128][136];   // B^T: [col][k]
    int t = threadIdx.x;
    int rbase = blockIdx.x * 128;
    #pragma unroll
    for (int j = 0; j < 8; ++j) {          // stage W1^T (bf16, linear)
        int i = t + 256 * j, row = i >> 4, seg = i & 15;
        *reinterpret_cast<uint4*>(&Bs[row][seg * 8]) =
            *reinterpret_cast<const uint4*>(W1bt + row * 128 + seg * 8);
    }
    #pragma unroll
    for (int j = 0; j < 16; ++j) {         // stage x tile, fp32->bf16
        int i = t + 256 * j, row = i >> 5, c4 = i & 31;
        int gr = rbase + row; if (gr >= NN) gr = NN - 1;
        float4 v = *reinterpret_cast<const float4*>(x + (size_t)gr * 128 + c4 * 4);
        ushort4 o2 = make_ushort4(f2bf(v.x), f2bf(v.y), f2bf(v.z), f2bf(v.w));
        *reinterpret_cast<ushort4*>(&As[row][c4 * 4]) = o2;
    }
    __syncthreads();
    int lane = t & 63, wv = t >> 6, wr = wv >> 1, wc = wv & 1;
    int fr = lane & 15, fg = lane >> 4;
    f32x4 acc[4][4];
    #pragma unroll
    for (int m = 0; m < 4; ++m)
        #pragma unroll
        for (int n = 0; n < 4; ++n) acc[m][n] = (f32x4){0.f, 0.f, 0.f, 0.f};
    #pragma unroll
    for (int kk = 0; kk < 4; ++kk) {
        bf16x8 af[4], bfr[4];
        #pragma unroll
        for (int m = 0; m < 4; ++m)
            af[m] = *reinterpret_cast<const bf16x8*>(&As[wr * 64 + m * 16 + fr][kk * 32 + fg * 8]);
        #pragma unroll
        for (int n = 0; n < 4; ++n)
            bfr[n] = *reinterpret_cast<const bf16x8*>(&Bs[wc * 64 + n * 16 + fr][kk * 32 + fg * 8]);
        #pragma unroll
        for (int m = 0; m < 4; ++m)
            #pragma unroll
            for (int n = 0; n < 4; ++n)
                acc[m][n] = __builtin_amdgcn_mfma_f32_16x16x32_bf16(af[m], bfr[n], acc[m][n], 0, 0, 0);
    }
    #pragma unroll
    for (int m = 0; m < 4; ++m)
        #pragma unroll
        for (int r = 0; r < 4; ++r) {
            int row = rbase + wr * 64 + m * 16 + fg * 4 + r;
            if (row < NN) {
                #pragma unroll
                for (int n = 0; n < 4; ++n)
                    h1b[(size_t)row * 128 + wc * 64 + n * 16 + fr] = f2bf(acc[m][n][r]);
            }
        }
}

// ======== layer-1 attention scores from h1b (4 heads x 32 ch) ========
__global__ __launch_bounds__(256) void kscore1(const u16* __restrict__ h1b,
    const float* __restrict__ as1, const float* __restrict__ ad1,
    float* __restrict__ ssrc, float* __restrict__ sdst) {
    __shared__ float asl[128], adl[128];
    if (threadIdx.x < 128) { asl[threadIdx.x] = as1[threadIdx.x]; adl[threadIdx.x] = ad1[threadIdx.x]; }
    __syncthreads();
    int g = blockIdx.x * 256 + threadIdx.x;
    if (g >= NN * 4) return;
    int row = g >> 2, h = g & 3;
    const u16* hp = h1b + (size_t)row * 128 + h * 32;
    float ps = 0.f, pd = 0.f;
    #pragma unroll
    for (int q = 0; q < 4; ++q) {
        uint4 pk = *reinterpret_cast<const uint4*>(hp + q * 8);
        u32 wsv[4] = {pk.x, pk.y, pk.z, pk.w};
        #pragma unroll
        for (int e = 0; e < 4; ++e) {
            int c = h * 32 + q * 8 + e * 2;
            float lo = bflo(wsv[e]), hi = bfhi(wsv[e]);
            ps = fmaf(lo, asl[c], ps); ps = fmaf(hi, asl[c + 1], ps);
            pd = fmaf(lo, adl[c], pd); pd = fmaf(hi, adl[c + 1], pd);
        }
    }
    ssrc[g] = ps;
    sdst[g] = pd;
}

// ====== Aggregation layer 1 + layer-2 scores; writes bf16 hrb ======
__global__ __launch_bounds__(256) void agg1(const int* __restrict__ rowstart,
    const int* __restrict__ eidx, const float* __restrict__ ssrc,
    const float* __restrict__ sdst, const u16* __restrict__ h1b,
    const float* __restrict__ b1, const float* __restrict__ usv,
    const float* __restrict__ udv, u16* __restrict__ hrb,
    float* __restrict__ ssrc2, float* __restrict__ sdst2) {
    int lane = threadIdx.x & 63;
    int n = blockIdx.x * 4 + (threadIdx.x >> 6);
    if (n >= NN) return;
    int r0 = rowstart[n], deg = rowstart[n + 1] - r0;
    int h4 = lane >> 4, j16 = lane & 15;
    int half = lane >> 5, c = lane & 31, hh = c >> 3;
    float sd = sdst[n * 4 + h4];
    int s0 = (j16 < deg) ? eidx[r0 + j16] : eidx[r0];
    uint2 pv[8];
    #pragma unroll
    for (int q = 0; q < 8; ++q) {
        int s = __shfl(s0, 2 * q + half);
        pv[q] = *(const uint2*)(h1b + (size_t)s * C1 + 4 * c);
    }
    float sv0 = (j16 < deg) ? lrelu(ssrc[s0 * 4 + h4] + sd) : -FLT_MAX;
    float mx = sv0;
    #pragma unroll
    for (int off = 1; off <= 8; off <<= 1) mx = fmaxf(mx, __shfl_xor(mx, off));
    for (int base = 16; base < deg; base += 16) {            // rare (deg>16)
        int j = base + j16;
        float sv = (j < deg) ? lrelu(ssrc[eidx[r0 + j] * 4 + h4] + sd) : -FLT_MAX;
        #pragma unroll
        for (int off = 1; off <= 8; off <<= 1) sv = fmaxf(sv, __shfl_xor(sv, off));
        mx = fmaxf(mx, sv);
    }
    float w = (j16 < deg) ? __expf(sv0 - mx) : 0.f;
    float den = w;
    float a0 = 0.f, a1 = 0.f, a2 = 0.f, a3 = 0.f;
    #pragma unroll
    for (int q = 0; q < 8; ++q) {
        float wq = __shfl(w, (hh << 4) + 2 * q + half);
        a0 = fmaf(wq, bflo(pv[q].x), a0);
        a1 = fmaf(wq, bfhi(pv[q].x), a1);
        a2 = fmaf(wq, bflo(pv[q].y), a2);
        a3 = fmaf(wq, bfhi(pv[q].y), a3);
    }
    for (int base = 16; base < deg; base += 16) {            // rare (deg>16)
        int j = base + j16;
        int sreg = (j < deg) ? eidx[r0 + j] : eidx[r0];
        uint2 qv[8];
        #pragma unroll
        for (int q = 0; q < 8; ++q) {
            int s = __shfl(sreg, 2 * q + half);
            qv[q] = *(const uint2*)(h1b + (size_t)s * C1 + 4 * c);
        }
        float wb = (j < deg) ? __expf(lrelu(ssrc[sreg * 4 + h4] + sd) - mx) : 0.f;
        den += wb;
        #pragma unroll
        for (int q = 0; q < 8; ++q) {
            float wq = __shfl(wb, (hh << 4) + 2 * q + half);
            a0 = fmaf(wq, bflo(qv[q].x), a0);
            a1 = fmaf(wq, bfhi(qv[q].x), a1);
            a2 = fmaf(wq, bflo(qv[q].y), a2);
            a3 = fmaf(wq, bfhi(qv[q].y), a3);
        }
    }
    #pragma unroll
    for (int off = 1; off <= 8; off <<= 1) den += __shfl_xor(den, off);
    float dh = __shfl(den, hh << 4);
    a0 += __shfl_xor(a0, 32);
    a1 += __shfl_xor(a1, 32);
    a2 += __shfl_xor(a2, 32);
    a3 += __shfl_xor(a3, 32);
    float4 bv = *(const float4*)(b1 + 4 * c);
    float rv = 1.f / dh;
    float v0 = fmaf(a0, rv, bv.x); v0 = v0 > 0.f ? v0 : 0.f;
    float v1 = fmaf(a1, rv, bv.y); v1 = v1 > 0.f ? v1 : 0.f;
    float v2 = fmaf(a2, rv, bv.z); v2 = v2 > 0.f ? v2 : 0.f;
    float v3 = fmaf(a3, rv, bv.w); v3 = v3 > 0.f ? v3 : 0.f;
    // layer-2 scores: dot(relu_h, us/ud) over 128 channels (32-lane reduce)
    float4 u_s = *(const float4*)(usv + 4 * c);
    float4 u_d = *(const float4*)(udv + 4 * c);
    float ps = v0 * u_s.x + v1 * u_s.y + v2 * u_s.z + v3 * u_s.w;
    float pd = v0 * u_d.x + v1 * u_d.y + v2 * u_d.z + v3 * u_d.w;
    #pragma unroll
    for (int off = 1; off <= 16; off <<= 1) {
        ps += __shfl_xor(ps, off); pd += __shfl_xor(pd, off);
    }
    if (lane == 0) { ssrc2[n] = ps; sdst2[n] = pd; }
    if (half == 0) {
        ushort4 hs = make_ushort4(f2bf(v0), f2bf(v1), f2bf(v2), f2bf(v3));
        *reinterpret_cast<ushort4*>(hrb + (size_t)n * C1 + 4 * c) = hs;
    }
}

// ============ GEMM2 (MFMA): h3 = hrb @ (W2@fcW), 128x64x128 per block ============
__global__ __launch_bounds__(256, 1) void k5_mfma(const u16* __restrict__ hrb,
    const u16* __restrict__ W2pbt, u16* __restrict__ h3b) {
    __shared__ u16 As[128][136];
    __shared__ u16 Bs[64][136];
    int t = threadIdx.x;
    int rbase = blockIdx.x * 128;
    #pragma unroll
    for (int j = 0; j < 4; ++j) {          // stage (W2@fcW)^T bf16
        int i = t + 256 * j, row = i >> 4, seg = i & 15;
        *reinterpret_cast<uint4*>(&Bs[row][seg * 8]) =
            *reinterpret_cast<const uint4*>(W2pbt + row * 128 + seg * 8);
    }
    #pragma unroll
    for (int j = 0; j < 8; ++j) {          // stage hrb tile (bf16, linear)
        int i = t + 256 * j, row = i >> 4, seg = i & 15;
        int gr = rbase + row; if (gr >= NN) gr = NN - 1;
        *reinterpret_cast<uint4*>(&As[row][seg * 8]) =
            *reinterpret_cast<const uint4*>(hrb + (size_t)gr * 128 + seg * 8);
    }
    __syncthreads();
    int lane = t & 63, wv = t >> 6, wr = wv >> 1, wc = wv & 1;
    int fr = lane & 15, fg = lane >> 4;
    f32x4 acc[4][2];
    #pragma unroll
    for (int m = 0; m < 4; ++m)
        #pragma unroll
        for (int n = 0; n < 2; ++n) acc[m][n] = (f32x4){0.f, 0.f, 0.f, 0.f};
    #pragma unroll
    for (int kk = 0; kk < 4; ++kk) {
        bf16x8 af[4], bfr[2];
        #pragma unroll
        for (int m = 0; m < 4; ++m)
            af[m] = *reinterpret_cast<const bf16x8*>(&As[wr * 64 + m * 16 + fr][kk * 32 + fg * 8]);
        #pragma unroll
        for (int n = 0; n < 2; ++n)
            bfr[n] = *reinterpret_cast<const bf16x8*>(&Bs[wc * 32 + n * 16 + fr][kk * 32 + fg * 8]);
        #pragma unroll
        for (int m = 0; m < 4; ++m)
            #pragma unroll
            for (int n = 0; n < 2; ++n)
                acc[m][n] = __builtin_amdgcn_mfma_f32_16x16x32_bf16(af[m], bfr[n], acc[m][n], 0, 0, 0);
    }
    #pragma unroll
    for (int m = 0; m < 4; ++m)
        #pragma unroll
        for (int r = 0; r < 4; ++r) {
            int row = rbase + wr * 64 + m * 16 + fg * 4 + r;
            if (row < NN) {
                #pragma unroll
                for (int n = 0; n < 2; ++n)
                    h3b[(size_t)row * 64 + wc * 32 + n * 16 + fr] = f2bf(acc[m][n][r]);
            }
        }
}

// ====== Aggregation layer 2 + log_softmax (FC pre-folded into h3) ======
__global__ __launch_bounds__(256) void agg2ls(const int* __restrict__ rowstart,
    const int* __restrict__ eidx, const float* __restrict__ ssrc,
    const float* __restrict__ sdst, const u16* __restrict__ h3b,
    const float* __restrict__ b2p, float* __restrict__ out) {
    int lane = threadIdx.x & 63;
    int n = blockIdx.x * 4 + (threadIdx.x >> 6);
    if (n >= NN) return;
    int r0 = rowstart[n], deg = rowstart[n + 1] - r0;
    int j16 = lane & 15, quarter = lane >> 4, c16 = lane & 15;
    float sd = sdst[n];
    int s0 = (j16 < deg) ? eidx[r0 + j16] : eidx[r0];
    uint2 pv[4];
    #pragma unroll
    for (int q = 0; q < 4; ++q) {
        int s = __shfl(s0, 4 * q + quarter);
        pv[q] = *(const uint2*)(h3b + (size_t)s * C2 + 4 * c16);
    }
    float sv0 = (j16 < deg) ? lrelu(ssrc[s0] + sd) : -FLT_MAX;
    float mx = sv0;
    #pragma unroll
    for (int off = 1; off <= 8; off <<= 1) mx = fmaxf(mx, __shfl_xor(mx, off));
    for (int base = 16; base < deg; base += 16) {            // rare
        int j = base + j16;
        float sv = (j < deg) ? lrelu(ssrc[eidx[r0 + j]] + sd) : -FLT_MAX;
        #pragma unroll
        for (int off = 1; off <= 8; off <<= 1) sv = fmaxf(sv, __shfl_xor(sv, off));
        mx = fmaxf(mx, sv);
    }
    float w = (j16 < deg) ? __expf(sv0 - mx) : 0.f;
    float den = w;
    float a0 = 0.f, a1 = 0.f, a2 = 0.f, a3 = 0.f;
    #pragma unroll
    for (int q = 0; q < 4; ++q) {
        float wq = __shfl(w, 4 * q + quarter);
        a0 = fmaf(wq, bflo(pv[q].x), a0);
        a1 = fmaf(wq, bfhi(pv[q].x), a1);
        a2 = fmaf(wq, bflo(pv[q].y), a2);
        a3 = fmaf(wq, bfhi(pv[q].y), a3);
    }
    for (int base = 16; base < deg; base += 16) {            // rare
        int j = base + j16;
        int sreg = (j < deg) ? eidx[r0 + j] : eidx[r0];
        uint2 qv[4];
        #pragma unroll
        for (int q = 0; q < 4; ++q) {
            int s = __shfl(sreg, 4 * q + quarter);
            qv[q] = *(const uint2*)(h3b + (size_t)s * C2 + 4 * c16);
        }
        float wb = (j < deg) ? __expf(lrelu(ssrc[sreg] + sd) - mx) : 0.f;
        den += wb;
        #pragma unroll
        for (int q = 0; q < 4; ++q) {
            float wq = __shfl(wb, 4 * q + quarter);
            a0 = fmaf(wq, bflo(qv[q].x), a0);
            a1 = fmaf(wq, bfhi(qv[q].x), a1);
            a2 = fmaf(wq, bflo(qv[q].y), a2);
            a3 = fmaf(wq, bfhi(qv[q].y), a3);
        }
    }
    #pragma unroll
    for (int off = 1; off <= 8; off <<= 1) den += __shfl_xor(den, off);
    a0 += __shfl_xor(a0, 16); a0 += __shfl_xor(a0, 32);
    a1 += __shfl_xor(a1, 16); a1 += __shfl_xor(a1, 32);
    a2 += __shfl_xor(a2, 16); a2 += __shfl_xor(a2, 32);
    a3 += __shfl_xor(a3, 16); a3 += __shfl_xor(a3, 32);
    float4 bv = *(const float4*)(b2p + 4 * c16);
    float rd = 1.f / den;
    float v0 = a0 * rd + bv.x, v1 = a1 * rd + bv.y;
    float v2 = a2 * rd + bv.z, v3 = a3 * rd + bv.w;
    float m4 = fmaxf(fmaxf(v0, v1), fmaxf(v2, v3));
    #pragma unroll
    for (int off = 1; off <= 8; off <<= 1) m4 = fmaxf(m4, __shfl_xor(m4, off));
    float se = __expf(v0 - m4) + __expf(v1 - m4) + __expf(v2 - m4) + __expf(v3 - m4);
    #pragma unroll
    for (int off = 1; off <= 8; off <<= 1) se += __shfl_xor(se, off);
    float lse = m4 + logf(se);
    if (quarter == 0) {
        *(float4*)(out + (size_t)n * C2 + 4 * c16) =
            make_float4(v0 - lse, v1 - lse, v2 - lse, v3 - lse);
    }
}

extern "C" void kernel_launch(void* const* d_in, const int* in_sizes, int n_in,
                              void* d_out, int out_size, void* d_ws, size_t ws_size,
                              hipStream_t stream) {
    const float* x   = (const float*)d_in[0];
    const int*   ei  = (const int*)d_in[1];
    const float* W1  = (const float*)d_in[2];
    const float* as1 = (const float*)d_in[3];
    const float* ad1 = (const float*)d_in[4];
    const float* b1  = (const float*)d_in[5];
    const float* W2  = (const float*)d_in[6];
    const float* as2 = (const float*)d_in[7];
    const float* ad2 = (const float*)d_in[8];
    const float* b2  = (const float*)d_in[9];
    const float* fcW = (const float*)d_in[10];
    const float* fcb = (const float*)d_in[11];
    float* out = (float*)d_out;

    float* ws = (float*)d_ws;
    size_t o = 0;
    u16* h1b   = (u16*)(ws + o); o += (size_t)NN * C1 / 2;  // bf16 [NN][128] (reused as h3b)
    u16* hrb   = (u16*)(ws + o); o += (size_t)NN * C1 / 2;  // bf16 [NN][128]
    float* ssrc1 = ws + o; o += (size_t)NN * 4;
    float* sdst1 = ws + o; o += (size_t)NN * 4;
    float* ssrc2 = ws + o; o += NN;
    float* sdst2 = ws + o; o += NN;
    float* usv   = ws + o; o += 128;
    float* udv   = ws + o; o += 128;
    float* b2p   = ws + o; o += 64;
    u16* W2pbt = (u16*)(ws + o); o += 64 * 128 / 2;
    u16* W1bt  = (u16*)(ws + o); o += 128 * 128 / 2;
    int* ip = (int*)(ws + o);
    int* bcnt     = ip; ip += NBKT * 16;       // line-padded counters
    int* bbase    = ip; ip += 1024;
    int* rowstart = ip; ip += NN + 2;
    int* eidx     = ip; ip += TE;
    u32* bbuf     = (u32*)ip; ip += (size_t)NBKT * BCAP;   // 12.8 MB
    u16* h3b = h1b;   // h1b dead after agg1; reuse for h3

    const int* esrc = ei;
    const int* edst = ei + EE;

    hipMemsetAsync(bcnt, 0, (size_t)NBKT * 16 * sizeof(int), stream);

    // fold FC into layer-2 weights; bf16-transposed weight copies
    kprep<<<259, 64, 0, stream>>>(W2, as2, ad2, b2, fcW, fcb, W1,
                                  W2pbt, W1bt, usv, udv, b2p);

    // CSR build, bucketed
    kpassA<<<(EE / 4 + 255) / 256, 256, 0, stream>>>(esrc, edst, bcnt, bbuf);
    kbscan<<<1, 1024, 0, stream>>>(bcnt, bbase);
    kpassB<<<NBKT, 256, 0, stream>>>(bcnt, bbase, bbuf, rowstart, eidx);

    // layer 1
    k1_mfma<<<NB1, 256, 0, stream>>>(x, W1bt, h1b);
    kscore1<<<(NN * 4 + 255) / 256, 256, 0, stream>>>(h1b, as1, ad1, ssrc1, sdst1);
    agg1<<<(NN + 3) / 4, 256, 0, stream>>>(rowstart, eidx, ssrc1, sdst1, h1b, b1,
                                           usv, udv, hrb, ssrc2, sdst2);
    // layer 2 (FC pre-folded)
    k5_mfma<<<NB1, 256, 0, stream>>>(hrb, W2pbt, h3b);
    agg2ls<<<(NN + 3) / 4, 256, 0, stream>>>(rowstart, eidx, ssrc2, sdst2, h3b, b2p, out);
}